// Round 11
// baseline (221.320 us; speedup 1.0000x reference)
//
#include <hip/hip_runtime.h>

// Problem constants
#define LQ  512
#define LKN 512
#define BB  32
#define DD  768
#define DSL (DD / 4)

typedef float    f4     __attribute__((ext_vector_type(4)));
typedef _Float16 half8  __attribute__((ext_vector_type(8)));
typedef _Float16 half4  __attribute__((ext_vector_type(4)));
typedef __fp16   fp16x2 __attribute__((ext_vector_type(2)));

union H8 { half8 h; unsigned int u[4]; };

__device__ __forceinline__ unsigned int pk2(float a, float b) {
    union { fp16x2 h; unsigned int u; } c;
    c.h = __builtin_amdgcn_cvt_pkrtz(a, b);
    return c.u;
}
__device__ __forceinline__ half8 cvt8(f4 a, f4 b) {
    H8 r;
    r.u[0] = pk2(a[0], a[1]); r.u[1] = pk2(a[2], a[3]);
    r.u[2] = pk2(b[0], b[1]); r.u[3] = pk2(b[2], b[3]);
    return r.h;
}

// ---------------------------------------------------------------------------
// Prep: XF fragment-packed f16; XT transposed f16 [B][D][L].
// ---------------------------------------------------------------------------
__global__ __launch_bounds__(256)
void prep_cvt_t(const float* __restrict__ x1, const float* __restrict__ x2,
                _Float16* __restrict__ xf1, _Float16* __restrict__ xf2,
                _Float16* __restrict__ xt1, _Float16* __restrict__ xt2)
{
    const int bi   = blockIdx.x;            // 6144
    const int side = bi / 3072;
    const int rem  = bi % 3072;
    const int b    = rem / 96;
    const int rem2 = rem % 96;
    const int l0   = (rem2 / 12) * 64;
    const int d0   = (rem2 % 12) * 64;

    const float* __restrict__ X  = side ? x2  : x1;
    _Float16* __restrict__    XF = side ? xf2 : xf1;
    _Float16* __restrict__    XT = side ? xt2 : xt1;

    __shared__ _Float16 T[64][72];

    const int tid = threadIdx.x;
    {
        const int r  = tid >> 4;
        const int c4 = (tid & 15) * 4;
        for (int rr = r; rr < 64; rr += 16) {
            const size_t idx = ((size_t)(l0 + rr) * BB + b) * DD + d0 + c4;
            f4 v = *(const f4*)(X + idx);
            half4 h;
            h[0] = (_Float16)v[0]; h[1] = (_Float16)v[1];
            h[2] = (_Float16)v[2]; h[3] = (_Float16)v[3];
            *(half4*)&T[rr][c4] = h;
        }
    }
    __syncthreads();
    {
        const int d  = tid >> 2;
        const int lq = (tid & 3) * 16;
        half8 a, c;
        #pragma unroll
        for (int i = 0; i < 8; ++i) { a[i] = T[lq + i][d]; c[i] = T[lq + 8 + i][d]; }
        _Float16* p = XT + ((size_t)b * DD + d0 + d) * LKN + l0 + lq;
        *(half8*)p       = a;
        *(half8*)(p + 8) = c;
    }
    #pragma unroll
    for (int c = tid; c < 512; c += 256) {
        const int t16l = c >> 7;
        const int ksl  = (c >> 6) & 1;
        const int ln   = c & 63;
        half8 v = *(const half8*)&T[t16l * 16 + (ln & 15)][ksl * 32 + (ln >> 4) * 8];
        const size_t t16g = (size_t)(l0 >> 4) + t16l;
        const size_t ksg  = (size_t)(d0 >> 5) + ksl;
        *(half8*)(XF + (((size_t)b * 32 + t16g) * 24 + ksg) * 512 + ln * 8) = v;
    }
}

// ---------------------------------------------------------------------------
// Stage 1: S = x1.x2^T (f32), 128x128 tile/block, no LDS.
// ---------------------------------------------------------------------------
__global__ __launch_bounds__(256, 3)
void gemm_s(const _Float16* __restrict__ xf1, const _Float16* __restrict__ xf2,
            float* __restrict__ S)
{
    const int i   = blockIdx.x;            // 512
    const int xcd = i & 7;
    const int j   = i >> 3;                // 0..63
    const int t   = j & 15;                // tile fastest
    const int b   = xcd * 4 + (j >> 4);    // b slowest
    const int lt  = t >> 2, mt = t & 3;
    const int l0b = lt * 128, m0b = mt * 128;

    const int tid  = threadIdx.x;
    const int lane = tid & 63;
    const int w    = tid >> 6;
    const int wl   = w >> 1, wm = w & 1;
    const int lr   = lane & 15;
    const int lg   = lane >> 4;

    f4 acc[16];
    #pragma unroll
    for (int t2 = 0; t2 < 16; ++t2) acc[t2] = f4{0.f, 0.f, 0.f, 0.f};

    {
        const _Float16* ab = xf1 + (((size_t)b * 32 + lt * 8 + wl * 4) * 24) * 512 + lane * 8;
        const _Float16* bb = xf2 + (((size_t)b * 32 + mt * 8 + wm * 4) * 24) * 512 + lane * 8;
        __builtin_amdgcn_s_setprio(1);
        #pragma unroll
        for (int ks = 0; ks < 24; ++ks) {
            half8 aF[4], bF[4];
            #pragma unroll
            for (int q = 0; q < 4; ++q) {
                aF[q] = *(const half8*)(ab + ((size_t)q * 24 + ks) * 512);
                bF[q] = *(const half8*)(bb + ((size_t)q * 24 + ks) * 512);
            }
            #pragma unroll
            for (int q = 0; q < 4; ++q)
                #pragma unroll
                for (int p = 0; p < 4; ++p)
                    acc[q * 4 + p] = __builtin_amdgcn_mfma_f32_16x16x32_f16(aF[q], bF[p], acc[q * 4 + p], 0, 0, 0);
        }
        __builtin_amdgcn_s_setprio(0);
    }

    {
        float* srow = S + ((size_t)b * 512 + l0b + wl * 64) * 512 + m0b + wm * 64;
        #pragma unroll
        for (int q = 0; q < 4; ++q)
            #pragma unroll
            for (int p = 0; p < 4; ++p)
                #pragma unroll
                for (int r = 0; r < 4; ++r)
                    srow[(size_t)(q * 16 + 4 * lg + r) * 512 + p * 16 + lr] = acc[q * 4 + p][r];
    }
}

// ---------------------------------------------------------------------------
// Stage 1b: ST = S^T (f32), 64x64 tiles via LDS (ST overlays dead XF region).
// ---------------------------------------------------------------------------
__global__ __launch_bounds__(256)
void transpose_s(const float* __restrict__ S, float* __restrict__ ST)
{
    const int i   = blockIdx.x;            // 2048
    const int xcd = i & 7;
    const int j   = i >> 3;                // 0..255
    const int t   = j & 63;
    const int b   = xcd * 4 + (j >> 6);
    const int lt  = t >> 3, mt = t & 7;

    __shared__ float T[64][65];

    const int tid = threadIdx.x;
    const int r   = tid >> 2;
    const int c0  = (tid & 3) * 16;

    {
        const float* src = S + ((size_t)b * 512 + lt * 64 + r) * 512 + mt * 64 + c0;
        #pragma unroll
        for (int k = 0; k < 4; ++k) {
            f4 v = *(const f4*)(src + k * 4);
            T[r][c0 + k * 4 + 0] = v[0]; T[r][c0 + k * 4 + 1] = v[1];
            T[r][c0 + k * 4 + 2] = v[2]; T[r][c0 + k * 4 + 3] = v[3];
        }
    }
    __syncthreads();
    {
        float* dst = ST + ((size_t)b * 512 + mt * 64 + r) * 512 + lt * 64 + c0;
        #pragma unroll
        for (int k = 0; k < 4; ++k) {
            f4 v;
            v[0] = T[c0 + k * 4 + 0][r]; v[1] = T[c0 + k * 4 + 1][r];
            v[2] = T[c0 + k * 4 + 2][r]; v[3] = T[c0 + k * 4 + 3][r];
            *(f4*)(dst + k * 4) = v;
        }
    }
}

// ---------------------------------------------------------------------------
// Stage 2: row softmax on f32 scores; writes normalized P f16 in-place into
// the first half of each f32 row slot.
// ---------------------------------------------------------------------------
__global__ __launch_bounds__(256)
void softmax_rows(float* __restrict__ S32, float* __restrict__ ST32,
                  const float* __restrict__ m1, const float* __restrict__ m2)
{
    const int bi   = blockIdx.x;           // 1024
    const int side = bi >> 9;
    const int idx  = bi & 511;
    const int b    = idx >> 4;
    const int rt   = idx & 15;

    float* __restrict__ P = side ? ST32 : S32;
    const float* __restrict__ MK = side ? m1 : m2;

    const int tid  = threadIdx.x;
    const int lane = tid & 63;
    const int w    = tid >> 6;

    __shared__ float mask_s[LKN];
    mask_s[tid] = MK[tid * BB + b];
    mask_s[tid + 256] = MK[(tid + 256) * BB + b];
    __syncthreads();

    float mk[8];
    #pragma unroll
    for (int j = 0; j < 8; ++j) mk[j] = mask_s[lane * 8 + j];

    for (int rr = 0; rr < 8; ++rr) {
        const int row = rt * 32 + w * 8 + rr;
        float* rp = P + ((size_t)b * 512 + row) * 512 + lane * 8;
        const f4 a = *(const f4*)rp;
        const f4 c = *(const f4*)(rp + 4);
        float f[8] = {a[0], a[1], a[2], a[3], c[0], c[1], c[2], c[3]};
        float m = fmaxf(fmaxf(fmaxf(f[0], f[1]), fmaxf(f[2], f[3])),
                        fmaxf(fmaxf(f[4], f[5]), fmaxf(f[6], f[7])));
        #pragma unroll
        for (int d = 1; d <= 32; d <<= 1) m = fmaxf(m, __shfl_xor(m, d));
        float e[8], s = 0.f;
        #pragma unroll
        for (int j = 0; j < 8; ++j) { e[j] = __expf(f[j] - m) * mk[j]; s += e[j]; }
        #pragma unroll
        for (int d = 1; d <= 32; d <<= 1) s += __shfl_xor(s, d);
        const float inv = 1.f / (s + 1e-8f);
        H8 o;
        o.u[0] = pk2(e[0] * inv, e[1] * inv); o.u[1] = pk2(e[2] * inv, e[3] * inv);
        o.u[2] = pk2(e[4] * inv, e[5] * inv); o.u[3] = pk2(e[6] * inv, e[7] * inv);
        *(half8*)((_Float16*)(P + ((size_t)b * 512 + row) * 512) + lane * 8) = o.h;
    }
}

// ---------------------------------------------------------------------------
// Stage 3: OUT = P.V — 32-row P tiles (32 KB LDS), 2048 blocks, 4 blocks/CU.
// P rows are f16 in f32 row slots (stride 1024 f16). lt fastest: 16
// consecutive blocks share one 393 KB V slice.
// ---------------------------------------------------------------------------
__global__ __launch_bounds__(256, 4)
void pv_gemm(const float* __restrict__ S32, const float* __restrict__ ST32,
             const _Float16* __restrict__ xt1, const _Float16* __restrict__ xt2,
             float* __restrict__ o1, float* __restrict__ o2)
{
    const int i    = blockIdx.x;           // 2048
    const int xcd  = i & 7;
    const int j    = i >> 3;               // 0..255
    const int lt   = j & 15;               // fastest: 16 l-tiles of 32 rows
    const int dh   = (j >> 4) & 1;
    const int side = (j >> 5) & 1;
    const int b    = xcd * 4 + (j >> 6);   // slowest
    const int l0   = lt * 32;
    const int dblk = dh * 384;

    const float* __restrict__ P32   = side ? ST32 : S32;
    const _Float16* __restrict__ VT = side ? xt1 : xt2;
    float* __restrict__ OUT         = side ? o2 : o1;

    const int tid  = threadIdx.x;
    const int lane = tid & 63;
    const int w    = tid >> 6;
    const int lr   = lane & 15;
    const int lg   = lane >> 4;

    __shared__ char plds[32 * 1024];       // 32 KB, byte = row*1024 + (col2 ^ ((row&7)<<4))

    // stage P-tile (32 rows x 512 f16), swizzled on LDS write
    {
        const int row = tid & 31;
        const int seg = tid >> 5;          // 0..7, 128B each
        const _Float16* src = (const _Float16*)(P32 + ((size_t)b * 512 + l0 + row) * 512) + seg * 64;
        #pragma unroll
        for (int it = 0; it < 8; ++it) {
            const half8 v = *(const half8*)(src + it * 8);
            const int byo = (seg * 128 + it * 16) ^ ((row & 7) << 4);
            *(half8*)(plds + row * 1024 + byo) = v;
        }
    }
    __syncthreads();

    f4 acc[12];                            // [q(0..1)][nt(0..5)]
    #pragma unroll
    for (int t = 0; t < 12; ++t) acc[t] = f4{0.f, 0.f, 0.f, 0.f};

    {
        const _Float16* vtb = VT + ((size_t)b * DD + dblk + w * 96 + lr) * LKN + lg * 8;
        __builtin_amdgcn_s_setprio(1);
        #pragma unroll
        for (int ks2 = 0; ks2 < 16; ++ks2) {
            half8 pa[2];
            #pragma unroll
            for (int q = 0; q < 2; ++q) {
                const int row = q * 16 + lr;
                pa[q] = *(const half8*)(plds + row * 1024 + ((ks2 * 64 + lg * 16) ^ ((row & 7) << 4)));
            }
            #pragma unroll
            for (int nt = 0; nt < 6; ++nt) {
                const half8 vf = *(const half8*)(vtb + (size_t)nt * 16 * LKN + ks2 * 32);
                acc[nt]     = __builtin_amdgcn_mfma_f32_16x16x32_f16(pa[0], vf, acc[nt], 0, 0, 0);
                acc[6 + nt] = __builtin_amdgcn_mfma_f32_16x16x32_f16(pa[1], vf, acc[6 + nt], 0, 0, 0);
            }
        }
        __builtin_amdgcn_s_setprio(0);
    }

    #pragma unroll
    for (int q = 0; q < 2; ++q)
        #pragma unroll
        for (int nt = 0; nt < 6; ++nt)
            #pragma unroll
            for (int r = 0; r < 4; ++r)
                OUT[((size_t)(l0 + q * 16 + 4 * lg + r) * BB + b) * DD + dblk + w * 96 + nt * 16 + lr]
                    = acc[q * 6 + nt][r];
}

// ---------------------------------------------------------------------------
// Fallback A (r7 fused kernel, needs 96 MiB ws).
// ---------------------------------------------------------------------------
__global__ __launch_bounds__(256, 3)
void coatt_flash_f16(const _Float16* __restrict__ xf1, const _Float16* __restrict__ xf2,
                     const _Float16* __restrict__ xt1, const _Float16* __restrict__ xt2,
                     const float* __restrict__ m1, const float* __restrict__ m2,
                     float* __restrict__ o1, float* __restrict__ o2)
{
    const int i    = blockIdx.x;
    const int xcd  = i & 7;
    const int j    = i >> 3;
    const int pair = xcd * 8 + (j >> 5);
    const int qt   = j & 31;
    const int side = pair >> 5;
    const int b    = pair & 31;

    const _Float16* __restrict__ QF = side ? xf2 : xf1;
    const _Float16* __restrict__ KF = side ? xf1 : xf2;
    const _Float16* __restrict__ VT = side ? xt1 : xt2;
    const float* __restrict__    MK = side ? m1  : m2;
    float* __restrict__         OUT = side ? o2  : o1;

    const int tid  = threadIdx.x;
    const int lane = tid & 63;
    const int w    = tid >> 6;
    const int lr   = lane & 15;
    const int lg   = lane >> 4;
    const int q0 = qt * 16;

    __shared__ _Float16 plds_h[16 * LKN];
    __shared__ float redmax[4][16];
    __shared__ float redsum[4][16];
    __shared__ float mask_s[LKN];
    char* const pb = (char*)plds_h;

    for (int t = tid; t < LKN; t += 256) mask_s[t] = MK[t * BB + b];

    f4 sacc[8];
    #pragma unroll
    for (int t = 0; t < 8; ++t) sacc[t] = f4{0.f, 0.f, 0.f, 0.f};
    {
        const _Float16* qbase = QF + (((size_t)b * 32 + qt) * 24) * 512 + lane * 8;
        const _Float16* kbase = KF + (((size_t)b * 32 + w * 8) * 24) * 512 + lane * 8;
        #pragma unroll
        for (int half = 0; half < 2; ++half) {
            half8 qf[12];
            #pragma unroll
            for (int ks = 0; ks < 12; ++ks) qf[ks] = *(const half8*)(qbase + (half * 12 + ks) * 512);
            __builtin_amdgcn_s_setprio(1);
            #pragma unroll
            for (int ks = 0; ks < 12; ++ks) {
                #pragma unroll
                for (int kt = 0; kt < 8; ++kt) {
                    const half8 kf = *(const half8*)(kbase + ((size_t)kt * 24 + half * 12 + ks) * 512);
                    sacc[kt] = __builtin_amdgcn_mfma_f32_16x16x32_f16(qf[ks], kf, sacc[kt], 0, 0, 0);
                }
            }
            __builtin_amdgcn_s_setprio(0);
        }
    }

    float rm[4];
    #pragma unroll
    for (int r = 0; r < 4; ++r) {
        float m0 = fmaxf(fmaxf(sacc[0][r], sacc[1][r]), fmaxf(sacc[2][r], sacc[3][r]));
        float m1_ = fmaxf(fmaxf(sacc[4][r], sacc[5][r]), fmaxf(sacc[6][r], sacc[7][r]));
        rm[r] = fmaxf(m0, m1_);
    }
    #pragma unroll
    for (int d = 1; d <= 8; d <<= 1) {
        #pragma unroll
        for (int r = 0; r < 4; ++r) rm[r] = fmaxf(rm[r], __shfl_xor(rm[r], d));
    }
    {
        float v = (lr == 0) ? rm[0] : (lr == 1) ? rm[1] : (lr == 2) ? rm[2] : rm[3];
        if (lr < 4) redmax[w][4 * lg + lr] = v;
    }
    __syncthreads();
    float M[4];
    #pragma unroll
    for (int r = 0; r < 4; ++r)
        M[r] = fmaxf(fmaxf(redmax[0][4 * lg + r], redmax[1][4 * lg + r]),
                     fmaxf(redmax[2][4 * lg + r], redmax[3][4 * lg + r]));
    float mval[8];
    #pragma unroll
    for (int kt = 0; kt < 8; ++kt) mval[kt] = mask_s[w * 128 + kt * 16 + lr];
    float ps[4] = {0.f, 0.f, 0.f, 0.f};
    #pragma unroll
    for (int kt = 0; kt < 8; ++kt) {
        #pragma unroll
        for (int r = 0; r < 4; ++r) {
            const float p = __expf(sacc[kt][r] - M[r]) * mval[kt];
            ps[r] += p;
            const int row = 4 * lg + r;
            *(_Float16*)(pb + row * 1024 + (((w * 128 + kt * 16 + lr) * 2) ^ ((row & 7) << 4))) = (_Float16)p;
        }
    }
    #pragma unroll
    for (int d = 1; d <= 8; d <<= 1) {
        #pragma unroll
        for (int r = 0; r < 4; ++r) ps[r] += __shfl_xor(ps[r], d);
    }
    {
        float v = (lr == 0) ? ps[0] : (lr == 1) ? ps[1] : (lr == 2) ? ps[2] : ps[3];
        if (lr < 4) redsum[w][4 * lg + lr] = v;
    }
    __syncthreads();
    float il[4];
    #pragma unroll
    for (int r = 0; r < 4; ++r) {
        const float L = redsum[0][4 * lg + r] + redsum[1][4 * lg + r]
                      + redsum[2][4 * lg + r] + redsum[3][4 * lg + r];
        il[r] = 1.f / (L + 1e-8f);
    }
    const int d0 = w * DSL;
    f4 acc[12];
    #pragma unroll
    for (int t = 0; t < 12; ++t) acc[t] = f4{0.f, 0.f, 0.f, 0.f};
    {
        const _Float16* vtb = VT + ((size_t)b * DD + d0 + lr) * LKN + lg * 8;
        __builtin_amdgcn_s_setprio(1);
        #pragma unroll
        for (int ks2 = 0; ks2 < 16; ++ks2) {
            const half8 pa = *(const half8*)(pb + lr * 1024 + ((ks2 * 64 + lg * 16) ^ ((lr & 7) << 4)));
            #pragma unroll
            for (int nt = 0; nt < 12; ++nt) {
                const half8 vf = *(const half8*)(vtb + (size_t)nt * 16 * LKN + ks2 * 32);
                acc[nt] = __builtin_amdgcn_mfma_f32_16x16x32_f16(pa, vf, acc[nt], 0, 0, 0);
            }
        }
        __builtin_amdgcn_s_setprio(0);
    }
    #pragma unroll
    for (int nt = 0; nt < 12; ++nt) {
        #pragma unroll
        for (int r = 0; r < 4; ++r) {
            OUT[((size_t)(q0 + 4 * lg + r) * BB + b) * DD + d0 + nt * 16 + lr] = acc[nt][r] * il[r];
        }
    }
}

// ---------------------------------------------------------------------------
// Fallback B (f32 direct, no ws).
// ---------------------------------------------------------------------------
__global__ __launch_bounds__(256)
void coatt_flash_f32(const float* __restrict__ x1, const float* __restrict__ m1,
                     const float* __restrict__ x2, const float* __restrict__ m2,
                     float* __restrict__ o1, float* __restrict__ o2)
{
    const int i    = blockIdx.x;
    const int xcd  = i & 7;
    const int j    = i >> 3;
    const int pair = xcd * 8 + (j >> 5);
    const int qt   = j & 31;
    const int side = pair >> 5;
    const int b    = pair & 31;

    const float* __restrict__ Q   = side ? x2 : x1;
    const float* __restrict__ K   = side ? x1 : x2;
    const float* __restrict__ MK  = side ? m1 : m2;
    float* __restrict__       OUT = side ? o2 : o1;

    const int tid  = threadIdx.x;
    const int lane = tid & 63;
    const int w    = tid >> 6;
    const int lr   = lane & 15;
    const int lg   = lane >> 4;
    const int q0 = qt * 16;
    const int d0 = w * DSL;

    __shared__ float sred[4][16][36];
    __shared__ float mask_s[LKN];
    for (int t = tid; t < LKN; t += 256) mask_s[t] = MK[t * BB + b];

    half8 qf[6];
    {
        const float* qrow = Q + ((q0 + lr) * BB + b) * DD + d0 + lg * 8;
        #pragma unroll
        for (int ks = 0; ks < 6; ++ks) {
            f4 a = *(const f4*)(qrow + ks * 32);
            f4 c = *(const f4*)(qrow + ks * 32 + 4);
            qf[ks] = cvt8(a, c);
        }
    }
    f4 acc[12];
    #pragma unroll
    for (int t = 0; t < 12; ++t) acc[t] = f4{0.f, 0.f, 0.f, 0.f};
    float Mrun = -3.0e38f, Lrun = 0.f;
    for (int kt = 0; kt < 16; ++kt) {
        const int k0 = kt * 32;
        f4 s0 = {0.f,0.f,0.f,0.f}, s1 = {0.f,0.f,0.f,0.f};
        {
            const float* kb0 = K + ((k0 + lr) * BB + b) * DD + d0 + lg * 8;
            const float* kb1 = kb0 + 16 * BB * DD;
            #pragma unroll
            for (int ks = 0; ks < 6; ++ks) {
                f4 a0 = *(const f4*)(kb0 + ks * 32);
                f4 c0 = *(const f4*)(kb0 + ks * 32 + 4);
                s0 = __builtin_amdgcn_mfma_f32_16x16x32_f16(qf[ks], cvt8(a0, c0), s0, 0, 0, 0);
                f4 a1 = *(const f4*)(kb1 + ks * 32);
                f4 c1 = *(const f4*)(kb1 + ks * 32 + 4);
                s1 = __builtin_amdgcn_mfma_f32_16x16x32_f16(qf[ks], cvt8(a1, c1), s1, 0, 0, 0);
            }
        }
        __syncthreads();
        #pragma unroll
        for (int r = 0; r < 4; ++r) {
            sred[w][4 * lg + r][lr]      = s0[r];
            sred[w][4 * lg + r][16 + lr] = s1[r];
        }
        __syncthreads();
        f4 sa = {0.f,0.f,0.f,0.f}, sb = {0.f,0.f,0.f,0.f};
        #pragma unroll
        for (int ww = 0; ww < 4; ++ww) {
            sa += *(const f4*)&sred[ww][lr][lg * 8];
            sb += *(const f4*)&sred[ww][lr][lg * 8 + 4];
        }
        float tmax = fmaxf(fmaxf(fmaxf(sa[0], sa[1]), fmaxf(sa[2], sa[3])),
                           fmaxf(fmaxf(sb[0], sb[1]), fmaxf(sb[2], sb[3])));
        tmax = fmaxf(tmax, __shfl_xor(tmax, 16));
        tmax = fmaxf(tmax, __shfl_xor(tmax, 32));
        const float Mnew  = fmaxf(Mrun, tmax);
        const float scale = __expf(Mrun - Mnew);
        float p[8];
        float psum = 0.f;
        const float* mrow = &mask_s[k0 + lg * 8];
        #pragma unroll
        for (int t = 0; t < 4; ++t) { p[t]     = __expf(sa[t] - Mnew) * mrow[t];     psum += p[t]; }
        #pragma unroll
        for (int t = 0; t < 4; ++t) { p[4 + t] = __expf(sb[t] - Mnew) * mrow[4 + t]; psum += p[4 + t]; }
        psum += __shfl_xor(psum, 16);
        psum += __shfl_xor(psum, 32);
        Lrun = Lrun * scale + psum;
        Mrun = Mnew;
        H8 pf;
        pf.u[0] = pk2(p[0], p[1]); pf.u[1] = pk2(p[2], p[3]);
        pf.u[2] = pk2(p[4], p[5]); pf.u[3] = pk2(p[6], p[7]);
        float sc[4];
        #pragma unroll
        for (int r = 0; r < 4; ++r) sc[r] = __shfl(scale, (lane & 48) + 4 * lg + r);
        #pragma unroll
        for (int t = 0; t < 12; ++t) {
            acc[t][0] *= sc[0]; acc[t][1] *= sc[1];
            acc[t][2] *= sc[2]; acc[t][3] *= sc[3];
        }
        const float* vb = K + ((k0 + lg * 8) * BB + b) * DD + d0 + lr;
        #pragma unroll
        for (int nt = 0; nt < 12; ++nt) {
            const float* vp = vb + nt * 16;
            float vv[8];
            #pragma unroll
            for (int t = 0; t < 8; ++t) vv[t] = vp[t * BB * DD];
            H8 vf;
            vf.u[0] = pk2(vv[0], vv[1]); vf.u[1] = pk2(vv[2], vv[3]);
            vf.u[2] = pk2(vv[4], vv[5]); vf.u[3] = pk2(vv[6], vv[7]);
            acc[nt] = __builtin_amdgcn_mfma_f32_16x16x32_f16(pf.h, vf.h, acc[nt], 0, 0, 0);
        }
    }
    float il[4];
    {
        const float inv = 1.f / (Lrun + 1e-8f);
        #pragma unroll
        for (int r = 0; r < 4; ++r) il[r] = __shfl(inv, (lane & 48) + 4 * lg + r);
    }
    #pragma unroll
    for (int nt = 0; nt < 12; ++nt) {
        #pragma unroll
        for (int r = 0; r < 4; ++r) {
            OUT[((q0 + 4 * lg + r) * BB + b) * DD + d0 + nt * 16 + lr] = acc[nt][r] * il[r];
        }
    }
}

extern "C" void kernel_launch(void* const* d_in, const int* in_sizes, int n_in,
                              void* d_out, int out_size, void* d_ws, size_t ws_size,
                              hipStream_t stream) {
    (void)in_sizes; (void)n_in; (void)out_size;
    const float* x1 = (const float*)d_in[0];
    const float* m1 = (const float*)d_in[1];
    const float* x2 = (const float*)d_in[2];
    const float* m2 = (const float*)d_in[3];
    float* o1 = (float*)d_out;
    float* o2 = o1 + (size_t)LQ * BB * DD;

    const size_t ELEMS = (size_t)LQ * BB * DD;           // 12.58M
    const size_t SELEM = (size_t)BB * 512 * 512;         // 8.39M
    const size_t NEED1 = 4 * ELEMS * sizeof(_Float16);   // 100.7 MB (XF/XT)
    const size_t NEED2 = NEED1 + SELEM * sizeof(float);  // 134.2 MB

    if (ws_size >= NEED2) {
        _Float16* xf1 = (_Float16*)d_ws;
        _Float16* xf2 = xf1 + ELEMS;
        _Float16* xt1 = xf2 + ELEMS;
        _Float16* xt2 = xt1 + ELEMS;
        float*    S32 = (float*)(xt2 + ELEMS);           // dedicated 33.6 MB
        float*    ST32 = (float*)d_ws;                   // overlays XF (dead after gemm_s)
        prep_cvt_t<<<6144, 256, 0, stream>>>(x1, x2, xf1, xf2, xt1, xt2);
        gemm_s<<<512, 256, 0, stream>>>(xf1, xf2, S32);
        transpose_s<<<2048, 256, 0, stream>>>(S32, ST32);
        softmax_rows<<<1024, 256, 0, stream>>>(S32, ST32, m1, m2);
        pv_gemm<<<2048, 256, 0, stream>>>(S32, ST32, xt1, xt2, o1, o2);
    } else if (ws_size >= NEED1) {
        _Float16* xf1 = (_Float16*)d_ws;
        _Float16* xf2 = xf1 + ELEMS;
        _Float16* xt1 = xf2 + ELEMS;
        _Float16* xt2 = xt1 + ELEMS;
        prep_cvt_t<<<6144, 256, 0, stream>>>(x1, x2, xf1, xf2, xt1, xt2);
        coatt_flash_f16<<<2048, 256, 0, stream>>>(xf1, xf2, xt1, xt2, m1, m2, o1, o2);
    } else {
        coatt_flash_f32<<<2048, 256, 0, stream>>>(x1, m1, x2, m2, o1, o2);
    }
}

// Round 12
// 179.284 us; speedup vs baseline: 1.2345x; 1.2345x over previous
//
#include <hip/hip_runtime.h>

// Problem constants
#define LQ  512
#define LKN 512
#define BB  32
#define DD  768
#define DSL (DD / 4)

typedef float    f4     __attribute__((ext_vector_type(4)));
typedef _Float16 half8  __attribute__((ext_vector_type(8)));
typedef _Float16 half4  __attribute__((ext_vector_type(4)));
typedef __fp16   fp16x2 __attribute__((ext_vector_type(2)));

union H8 { half8 h; unsigned int u[4]; };

__device__ __forceinline__ unsigned int pk2(float a, float b) {
    union { fp16x2 h; unsigned int u; } c;
    c.h = __builtin_amdgcn_cvt_pkrtz(a, b);
    return c.u;
}
__device__ __forceinline__ half8 cvt8(f4 a, f4 b) {
    H8 r;
    r.u[0] = pk2(a[0], a[1]); r.u[1] = pk2(a[2], a[3]);
    r.u[2] = pk2(b[0], b[1]); r.u[3] = pk2(b[2], b[3]);
    return r.h;
}

// ---------------------------------------------------------------------------
// Prep: XF fragment-packed f16; XT transposed f16 [B][D][L].
// ---------------------------------------------------------------------------
__global__ __launch_bounds__(256)
void prep_cvt_t(const float* __restrict__ x1, const float* __restrict__ x2,
                _Float16* __restrict__ xf1, _Float16* __restrict__ xf2,
                _Float16* __restrict__ xt1, _Float16* __restrict__ xt2)
{
    const int bi   = blockIdx.x;            // 6144
    const int side = bi / 3072;
    const int rem  = bi % 3072;
    const int b    = rem / 96;
    const int rem2 = rem % 96;
    const int l0   = (rem2 / 12) * 64;
    const int d0   = (rem2 % 12) * 64;

    const float* __restrict__ X  = side ? x2  : x1;
    _Float16* __restrict__    XF = side ? xf2 : xf1;
    _Float16* __restrict__    XT = side ? xt2 : xt1;

    __shared__ _Float16 T[64][72];

    const int tid = threadIdx.x;
    {
        const int r  = tid >> 4;
        const int c4 = (tid & 15) * 4;
        for (int rr = r; rr < 64; rr += 16) {
            const size_t idx = ((size_t)(l0 + rr) * BB + b) * DD + d0 + c4;
            f4 v = *(const f4*)(X + idx);
            half4 h;
            h[0] = (_Float16)v[0]; h[1] = (_Float16)v[1];
            h[2] = (_Float16)v[2]; h[3] = (_Float16)v[3];
            *(half4*)&T[rr][c4] = h;
        }
    }
    __syncthreads();
    {
        const int d  = tid >> 2;
        const int lq = (tid & 3) * 16;
        half8 a, c;
        #pragma unroll
        for (int i = 0; i < 8; ++i) { a[i] = T[lq + i][d]; c[i] = T[lq + 8 + i][d]; }
        _Float16* p = XT + ((size_t)b * DD + d0 + d) * LKN + l0 + lq;
        *(half8*)p       = a;
        *(half8*)(p + 8) = c;
    }
    #pragma unroll
    for (int c = tid; c < 512; c += 256) {
        const int t16l = c >> 7;
        const int ksl  = (c >> 6) & 1;
        const int ln   = c & 63;
        half8 v = *(const half8*)&T[t16l * 16 + (ln & 15)][ksl * 32 + (ln >> 4) * 8];
        const size_t t16g = (size_t)(l0 >> 4) + t16l;
        const size_t ksg  = (size_t)(d0 >> 5) + ksl;
        *(half8*)(XF + (((size_t)b * 32 + t16g) * 24 + ksg) * 512 + ln * 8) = v;
    }
}

// ---------------------------------------------------------------------------
// Stage 1: S = x1.x2^T (f32), 128x128 tile/block, no LDS.
// ---------------------------------------------------------------------------
__global__ __launch_bounds__(256, 3)
void gemm_s(const _Float16* __restrict__ xf1, const _Float16* __restrict__ xf2,
            float* __restrict__ S)
{
    const int i   = blockIdx.x;            // 512
    const int xcd = i & 7;
    const int j   = i >> 3;                // 0..63
    const int t   = j & 15;                // tile fastest
    const int b   = xcd * 4 + (j >> 4);    // b slowest
    const int lt  = t >> 2, mt = t & 3;
    const int l0b = lt * 128, m0b = mt * 128;

    const int tid  = threadIdx.x;
    const int lane = tid & 63;
    const int w    = tid >> 6;
    const int wl   = w >> 1, wm = w & 1;
    const int lr   = lane & 15;
    const int lg   = lane >> 4;

    f4 acc[16];
    #pragma unroll
    for (int t2 = 0; t2 < 16; ++t2) acc[t2] = f4{0.f, 0.f, 0.f, 0.f};

    {
        const _Float16* ab = xf1 + (((size_t)b * 32 + lt * 8 + wl * 4) * 24) * 512 + lane * 8;
        const _Float16* bb = xf2 + (((size_t)b * 32 + mt * 8 + wm * 4) * 24) * 512 + lane * 8;
        __builtin_amdgcn_s_setprio(1);
        #pragma unroll
        for (int ks = 0; ks < 24; ++ks) {
            half8 aF[4], bF[4];
            #pragma unroll
            for (int q = 0; q < 4; ++q) {
                aF[q] = *(const half8*)(ab + ((size_t)q * 24 + ks) * 512);
                bF[q] = *(const half8*)(bb + ((size_t)q * 24 + ks) * 512);
            }
            #pragma unroll
            for (int q = 0; q < 4; ++q)
                #pragma unroll
                for (int p = 0; p < 4; ++p)
                    acc[q * 4 + p] = __builtin_amdgcn_mfma_f32_16x16x32_f16(aF[q], bF[p], acc[q * 4 + p], 0, 0, 0);
        }
        __builtin_amdgcn_s_setprio(0);
    }

    {
        float* srow = S + ((size_t)b * 512 + l0b + wl * 64) * 512 + m0b + wm * 64;
        #pragma unroll
        for (int q = 0; q < 4; ++q)
            #pragma unroll
            for (int p = 0; p < 4; ++p)
                #pragma unroll
                for (int r = 0; r < 4; ++r)
                    srow[(size_t)(q * 16 + 4 * lg + r) * 512 + p * 16 + lr] = acc[q * 4 + p][r];
    }
}

// ---------------------------------------------------------------------------
// Stage 1b: ST = S^T (f32), 64x64 tiles via LDS (ST overlays dead XF region).
// ---------------------------------------------------------------------------
__global__ __launch_bounds__(256)
void transpose_s(const float* __restrict__ S, float* __restrict__ ST)
{
    const int i   = blockIdx.x;            // 2048
    const int xcd = i & 7;
    const int j   = i >> 3;                // 0..255
    const int t   = j & 63;
    const int b   = xcd * 4 + (j >> 6);
    const int lt  = t >> 3, mt = t & 7;

    __shared__ float T[64][65];

    const int tid = threadIdx.x;
    const int r   = tid >> 2;
    const int c0  = (tid & 3) * 16;

    {
        const float* src = S + ((size_t)b * 512 + lt * 64 + r) * 512 + mt * 64 + c0;
        #pragma unroll
        for (int k = 0; k < 4; ++k) {
            f4 v = *(const f4*)(src + k * 4);
            T[r][c0 + k * 4 + 0] = v[0]; T[r][c0 + k * 4 + 1] = v[1];
            T[r][c0 + k * 4 + 2] = v[2]; T[r][c0 + k * 4 + 3] = v[3];
        }
    }
    __syncthreads();
    {
        float* dst = ST + ((size_t)b * 512 + mt * 64 + r) * 512 + lt * 64 + c0;
        #pragma unroll
        for (int k = 0; k < 4; ++k) {
            f4 v;
            v[0] = T[c0 + k * 4 + 0][r]; v[1] = T[c0 + k * 4 + 1][r];
            v[2] = T[c0 + k * 4 + 2][r]; v[3] = T[c0 + k * 4 + 3][r];
            *(f4*)(dst + k * 4) = v;
        }
    }
}

// ---------------------------------------------------------------------------
// Stage 2: row softmax on f32 scores; writes normalized P f16 in-place into
// the first half of each f32 row slot.
// ---------------------------------------------------------------------------
__global__ __launch_bounds__(256)
void softmax_rows(float* __restrict__ S32, float* __restrict__ ST32,
                  const float* __restrict__ m1, const float* __restrict__ m2)
{
    const int bi   = blockIdx.x;           // 1024
    const int side = bi >> 9;
    const int idx  = bi & 511;
    const int b    = idx >> 4;
    const int rt   = idx & 15;

    float* __restrict__ P = side ? ST32 : S32;
    const float* __restrict__ MK = side ? m1 : m2;

    const int tid  = threadIdx.x;
    const int lane = tid & 63;
    const int w    = tid >> 6;

    __shared__ float mask_s[LKN];
    mask_s[tid] = MK[tid * BB + b];
    mask_s[tid + 256] = MK[(tid + 256) * BB + b];
    __syncthreads();

    float mk[8];
    #pragma unroll
    for (int j = 0; j < 8; ++j) mk[j] = mask_s[lane * 8 + j];

    for (int rr = 0; rr < 8; ++rr) {
        const int row = rt * 32 + w * 8 + rr;
        float* rp = P + ((size_t)b * 512 + row) * 512 + lane * 8;
        const f4 a = *(const f4*)rp;
        const f4 c = *(const f4*)(rp + 4);
        float f[8] = {a[0], a[1], a[2], a[3], c[0], c[1], c[2], c[3]};
        float m = fmaxf(fmaxf(fmaxf(f[0], f[1]), fmaxf(f[2], f[3])),
                        fmaxf(fmaxf(f[4], f[5]), fmaxf(f[6], f[7])));
        #pragma unroll
        for (int d = 1; d <= 32; d <<= 1) m = fmaxf(m, __shfl_xor(m, d));
        float e[8], s = 0.f;
        #pragma unroll
        for (int j = 0; j < 8; ++j) { e[j] = __expf(f[j] - m) * mk[j]; s += e[j]; }
        #pragma unroll
        for (int d = 1; d <= 32; d <<= 1) s += __shfl_xor(s, d);
        const float inv = 1.f / (s + 1e-8f);
        H8 o;
        o.u[0] = pk2(e[0] * inv, e[1] * inv); o.u[1] = pk2(e[2] * inv, e[3] * inv);
        o.u[2] = pk2(e[4] * inv, e[5] * inv); o.u[3] = pk2(e[6] * inv, e[7] * inv);
        *(half8*)((_Float16*)(P + ((size_t)b * 512 + row) * 512) + lane * 8) = o.h;
    }
}

// ---------------------------------------------------------------------------
// Stage 3: OUT = P.V — 64-row P tiles (64 KB LDS), 1024 blocks.
// V-fragments loaded in 24-wide register batches (4 ks2 per chunk) to force
// deep memory-level parallelism; all vf/acc indices compile-time.
// ---------------------------------------------------------------------------
__global__ __launch_bounds__(256, 2)
void pv_gemm(const float* __restrict__ S32, const float* __restrict__ ST32,
             const _Float16* __restrict__ xt1, const _Float16* __restrict__ xt2,
             float* __restrict__ o1, float* __restrict__ o2)
{
    const int i    = blockIdx.x;           // 1024
    const int xcd  = i & 7;
    const int j    = i >> 3;               // 0..127
    const int lt   = j & 7;                // fastest: shares V slice
    const int dh   = (j >> 3) & 1;
    const int side = (j >> 4) & 1;
    const int b    = xcd * 4 + (j >> 5);   // slowest
    const int l0   = lt * 64;
    const int dblk = dh * 384;

    const float* __restrict__ P32   = side ? ST32 : S32;
    const _Float16* __restrict__ VT = side ? xt1 : xt2;
    float* __restrict__ OUT         = side ? o2 : o1;

    const int tid  = threadIdx.x;
    const int lane = tid & 63;
    const int w    = tid >> 6;
    const int lr   = lane & 15;
    const int lg   = lane >> 4;

    __shared__ char plds[64 * 1024];       // 64 KB, byte = row*1024 + (col2 ^ ((row&7)<<4))

    // stage P-tile (64 rows x 512 f16 in f32 row slots), swizzled on LDS write
    {
        const int row = tid & 63;
        const int seg = tid >> 6;          // 0..3
        const _Float16* src = (const _Float16*)(P32 + ((size_t)b * 512 + l0 + row) * 512) + seg * 128;
        #pragma unroll
        for (int it = 0; it < 16; ++it) {
            const half8 v = *(const half8*)(src + it * 8);
            const int byo = (seg * 256 + it * 16) ^ ((row & 7) << 4);
            *(half8*)(plds + row * 1024 + byo) = v;
        }
    }
    __syncthreads();

    f4 acc[24];                            // [q(0..3)][nt(0..5)]
    #pragma unroll
    for (int t = 0; t < 24; ++t) acc[t] = f4{0.f, 0.f, 0.f, 0.f};

    {
        const _Float16* vtb = VT + ((size_t)b * DD + dblk + w * 96 + lr) * LKN + lg * 8;
        __builtin_amdgcn_s_setprio(1);
        for (int c = 0; c < 4; ++c) {      // 4 chunks x 4 ks2
            // batch-load 24 independent V-fragments (forces >=24-deep MLP)
            half8 vf[24];
            #pragma unroll
            for (int k2 = 0; k2 < 4; ++k2)
                #pragma unroll
                for (int nt = 0; nt < 6; ++nt)
                    vf[k2 * 6 + nt] = *(const half8*)(vtb + (size_t)nt * 16 * LKN + (c * 4 + k2) * 32);
            #pragma unroll
            for (int k2 = 0; k2 < 4; ++k2) {
                const int ks2 = c * 4 + k2;
                half8 pa[4];
                #pragma unroll
                for (int q = 0; q < 4; ++q) {
                    const int row = q * 16 + lr;
                    pa[q] = *(const half8*)(plds + row * 1024 + ((ks2 * 64 + lg * 16) ^ ((row & 7) << 4)));
                }
                #pragma unroll
                for (int nt = 0; nt < 6; ++nt) {
                    #pragma unroll
                    for (int q = 0; q < 4; ++q)
                        acc[q * 6 + nt] = __builtin_amdgcn_mfma_f32_16x16x32_f16(pa[q], vf[k2 * 6 + nt], acc[q * 6 + nt], 0, 0, 0);
                }
            }
        }
        __builtin_amdgcn_s_setprio(0);
    }

    #pragma unroll
    for (int q = 0; q < 4; ++q)
        #pragma unroll
        for (int nt = 0; nt < 6; ++nt)
            #pragma unroll
            for (int r = 0; r < 4; ++r)
                OUT[((size_t)(l0 + q * 16 + 4 * lg + r) * BB + b) * DD + dblk + w * 96 + nt * 16 + lr]
                    = acc[q * 6 + nt][r];
}

// ---------------------------------------------------------------------------
// Fallback A (r7 fused kernel, needs 96 MiB ws).
// ---------------------------------------------------------------------------
__global__ __launch_bounds__(256, 3)
void coatt_flash_f16(const _Float16* __restrict__ xf1, const _Float16* __restrict__ xf2,
                     const _Float16* __restrict__ xt1, const _Float16* __restrict__ xt2,
                     const float* __restrict__ m1, const float* __restrict__ m2,
                     float* __restrict__ o1, float* __restrict__ o2)
{
    const int i    = blockIdx.x;
    const int xcd  = i & 7;
    const int j    = i >> 3;
    const int pair = xcd * 8 + (j >> 5);
    const int qt   = j & 31;
    const int side = pair >> 5;
    const int b    = pair & 31;

    const _Float16* __restrict__ QF = side ? xf2 : xf1;
    const _Float16* __restrict__ KF = side ? xf1 : xf2;
    const _Float16* __restrict__ VT = side ? xt1 : xt2;
    const float* __restrict__    MK = side ? m1  : m2;
    float* __restrict__         OUT = side ? o2  : o1;

    const int tid  = threadIdx.x;
    const int lane = tid & 63;
    const int w    = tid >> 6;
    const int lr   = lane & 15;
    const int lg   = lane >> 4;
    const int q0 = qt * 16;

    __shared__ _Float16 plds_h[16 * LKN];
    __shared__ float redmax[4][16];
    __shared__ float redsum[4][16];
    __shared__ float mask_s[LKN];
    char* const pb = (char*)plds_h;

    for (int t = tid; t < LKN; t += 256) mask_s[t] = MK[t * BB + b];

    f4 sacc[8];
    #pragma unroll
    for (int t = 0; t < 8; ++t) sacc[t] = f4{0.f, 0.f, 0.f, 0.f};
    {
        const _Float16* qbase = QF + (((size_t)b * 32 + qt) * 24) * 512 + lane * 8;
        const _Float16* kbase = KF + (((size_t)b * 32 + w * 8) * 24) * 512 + lane * 8;
        #pragma unroll
        for (int half = 0; half < 2; ++half) {
            half8 qf[12];
            #pragma unroll
            for (int ks = 0; ks < 12; ++ks) qf[ks] = *(const half8*)(qbase + (half * 12 + ks) * 512);
            __builtin_amdgcn_s_setprio(1);
            #pragma unroll
            for (int ks = 0; ks < 12; ++ks) {
                #pragma unroll
                for (int kt = 0; kt < 8; ++kt) {
                    const half8 kf = *(const half8*)(kbase + ((size_t)kt * 24 + half * 12 + ks) * 512);
                    sacc[kt] = __builtin_amdgcn_mfma_f32_16x16x32_f16(qf[ks], kf, sacc[kt], 0, 0, 0);
                }
            }
            __builtin_amdgcn_s_setprio(0);
        }
    }

    float rm[4];
    #pragma unroll
    for (int r = 0; r < 4; ++r) {
        float m0 = fmaxf(fmaxf(sacc[0][r], sacc[1][r]), fmaxf(sacc[2][r], sacc[3][r]));
        float m1_ = fmaxf(fmaxf(sacc[4][r], sacc[5][r]), fmaxf(sacc[6][r], sacc[7][r]));
        rm[r] = fmaxf(m0, m1_);
    }
    #pragma unroll
    for (int d = 1; d <= 8; d <<= 1) {
        #pragma unroll
        for (int r = 0; r < 4; ++r) rm[r] = fmaxf(rm[r], __shfl_xor(rm[r], d));
    }
    {
        float v = (lr == 0) ? rm[0] : (lr == 1) ? rm[1] : (lr == 2) ? rm[2] : rm[3];
        if (lr < 4) redmax[w][4 * lg + lr] = v;
    }
    __syncthreads();
    float M[4];
    #pragma unroll
    for (int r = 0; r < 4; ++r)
        M[r] = fmaxf(fmaxf(redmax[0][4 * lg + r], redmax[1][4 * lg + r]),
                     fmaxf(redmax[2][4 * lg + r], redmax[3][4 * lg + r]));
    float mval[8];
    #pragma unroll
    for (int kt = 0; kt < 8; ++kt) mval[kt] = mask_s[w * 128 + kt * 16 + lr];
    float ps[4] = {0.f, 0.f, 0.f, 0.f};
    #pragma unroll
    for (int kt = 0; kt < 8; ++kt) {
        #pragma unroll
        for (int r = 0; r < 4; ++r) {
            const float p = __expf(sacc[kt][r] - M[r]) * mval[kt];
            ps[r] += p;
            const int row = 4 * lg + r;
            *(_Float16*)(pb + row * 1024 + (((w * 128 + kt * 16 + lr) * 2) ^ ((row & 7) << 4))) = (_Float16)p;
        }
    }
    #pragma unroll
    for (int d = 1; d <= 8; d <<= 1) {
        #pragma unroll
        for (int r = 0; r < 4; ++r) ps[r] += __shfl_xor(ps[r], d);
    }
    {
        float v = (lr == 0) ? ps[0] : (lr == 1) ? ps[1] : (lr == 2) ? ps[2] : ps[3];
        if (lr < 4) redsum[w][4 * lg + lr] = v;
    }
    __syncthreads();
    float il[4];
    #pragma unroll
    for (int r = 0; r < 4; ++r) {
        const float L = redsum[0][4 * lg + r] + redsum[1][4 * lg + r]
                      + redsum[2][4 * lg + r] + redsum[3][4 * lg + r];
        il[r] = 1.f / (L + 1e-8f);
    }
    const int d0 = w * DSL;
    f4 acc[12];
    #pragma unroll
    for (int t = 0; t < 12; ++t) acc[t] = f4{0.f, 0.f, 0.f, 0.f};
    {
        const _Float16* vtb = VT + ((size_t)b * DD + d0 + lr) * LKN + lg * 8;
        __builtin_amdgcn_s_setprio(1);
        #pragma unroll
        for (int ks2 = 0; ks2 < 16; ++ks2) {
            const half8 pa = *(const half8*)(pb + lr * 1024 + ((ks2 * 64 + lg * 16) ^ ((lr & 7) << 4)));
            #pragma unroll
            for (int nt = 0; nt < 12; ++nt) {
                const half8 vf = *(const half8*)(vtb + (size_t)nt * 16 * LKN + ks2 * 32);
                acc[nt] = __builtin_amdgcn_mfma_f32_16x16x32_f16(pa, vf, acc[nt], 0, 0, 0);
            }
        }
        __builtin_amdgcn_s_setprio(0);
    }
    #pragma unroll
    for (int nt = 0; nt < 12; ++nt) {
        #pragma unroll
        for (int r = 0; r < 4; ++r) {
            OUT[((size_t)(q0 + 4 * lg + r) * BB + b) * DD + d0 + nt * 16 + lr] = acc[nt][r] * il[r];
        }
    }
}

// ---------------------------------------------------------------------------
// Fallback B (f32 direct, no ws).
// ---------------------------------------------------------------------------
__global__ __launch_bounds__(256)
void coatt_flash_f32(const float* __restrict__ x1, const float* __restrict__ m1,
                     const float* __restrict__ x2, const float* __restrict__ m2,
                     float* __restrict__ o1, float* __restrict__ o2)
{
    const int i    = blockIdx.x;
    const int xcd  = i & 7;
    const int j    = i >> 3;
    const int pair = xcd * 8 + (j >> 5);
    const int qt   = j & 31;
    const int side = pair >> 5;
    const int b    = pair & 31;

    const float* __restrict__ Q   = side ? x2 : x1;
    const float* __restrict__ K   = side ? x1 : x2;
    const float* __restrict__ MK  = side ? m1 : m2;
    float* __restrict__       OUT = side ? o2 : o1;

    const int tid  = threadIdx.x;
    const int lane = tid & 63;
    const int w    = tid >> 6;
    const int lr   = lane & 15;
    const int lg   = lane >> 4;
    const int q0 = qt * 16;
    const int d0 = w * DSL;

    __shared__ float sred[4][16][36];
    __shared__ float mask_s[LKN];
    for (int t = tid; t < LKN; t += 256) mask_s[t] = MK[t * BB + b];

    half8 qf[6];
    {
        const float* qrow = Q + ((q0 + lr) * BB + b) * DD + d0 + lg * 8;
        #pragma unroll
        for (int ks = 0; ks < 6; ++ks) {
            f4 a = *(const f4*)(qrow + ks * 32);
            f4 c = *(const f4*)(qrow + ks * 32 + 4);
            qf[ks] = cvt8(a, c);
        }
    }
    f4 acc[12];
    #pragma unroll
    for (int t = 0; t < 12; ++t) acc[t] = f4{0.f, 0.f, 0.f, 0.f};
    float Mrun = -3.0e38f, Lrun = 0.f;
    for (int kt = 0; kt < 16; ++kt) {
        const int k0 = kt * 32;
        f4 s0 = {0.f,0.f,0.f,0.f}, s1 = {0.f,0.f,0.f,0.f};
        {
            const float* kb0 = K + ((k0 + lr) * BB + b) * DD + d0 + lg * 8;
            const float* kb1 = kb0 + 16 * BB * DD;
            #pragma unroll
            for (int ks = 0; ks < 6; ++ks) {
                f4 a0 = *(const f4*)(kb0 + ks * 32);
                f4 c0 = *(const f4*)(kb0 + ks * 32 + 4);
                s0 = __builtin_amdgcn_mfma_f32_16x16x32_f16(qf[ks], cvt8(a0, c0), s0, 0, 0, 0);
                f4 a1 = *(const f4*)(kb1 + ks * 32);
                f4 c1 = *(const f4*)(kb1 + ks * 32 + 4);
                s1 = __builtin_amdgcn_mfma_f32_16x16x32_f16(qf[ks], cvt8(a1, c1), s1, 0, 0, 0);
            }
        }
        __syncthreads();
        #pragma unroll
        for (int r = 0; r < 4; ++r) {
            sred[w][4 * lg + r][lr]      = s0[r];
            sred[w][4 * lg + r][16 + lr] = s1[r];
        }
        __syncthreads();
        f4 sa = {0.f,0.f,0.f,0.f}, sb = {0.f,0.f,0.f,0.f};
        #pragma unroll
        for (int ww = 0; ww < 4; ++ww) {
            sa += *(const f4*)&sred[ww][lr][lg * 8];
            sb += *(const f4*)&sred[ww][lr][lg * 8 + 4];
        }
        float tmax = fmaxf(fmaxf(fmaxf(sa[0], sa[1]), fmaxf(sa[2], sa[3])),
                           fmaxf(fmaxf(sb[0], sb[1]), fmaxf(sb[2], sb[3])));
        tmax = fmaxf(tmax, __shfl_xor(tmax, 16));
        tmax = fmaxf(tmax, __shfl_xor(tmax, 32));
        const float Mnew  = fmaxf(Mrun, tmax);
        const float scale = __expf(Mrun - Mnew);
        float p[8];
        float psum = 0.f;
        const float* mrow = &mask_s[k0 + lg * 8];
        #pragma unroll
        for (int t = 0; t < 4; ++t) { p[t]     = __expf(sa[t] - Mnew) * mrow[t];     psum += p[t]; }
        #pragma unroll
        for (int t = 0; t < 4; ++t) { p[4 + t] = __expf(sb[t] - Mnew) * mrow[4 + t]; psum += p[4 + t]; }
        psum += __shfl_xor(psum, 16);
        psum += __shfl_xor(psum, 32);
        Lrun = Lrun * scale + psum;
        Mrun = Mnew;
        H8 pf;
        pf.u[0] = pk2(p[0], p[1]); pf.u[1] = pk2(p[2], p[3]);
        pf.u[2] = pk2(p[4], p[5]); pf.u[3] = pk2(p[6], p[7]);
        float sc[4];
        #pragma unroll
        for (int r = 0; r < 4; ++r) sc[r] = __shfl(scale, (lane & 48) + 4 * lg + r);
        #pragma unroll
        for (int t = 0; t < 12; ++t) {
            acc[t][0] *= sc[0]; acc[t][1] *= sc[1];
            acc[t][2] *= sc[2]; acc[t][3] *= sc[3];
        }
        const float* vb = K + ((k0 + lg * 8) * BB + b) * DD + d0 + lr;
        #pragma unroll
        for (int nt = 0; nt < 12; ++nt) {
            const float* vp = vb + nt * 16;
            float vv[8];
            #pragma unroll
            for (int t = 0; t < 8; ++t) vv[t] = vp[t * BB * DD];
            H8 vf;
            vf.u[0] = pk2(vv[0], vv[1]); vf.u[1] = pk2(vv[2], vv[3]);
            vf.u[2] = pk2(vv[4], vv[5]); vf.u[3] = pk2(vv[6], vv[7]);
            acc[nt] = __builtin_amdgcn_mfma_f32_16x16x32_f16(pf.h, vf.h, acc[nt], 0, 0, 0);
        }
    }
    float il[4];
    {
        const float inv = 1.f / (Lrun + 1e-8f);
        #pragma unroll
        for (int r = 0; r < 4; ++r) il[r] = __shfl(inv, (lane & 48) + 4 * lg + r);
    }
    #pragma unroll
    for (int nt = 0; nt < 12; ++nt) {
        #pragma unroll
        for (int r = 0; r < 4; ++r) {
            OUT[((q0 + 4 * lg + r) * BB + b) * DD + d0 + nt * 16 + lr] = acc[nt][r] * il[r];
        }
    }
}

extern "C" void kernel_launch(void* const* d_in, const int* in_sizes, int n_in,
                              void* d_out, int out_size, void* d_ws, size_t ws_size,
                              hipStream_t stream) {
    (void)in_sizes; (void)n_in; (void)out_size;
    const float* x1 = (const float*)d_in[0];
    const float* m1 = (const float*)d_in[1];
    const float* x2 = (const float*)d_in[2];
    const float* m2 = (const float*)d_in[3];
    float* o1 = (float*)d_out;
    float* o2 = o1 + (size_t)LQ * BB * DD;

    const size_t ELEMS = (size_t)LQ * BB * DD;           // 12.58M
    const size_t SELEM = (size_t)BB * 512 * 512;         // 8.39M
    const size_t NEED1 = 4 * ELEMS * sizeof(_Float16);   // 100.7 MB (XF/XT)
    const size_t NEED2 = NEED1 + SELEM * sizeof(float);  // 134.2 MB

    if (ws_size >= NEED2) {
        _Float16* xf1 = (_Float16*)d_ws;
        _Float16* xf2 = xf1 + ELEMS;
        _Float16* xt1 = xf2 + ELEMS;
        _Float16* xt2 = xt1 + ELEMS;
        float*    S32 = (float*)(xt2 + ELEMS);           // dedicated 33.6 MB
        float*    ST32 = (float*)d_ws;                   // overlays XF (dead after gemm_s)
        prep_cvt_t<<<6144, 256, 0, stream>>>(x1, x2, xf1, xf2, xt1, xt2);
        gemm_s<<<512, 256, 0, stream>>>(xf1, xf2, S32);
        transpose_s<<<2048, 256, 0, stream>>>(S32, ST32);
        softmax_rows<<<1024, 256, 0, stream>>>(S32, ST32, m1, m2);
        pv_gemm<<<1024, 256, 0, stream>>>(S32, ST32, xt1, xt2, o1, o2);
    } else if (ws_size >= NEED1) {
        _Float16* xf1 = (_Float16*)d_ws;
        _Float16* xf2 = xf1 + ELEMS;
        _Float16* xt1 = xf2 + ELEMS;
        _Float16* xt2 = xt1 + ELEMS;
        prep_cvt_t<<<6144, 256, 0, stream>>>(x1, x2, xf1, xf2, xt1, xt2);
        coatt_flash_f16<<<2048, 256, 0, stream>>>(xf1, xf2, xt1, xt2, m1, m2, o1, o2);
    } else {
        coatt_flash_f32<<<2048, 256, 0, stream>>>(x1, m1, x2, m2, o1, o2);
    }
}

// Round 13
// 173.565 us; speedup vs baseline: 1.2751x; 1.0330x over previous
//
#include <hip/hip_runtime.h>

// Problem constants
#define LQ  512
#define LKN 512
#define BB  32
#define DD  768
#define DSL (DD / 4)

typedef float    f4     __attribute__((ext_vector_type(4)));
typedef _Float16 half8  __attribute__((ext_vector_type(8)));
typedef _Float16 half4  __attribute__((ext_vector_type(4)));
typedef __fp16   fp16x2 __attribute__((ext_vector_type(2)));

union H8 { half8 h; unsigned int u[4]; };

__device__ __forceinline__ unsigned int pk2(float a, float b) {
    union { fp16x2 h; unsigned int u; } c;
    c.h = __builtin_amdgcn_cvt_pkrtz(a, b);
    return c.u;
}
__device__ __forceinline__ half8 cvt8(f4 a, f4 b) {
    H8 r;
    r.u[0] = pk2(a[0], a[1]); r.u[1] = pk2(a[2], a[3]);
    r.u[2] = pk2(b[0], b[1]); r.u[3] = pk2(b[2], b[3]);
    return r.h;
}

// Forced-in-flight global load: volatile asm pins the destination registers
// and cannot be sunk to the use site by the scheduler.
__device__ __forceinline__ void gload16(half8& dst, const _Float16* p) {
    asm volatile("global_load_dwordx4 %0, %1, off" : "=v"(dst) : "v"(p));
}

// ---------------------------------------------------------------------------
// Prep: XF fragment-packed f16; XT transposed f16 [B][D][L].
// ---------------------------------------------------------------------------
__global__ __launch_bounds__(256)
void prep_cvt_t(const float* __restrict__ x1, const float* __restrict__ x2,
                _Float16* __restrict__ xf1, _Float16* __restrict__ xf2,
                _Float16* __restrict__ xt1, _Float16* __restrict__ xt2)
{
    const int bi   = blockIdx.x;            // 6144
    const int side = bi / 3072;
    const int rem  = bi % 3072;
    const int b    = rem / 96;
    const int rem2 = rem % 96;
    const int l0   = (rem2 / 12) * 64;
    const int d0   = (rem2 % 12) * 64;

    const float* __restrict__ X  = side ? x2  : x1;
    _Float16* __restrict__    XF = side ? xf2 : xf1;
    _Float16* __restrict__    XT = side ? xt2 : xt1;

    __shared__ _Float16 T[64][72];

    const int tid = threadIdx.x;
    {
        const int r  = tid >> 4;
        const int c4 = (tid & 15) * 4;
        for (int rr = r; rr < 64; rr += 16) {
            const size_t idx = ((size_t)(l0 + rr) * BB + b) * DD + d0 + c4;
            f4 v = *(const f4*)(X + idx);
            half4 h;
            h[0] = (_Float16)v[0]; h[1] = (_Float16)v[1];
            h[2] = (_Float16)v[2]; h[3] = (_Float16)v[3];
            *(half4*)&T[rr][c4] = h;
        }
    }
    __syncthreads();
    {
        const int d  = tid >> 2;
        const int lq = (tid & 3) * 16;
        half8 a, c;
        #pragma unroll
        for (int i = 0; i < 8; ++i) { a[i] = T[lq + i][d]; c[i] = T[lq + 8 + i][d]; }
        _Float16* p = XT + ((size_t)b * DD + d0 + d) * LKN + l0 + lq;
        *(half8*)p       = a;
        *(half8*)(p + 8) = c;
    }
    #pragma unroll
    for (int c = tid; c < 512; c += 256) {
        const int t16l = c >> 7;
        const int ksl  = (c >> 6) & 1;
        const int ln   = c & 63;
        half8 v = *(const half8*)&T[t16l * 16 + (ln & 15)][ksl * 32 + (ln >> 4) * 8];
        const size_t t16g = (size_t)(l0 >> 4) + t16l;
        const size_t ksg  = (size_t)(d0 >> 5) + ksl;
        *(half8*)(XF + (((size_t)b * 32 + t16g) * 24 + ksg) * 512 + ln * 8) = v;
    }
}

// ---------------------------------------------------------------------------
// Stage 1: S = x1.x2^T (f32), 128x128 tile/block, no LDS.
// ---------------------------------------------------------------------------
__global__ __launch_bounds__(256, 3)
void gemm_s(const _Float16* __restrict__ xf1, const _Float16* __restrict__ xf2,
            float* __restrict__ S)
{
    const int i   = blockIdx.x;            // 512
    const int xcd = i & 7;
    const int j   = i >> 3;                // 0..63
    const int t   = j & 15;                // tile fastest
    const int b   = xcd * 4 + (j >> 4);    // b slowest
    const int lt  = t >> 2, mt = t & 3;
    const int l0b = lt * 128, m0b = mt * 128;

    const int tid  = threadIdx.x;
    const int lane = tid & 63;
    const int w    = tid >> 6;
    const int wl   = w >> 1, wm = w & 1;
    const int lr   = lane & 15;
    const int lg   = lane >> 4;

    f4 acc[16];
    #pragma unroll
    for (int t2 = 0; t2 < 16; ++t2) acc[t2] = f4{0.f, 0.f, 0.f, 0.f};

    {
        const _Float16* ab = xf1 + (((size_t)b * 32 + lt * 8 + wl * 4) * 24) * 512 + lane * 8;
        const _Float16* bb = xf2 + (((size_t)b * 32 + mt * 8 + wm * 4) * 24) * 512 + lane * 8;
        __builtin_amdgcn_s_setprio(1);
        #pragma unroll
        for (int ks = 0; ks < 24; ++ks) {
            half8 aF[4], bF[4];
            #pragma unroll
            for (int q = 0; q < 4; ++q) {
                aF[q] = *(const half8*)(ab + ((size_t)q * 24 + ks) * 512);
                bF[q] = *(const half8*)(bb + ((size_t)q * 24 + ks) * 512);
            }
            #pragma unroll
            for (int q = 0; q < 4; ++q)
                #pragma unroll
                for (int p = 0; p < 4; ++p)
                    acc[q * 4 + p] = __builtin_amdgcn_mfma_f32_16x16x32_f16(aF[q], bF[p], acc[q * 4 + p], 0, 0, 0);
        }
        __builtin_amdgcn_s_setprio(0);
    }

    {
        float* srow = S + ((size_t)b * 512 + l0b + wl * 64) * 512 + m0b + wm * 64;
        #pragma unroll
        for (int q = 0; q < 4; ++q)
            #pragma unroll
            for (int p = 0; p < 4; ++p)
                #pragma unroll
                for (int r = 0; r < 4; ++r)
                    srow[(size_t)(q * 16 + 4 * lg + r) * 512 + p * 16 + lr] = acc[q * 4 + p][r];
    }
}

// ---------------------------------------------------------------------------
// Stage 1b: ST = S^T (f32), 64x64 tiles via LDS (ST overlays dead XF region).
// ---------------------------------------------------------------------------
__global__ __launch_bounds__(256)
void transpose_s(const float* __restrict__ S, float* __restrict__ ST)
{
    const int i   = blockIdx.x;            // 2048
    const int xcd = i & 7;
    const int j   = i >> 3;                // 0..255
    const int t   = j & 63;
    const int b   = xcd * 4 + (j >> 6);
    const int lt  = t >> 3, mt = t & 7;

    __shared__ float T[64][65];

    const int tid = threadIdx.x;
    const int r   = tid >> 2;
    const int c0  = (tid & 3) * 16;

    {
        const float* src = S + ((size_t)b * 512 + lt * 64 + r) * 512 + mt * 64 + c0;
        #pragma unroll
        for (int k = 0; k < 4; ++k) {
            f4 v = *(const f4*)(src + k * 4);
            T[r][c0 + k * 4 + 0] = v[0]; T[r][c0 + k * 4 + 1] = v[1];
            T[r][c0 + k * 4 + 2] = v[2]; T[r][c0 + k * 4 + 3] = v[3];
        }
    }
    __syncthreads();
    {
        float* dst = ST + ((size_t)b * 512 + mt * 64 + r) * 512 + lt * 64 + c0;
        #pragma unroll
        for (int k = 0; k < 4; ++k) {
            f4 v;
            v[0] = T[c0 + k * 4 + 0][r]; v[1] = T[c0 + k * 4 + 1][r];
            v[2] = T[c0 + k * 4 + 2][r]; v[3] = T[c0 + k * 4 + 3][r];
            *(f4*)(dst + k * 4) = v;
        }
    }
}

// ---------------------------------------------------------------------------
// Stage 2: row softmax on f32 scores; writes normalized P f16 in-place into
// the first half of each f32 row slot.
// ---------------------------------------------------------------------------
__global__ __launch_bounds__(256)
void softmax_rows(float* __restrict__ S32, float* __restrict__ ST32,
                  const float* __restrict__ m1, const float* __restrict__ m2)
{
    const int bi   = blockIdx.x;           // 1024
    const int side = bi >> 9;
    const int idx  = bi & 511;
    const int b    = idx >> 4;
    const int rt   = idx & 15;

    float* __restrict__ P = side ? ST32 : S32;
    const float* __restrict__ MK = side ? m1 : m2;

    const int tid  = threadIdx.x;
    const int lane = tid & 63;
    const int w    = tid >> 6;

    __shared__ float mask_s[LKN];
    mask_s[tid] = MK[tid * BB + b];
    mask_s[tid + 256] = MK[(tid + 256) * BB + b];
    __syncthreads();

    float mk[8];
    #pragma unroll
    for (int j = 0; j < 8; ++j) mk[j] = mask_s[lane * 8 + j];

    for (int rr = 0; rr < 8; ++rr) {
        const int row = rt * 32 + w * 8 + rr;
        float* rp = P + ((size_t)b * 512 + row) * 512 + lane * 8;
        const f4 a = *(const f4*)rp;
        const f4 c = *(const f4*)(rp + 4);
        float f[8] = {a[0], a[1], a[2], a[3], c[0], c[1], c[2], c[3]};
        float m = fmaxf(fmaxf(fmaxf(f[0], f[1]), fmaxf(f[2], f[3])),
                        fmaxf(fmaxf(f[4], f[5]), fmaxf(f[6], f[7])));
        #pragma unroll
        for (int d = 1; d <= 32; d <<= 1) m = fmaxf(m, __shfl_xor(m, d));
        float e[8], s = 0.f;
        #pragma unroll
        for (int j = 0; j < 8; ++j) { e[j] = __expf(f[j] - m) * mk[j]; s += e[j]; }
        #pragma unroll
        for (int d = 1; d <= 32; d <<= 1) s += __shfl_xor(s, d);
        const float inv = 1.f / (s + 1e-8f);
        H8 o;
        o.u[0] = pk2(e[0] * inv, e[1] * inv); o.u[1] = pk2(e[2] * inv, e[3] * inv);
        o.u[2] = pk2(e[4] * inv, e[5] * inv); o.u[3] = pk2(e[6] * inv, e[7] * inv);
        *(half8*)((_Float16*)(P + ((size_t)b * 512 + row) * 512) + lane * 8) = o.h;
    }
}

// ---------------------------------------------------------------------------
// Stage 3: OUT = P.V — 64-row P tiles (64 KB LDS), 1024 blocks.
// V-fragments loaded via volatile-asm global_load_dwordx4 in 24-wide batches
// + explicit s_waitcnt vmcnt(0) + sched_barrier: forces 24-deep MLP the
// compiler cannot undo (r11/r12 showed C-level batching gets rescheduled).
// ---------------------------------------------------------------------------
__global__ __launch_bounds__(256, 2)
void pv_gemm(const float* __restrict__ S32, const float* __restrict__ ST32,
             const _Float16* __restrict__ xt1, const _Float16* __restrict__ xt2,
             float* __restrict__ o1, float* __restrict__ o2)
{
    const int i    = blockIdx.x;           // 1024
    const int xcd  = i & 7;
    const int j    = i >> 3;               // 0..127
    const int lt   = j & 7;                // fastest: shares V slice
    const int dh   = (j >> 3) & 1;
    const int side = (j >> 4) & 1;
    const int b    = xcd * 4 + (j >> 5);   // slowest
    const int l0   = lt * 64;
    const int dblk = dh * 384;

    const float* __restrict__ P32   = side ? ST32 : S32;
    const _Float16* __restrict__ VT = side ? xt1 : xt2;
    float* __restrict__ OUT         = side ? o2 : o1;

    const int tid  = threadIdx.x;
    const int lane = tid & 63;
    const int w    = tid >> 6;
    const int lr   = lane & 15;
    const int lg   = lane >> 4;

    __shared__ char plds[64 * 1024];       // 64 KB, byte = row*1024 + (col2 ^ ((row&7)<<4))

    // stage P-tile (64 rows x 512 f16 in f32 row slots), swizzled on LDS write
    {
        const int row = tid & 63;
        const int seg = tid >> 6;          // 0..3
        const _Float16* src = (const _Float16*)(P32 + ((size_t)b * 512 + l0 + row) * 512) + seg * 128;
        #pragma unroll
        for (int it = 0; it < 16; ++it) {
            const half8 v = *(const half8*)(src + it * 8);
            const int byo = (seg * 256 + it * 16) ^ ((row & 7) << 4);
            *(half8*)(plds + row * 1024 + byo) = v;
        }
    }
    __syncthreads();

    f4 acc[24];                            // [q(0..3)][nt(0..5)] -> AGPRs
    #pragma unroll
    for (int t = 0; t < 24; ++t) acc[t] = f4{0.f, 0.f, 0.f, 0.f};

    {
        const _Float16* vtb = VT + ((size_t)b * DD + dblk + w * 96 + lr) * LKN + lg * 8;
        #pragma unroll
        for (int c = 0; c < 4; ++c) {      // 4 chunks x 4 ks2
            half8 vf[24];
            // issue 24 independent loads; volatile asm pins them in flight
            #pragma unroll
            for (int k2 = 0; k2 < 4; ++k2)
                #pragma unroll
                for (int nt = 0; nt < 6; ++nt)
                    gload16(vf[k2 * 6 + nt], vtb + (size_t)nt * 16 * LKN + (c * 4 + k2) * 32);
            asm volatile("s_waitcnt vmcnt(0)" ::: "memory");
            __builtin_amdgcn_sched_barrier(0);   // rule #18: no MFMA hoisted above the wait
            __builtin_amdgcn_s_setprio(1);
            #pragma unroll
            for (int k2 = 0; k2 < 4; ++k2) {
                const int ks2 = c * 4 + k2;
                half8 pa[4];
                #pragma unroll
                for (int q = 0; q < 4; ++q) {
                    const int row = q * 16 + lr;
                    pa[q] = *(const half8*)(plds + row * 1024 + ((ks2 * 64 + lg * 16) ^ ((row & 7) << 4)));
                }
                #pragma unroll
                for (int nt = 0; nt < 6; ++nt) {
                    #pragma unroll
                    for (int q = 0; q < 4; ++q)
                        acc[q * 6 + nt] = __builtin_amdgcn_mfma_f32_16x16x32_f16(pa[q], vf[k2 * 6 + nt], acc[q * 6 + nt], 0, 0, 0);
                }
            }
            __builtin_amdgcn_s_setprio(0);
        }
    }

    #pragma unroll
    for (int q = 0; q < 4; ++q)
        #pragma unroll
        for (int nt = 0; nt < 6; ++nt)
            #pragma unroll
            for (int r = 0; r < 4; ++r)
                OUT[((size_t)(l0 + q * 16 + 4 * lg + r) * BB + b) * DD + dblk + w * 96 + nt * 16 + lr]
                    = acc[q * 6 + nt][r];
}

// ---------------------------------------------------------------------------
// Fallback A (r7 fused kernel, needs 96 MiB ws).
// ---------------------------------------------------------------------------
__global__ __launch_bounds__(256, 3)
void coatt_flash_f16(const _Float16* __restrict__ xf1, const _Float16* __restrict__ xf2,
                     const _Float16* __restrict__ xt1, const _Float16* __restrict__ xt2,
                     const float* __restrict__ m1, const float* __restrict__ m2,
                     float* __restrict__ o1, float* __restrict__ o2)
{
    const int i    = blockIdx.x;
    const int xcd  = i & 7;
    const int j    = i >> 3;
    const int pair = xcd * 8 + (j >> 5);
    const int qt   = j & 31;
    const int side = pair >> 5;
    const int b    = pair & 31;

    const _Float16* __restrict__ QF = side ? xf2 : xf1;
    const _Float16* __restrict__ KF = side ? xf1 : xf2;
    const _Float16* __restrict__ VT = side ? xt1 : xt2;
    const float* __restrict__    MK = side ? m1  : m2;
    float* __restrict__         OUT = side ? o2  : o1;

    const int tid  = threadIdx.x;
    const int lane = tid & 63;
    const int w    = tid >> 6;
    const int lr   = lane & 15;
    const int lg   = lane >> 4;
    const int q0 = qt * 16;

    __shared__ _Float16 plds_h[16 * LKN];
    __shared__ float redmax[4][16];
    __shared__ float redsum[4][16];
    __shared__ float mask_s[LKN];
    char* const pb = (char*)plds_h;

    for (int t = tid; t < LKN; t += 256) mask_s[t] = MK[t * BB + b];

    f4 sacc[8];
    #pragma unroll
    for (int t = 0; t < 8; ++t) sacc[t] = f4{0.f, 0.f, 0.f, 0.f};
    {
        const _Float16* qbase = QF + (((size_t)b * 32 + qt) * 24) * 512 + lane * 8;
        const _Float16* kbase = KF + (((size_t)b * 32 + w * 8) * 24) * 512 + lane * 8;
        #pragma unroll
        for (int half = 0; half < 2; ++half) {
            half8 qf[12];
            #pragma unroll
            for (int ks = 0; ks < 12; ++ks) qf[ks] = *(const half8*)(qbase + (half * 12 + ks) * 512);
            __builtin_amdgcn_s_setprio(1);
            #pragma unroll
            for (int ks = 0; ks < 12; ++ks) {
                #pragma unroll
                for (int kt = 0; kt < 8; ++kt) {
                    const half8 kf = *(const half8*)(kbase + ((size_t)kt * 24 + half * 12 + ks) * 512);
                    sacc[kt] = __builtin_amdgcn_mfma_f32_16x16x32_f16(qf[ks], kf, sacc[kt], 0, 0, 0);
                }
            }
            __builtin_amdgcn_s_setprio(0);
        }
    }

    float rm[4];
    #pragma unroll
    for (int r = 0; r < 4; ++r) {
        float m0 = fmaxf(fmaxf(sacc[0][r], sacc[1][r]), fmaxf(sacc[2][r], sacc[3][r]));
        float m1_ = fmaxf(fmaxf(sacc[4][r], sacc[5][r]), fmaxf(sacc[6][r], sacc[7][r]));
        rm[r] = fmaxf(m0, m1_);
    }
    #pragma unroll
    for (int d = 1; d <= 8; d <<= 1) {
        #pragma unroll
        for (int r = 0; r < 4; ++r) rm[r] = fmaxf(rm[r], __shfl_xor(rm[r], d));
    }
    {
        float v = (lr == 0) ? rm[0] : (lr == 1) ? rm[1] : (lr == 2) ? rm[2] : rm[3];
        if (lr < 4) redmax[w][4 * lg + lr] = v;
    }
    __syncthreads();
    float M[4];
    #pragma unroll
    for (int r = 0; r < 4; ++r)
        M[r] = fmaxf(fmaxf(redmax[0][4 * lg + r], redmax[1][4 * lg + r]),
                     fmaxf(redmax[2][4 * lg + r], redmax[3][4 * lg + r]));
    float mval[8];
    #pragma unroll
    for (int kt = 0; kt < 8; ++kt) mval[kt] = mask_s[w * 128 + kt * 16 + lr];
    float ps[4] = {0.f, 0.f, 0.f, 0.f};
    #pragma unroll
    for (int kt = 0; kt < 8; ++kt) {
        #pragma unroll
        for (int r = 0; r < 4; ++r) {
            const float p = __expf(sacc[kt][r] - M[r]) * mval[kt];
            ps[r] += p;
            const int row = 4 * lg + r;
            *(_Float16*)(pb + row * 1024 + (((w * 128 + kt * 16 + lr) * 2) ^ ((row & 7) << 4))) = (_Float16)p;
        }
    }
    #pragma unroll
    for (int d = 1; d <= 8; d <<= 1) {
        #pragma unroll
        for (int r = 0; r < 4; ++r) ps[r] += __shfl_xor(ps[r], d);
    }
    {
        float v = (lr == 0) ? ps[0] : (lr == 1) ? ps[1] : (lr == 2) ? ps[2] : ps[3];
        if (lr < 4) redsum[w][4 * lg + lr] = v;
    }
    __syncthreads();
    float il[4];
    #pragma unroll
    for (int r = 0; r < 4; ++r) {
        const float L = redsum[0][4 * lg + r] + redsum[1][4 * lg + r]
                      + redsum[2][4 * lg + r] + redsum[3][4 * lg + r];
        il[r] = 1.f / (L + 1e-8f);
    }
    const int d0 = w * DSL;
    f4 acc[12];
    #pragma unroll
    for (int t = 0; t < 12; ++t) acc[t] = f4{0.f, 0.f, 0.f, 0.f};
    {
        const _Float16* vtb = VT + ((size_t)b * DD + d0 + lr) * LKN + lg * 8;
        __builtin_amdgcn_s_setprio(1);
        #pragma unroll
        for (int ks2 = 0; ks2 < 16; ++ks2) {
            const half8 pa = *(const half8*)(pb + lr * 1024 + ((ks2 * 64 + lg * 16) ^ ((lr & 7) << 4)));
            #pragma unroll
            for (int nt = 0; nt < 12; ++nt) {
                const half8 vf = *(const half8*)(vtb + (size_t)nt * 16 * LKN + ks2 * 32);
                acc[nt] = __builtin_amdgcn_mfma_f32_16x16x32_f16(pa, vf, acc[nt], 0, 0, 0);
            }
        }
        __builtin_amdgcn_s_setprio(0);
    }
    #pragma unroll
    for (int nt = 0; nt < 12; ++nt) {
        #pragma unroll
        for (int r = 0; r < 4; ++r) {
            OUT[((size_t)(q0 + 4 * lg + r) * BB + b) * DD + d0 + nt * 16 + lr] = acc[nt][r] * il[r];
        }
    }
}

// ---------------------------------------------------------------------------
// Fallback B (f32 direct, no ws).
// ---------------------------------------------------------------------------
__global__ __launch_bounds__(256)
void coatt_flash_f32(const float* __restrict__ x1, const float* __restrict__ m1,
                     const float* __restrict__ x2, const float* __restrict__ m2,
                     float* __restrict__ o1, float* __restrict__ o2)
{
    const int i    = blockIdx.x;
    const int xcd  = i & 7;
    const int j    = i >> 3;
    const int pair = xcd * 8 + (j >> 5);
    const int qt   = j & 31;
    const int side = pair >> 5;
    const int b    = pair & 31;

    const float* __restrict__ Q   = side ? x2 : x1;
    const float* __restrict__ K   = side ? x1 : x2;
    const float* __restrict__ MK  = side ? m1 : m2;
    float* __restrict__       OUT = side ? o2 : o1;

    const int tid  = threadIdx.x;
    const int lane = tid & 63;
    const int w    = tid >> 6;
    const int lr   = lane & 15;
    const int lg   = lane >> 4;
    const int q0 = qt * 16;
    const int d0 = w * DSL;

    __shared__ float sred[4][16][36];
    __shared__ float mask_s[LKN];
    for (int t = tid; t < LKN; t += 256) mask_s[t] = MK[t * BB + b];

    half8 qf[6];
    {
        const float* qrow = Q + ((q0 + lr) * BB + b) * DD + d0 + lg * 8;
        #pragma unroll
        for (int ks = 0; ks < 6; ++ks) {
            f4 a = *(const f4*)(qrow + ks * 32);
            f4 c = *(const f4*)(qrow + ks * 32 + 4);
            qf[ks] = cvt8(a, c);
        }
    }
    f4 acc[12];
    #pragma unroll
    for (int t = 0; t < 12; ++t) acc[t] = f4{0.f, 0.f, 0.f, 0.f};
    float Mrun = -3.0e38f, Lrun = 0.f;
    for (int kt = 0; kt < 16; ++kt) {
        const int k0 = kt * 32;
        f4 s0 = {0.f,0.f,0.f,0.f}, s1 = {0.f,0.f,0.f,0.f};
        {
            const float* kb0 = K + ((k0 + lr) * BB + b) * DD + d0 + lg * 8;
            const float* kb1 = kb0 + 16 * BB * DD;
            #pragma unroll
            for (int ks = 0; ks < 6; ++ks) {
                f4 a0 = *(const f4*)(kb0 + ks * 32);
                f4 c0 = *(const f4*)(kb0 + ks * 32 + 4);
                s0 = __builtin_amdgcn_mfma_f32_16x16x32_f16(qf[ks], cvt8(a0, c0), s0, 0, 0, 0);
                f4 a1 = *(const f4*)(kb1 + ks * 32);
                f4 c1 = *(const f4*)(kb1 + ks * 32 + 4);
                s1 = __builtin_amdgcn_mfma_f32_16x16x32_f16(qf[ks], cvt8(a1, c1), s1, 0, 0, 0);
            }
        }
        __syncthreads();
        #pragma unroll
        for (int r = 0; r < 4; ++r) {
            sred[w][4 * lg + r][lr]      = s0[r];
            sred[w][4 * lg + r][16 + lr] = s1[r];
        }
        __syncthreads();
        f4 sa = {0.f,0.f,0.f,0.f}, sb = {0.f,0.f,0.f,0.f};
        #pragma unroll
        for (int ww = 0; ww < 4; ++ww) {
            sa += *(const f4*)&sred[ww][lr][lg * 8];
            sb += *(const f4*)&sred[ww][lr][lg * 8 + 4];
        }
        float tmax = fmaxf(fmaxf(fmaxf(sa[0], sa[1]), fmaxf(sa[2], sa[3])),
                           fmaxf(fmaxf(sb[0], sb[1]), fmaxf(sb[2], sb[3])));
        tmax = fmaxf(tmax, __shfl_xor(tmax, 16));
        tmax = fmaxf(tmax, __shfl_xor(tmax, 32));
        const float Mnew  = fmaxf(Mrun, tmax);
        const float scale = __expf(Mrun - Mnew);
        float p[8];
        float psum = 0.f;
        const float* mrow = &mask_s[k0 + lg * 8];
        #pragma unroll
        for (int t = 0; t < 4; ++t) { p[t]     = __expf(sa[t] - Mnew) * mrow[t];     psum += p[t]; }
        #pragma unroll
        for (int t = 0; t < 4; ++t) { p[4 + t] = __expf(sb[t] - Mnew) * mrow[4 + t]; psum += p[4 + t]; }
        psum += __shfl_xor(psum, 16);
        psum += __shfl_xor(psum, 32);
        Lrun = Lrun * scale + psum;
        Mrun = Mnew;
        H8 pf;
        pf.u[0] = pk2(p[0], p[1]); pf.u[1] = pk2(p[2], p[3]);
        pf.u[2] = pk2(p[4], p[5]); pf.u[3] = pk2(p[6], p[7]);
        float sc[4];
        #pragma unroll
        for (int r = 0; r < 4; ++r) sc[r] = __shfl(scale, (lane & 48) + 4 * lg + r);
        #pragma unroll
        for (int t = 0; t < 12; ++t) {
            acc[t][0] *= sc[0]; acc[t][1] *= sc[1];
            acc[t][2] *= sc[2]; acc[t][3] *= sc[3];
        }
        const float* vb = K + ((k0 + lg * 8) * BB + b) * DD + d0 + lr;
        #pragma unroll
        for (int nt = 0; nt < 12; ++nt) {
            const float* vp = vb + nt * 16;
            float vv[8];
            #pragma unroll
            for (int t = 0; t < 8; ++t) vv[t] = vp[t * BB * DD];
            H8 vf;
            vf.u[0] = pk2(vv[0], vv[1]); vf.u[1] = pk2(vv[2], vv[3]);
            vf.u[2] = pk2(vv[4], vv[5]); vf.u[3] = pk2(vv[6], vv[7]);
            acc[nt] = __builtin_amdgcn_mfma_f32_16x16x32_f16(pf.h, vf.h, acc[nt], 0, 0, 0);
        }
    }
    float il[4];
    {
        const float inv = 1.f / (Lrun + 1e-8f);
        #pragma unroll
        for (int r = 0; r < 4; ++r) il[r] = __shfl(inv, (lane & 48) + 4 * lg + r);
    }
    #pragma unroll
    for (int nt = 0; nt < 12; ++nt) {
        #pragma unroll
        for (int r = 0; r < 4; ++r) {
            OUT[((q0 + 4 * lg + r) * BB + b) * DD + d0 + nt * 16 + lr] = acc[nt][r] * il[r];
        }
    }
}

extern "C" void kernel_launch(void* const* d_in, const int* in_sizes, int n_in,
                              void* d_out, int out_size, void* d_ws, size_t ws_size,
                              hipStream_t stream) {
    (void)in_sizes; (void)n_in; (void)out_size;
    const float* x1 = (const float*)d_in[0];
    const float* m1 = (const float*)d_in[1];
    const float* x2 = (const float*)d_in[2];
    const float* m2 = (const float*)d_in[3];
    float* o1 = (float*)d_out;
    float* o2 = o1 + (size_t)LQ * BB * DD;

    const size_t ELEMS = (size_t)LQ * BB * DD;           // 12.58M
    const size_t SELEM = (size_t)BB * 512 * 512;         // 8.39M
    const size_t NEED1 = 4 * ELEMS * sizeof(_Float16);   // 100.7 MB (XF/XT)
    const size_t NEED2 = NEED1 + SELEM * sizeof(float);  // 134.2 MB

    if (ws_size >= NEED2) {
        _Float16* xf1 = (_Float16*)d_ws;
        _Float16* xf2 = xf1 + ELEMS;
        _Float16* xt1 = xf2 + ELEMS;
        _Float16* xt2 = xt1 + ELEMS;
        float*    S32 = (float*)(xt2 + ELEMS);           // dedicated 33.6 MB
        float*    ST32 = (float*)d_ws;                   // overlays XF (dead after gemm_s)
        prep_cvt_t<<<6144, 256, 0, stream>>>(x1, x2, xf1, xf2, xt1, xt2);
        gemm_s<<<512, 256, 0, stream>>>(xf1, xf2, S32);
        transpose_s<<<2048, 256, 0, stream>>>(S32, ST32);
        softmax_rows<<<1024, 256, 0, stream>>>(S32, ST32, m1, m2);
        pv_gemm<<<1024, 256, 0, stream>>>(S32, ST32, xt1, xt2, o1, o2);
    } else if (ws_size >= NEED1) {
        _Float16* xf1 = (_Float16*)d_ws;
        _Float16* xf2 = xf1 + ELEMS;
        _Float16* xt1 = xf2 + ELEMS;
        _Float16* xt2 = xt1 + ELEMS;
        prep_cvt_t<<<6144, 256, 0, stream>>>(x1, x2, xf1, xf2, xt1, xt2);
        coatt_flash_f16<<<2048, 256, 0, stream>>>(xf1, xf2, xt1, xt2, m1, m2, o1, o2);
    } else {
        coatt_flash_f32<<<2048, 256, 0, stream>>>(x1, m1, x2, m2, o1, o2);
    }
}

// Round 14
// 159.413 us; speedup vs baseline: 1.3883x; 1.0888x over previous
//
#include <hip/hip_runtime.h>

// Problem constants
#define LQ  512
#define LKN 512
#define BB  32
#define DD  768
#define DSL (DD / 4)

typedef float    f4     __attribute__((ext_vector_type(4)));
typedef _Float16 half8  __attribute__((ext_vector_type(8)));
typedef _Float16 half4  __attribute__((ext_vector_type(4)));
typedef __fp16   fp16x2 __attribute__((ext_vector_type(2)));

union H8 { half8 h; unsigned int u[4]; };

__device__ __forceinline__ unsigned int pk2(float a, float b) {
    union { fp16x2 h; unsigned int u; } c;
    c.h = __builtin_amdgcn_cvt_pkrtz(a, b);
    return c.u;
}
__device__ __forceinline__ half8 cvt8(f4 a, f4 b) {
    H8 r;
    r.u[0] = pk2(a[0], a[1]); r.u[1] = pk2(a[2], a[3]);
    r.u[2] = pk2(b[0], b[1]); r.u[3] = pk2(b[2], b[3]);
    return r.h;
}

// Forced-in-flight global load (volatile asm cannot be sunk by the scheduler).
__device__ __forceinline__ void gload16(half8& dst, const _Float16* p) {
    asm volatile("global_load_dwordx4 %0, %1, off" : "=v"(dst) : "v"(p));
}

// ---------------------------------------------------------------------------
// Prep: XF = A/B-fragment-packed X (for QK^T GEMM);
//       XV = B-fragment-packed V (for PV GEMM), replacing the old XT:
//       XV[((b*48 + dt)*16 + ks2)*512 + ln*8 + j] = X[ks2*32+(ln>>4)*8+j][b][dt*16+(ln&15)]
// ---------------------------------------------------------------------------
__global__ __launch_bounds__(256)
void prep_cvt_t(const float* __restrict__ x1, const float* __restrict__ x2,
                _Float16* __restrict__ xf1, _Float16* __restrict__ xf2,
                _Float16* __restrict__ xv1, _Float16* __restrict__ xv2)
{
    const int bi   = blockIdx.x;            // 6144
    const int side = bi / 3072;
    const int rem  = bi % 3072;
    const int b    = rem / 96;
    const int rem2 = rem % 96;
    const int l0   = (rem2 / 12) * 64;
    const int d0   = (rem2 % 12) * 64;

    const float* __restrict__ X  = side ? x2  : x1;
    _Float16* __restrict__    XF = side ? xf2 : xf1;
    _Float16* __restrict__    XV = side ? xv2 : xv1;

    __shared__ _Float16 T[64][72];

    const int tid = threadIdx.x;
    {
        const int r  = tid >> 4;
        const int c4 = (tid & 15) * 4;
        for (int rr = r; rr < 64; rr += 16) {
            const size_t idx = ((size_t)(l0 + rr) * BB + b) * DD + d0 + c4;
            f4 v = *(const f4*)(X + idx);
            half4 h;
            h[0] = (_Float16)v[0]; h[1] = (_Float16)v[1];
            h[2] = (_Float16)v[2]; h[3] = (_Float16)v[3];
            *(half4*)&T[rr][c4] = h;
        }
    }
    __syncthreads();
    // XF: fragment-packed (A/B operand for QK^T)
    #pragma unroll
    for (int c = tid; c < 512; c += 256) {
        const int t16l = c >> 7;
        const int ksl  = (c >> 6) & 1;
        const int ln   = c & 63;
        half8 v = *(const half8*)&T[t16l * 16 + (ln & 15)][ksl * 32 + (ln >> 4) * 8];
        const size_t t16g = (size_t)(l0 >> 4) + t16l;
        const size_t ksg  = (size_t)(d0 >> 5) + ksl;
        *(half8*)(XF + (((size_t)b * 32 + t16g) * 24 + ksg) * 512 + ln * 8) = v;
    }
    // XV: B-fragment-packed V (k = l dimension, n = d dimension)
    #pragma unroll
    for (int c = tid; c < 512; c += 256) {
        const int dtl  = c >> 7;            // 0..3 (local d-tile)
        const int ks2l = (c >> 6) & 1;      // 0..1 (local k-block of 32)
        const int ln   = c & 63;
        half8 v;
        #pragma unroll
        for (int jj = 0; jj < 8; ++jj)
            v[jj] = T[ks2l * 32 + (ln >> 4) * 8 + jj][dtl * 16 + (ln & 15)];
        *(half8*)(XV + (((size_t)b * 48 + (d0 >> 4) + dtl) * 16 + (l0 >> 5) + ks2l) * 512 + ln * 8) = v;
    }
}

// ---------------------------------------------------------------------------
// Stage 1: S = x1.x2^T (f32), 128x128 tile/block, no LDS.
// ---------------------------------------------------------------------------
__global__ __launch_bounds__(256, 3)
void gemm_s(const _Float16* __restrict__ xf1, const _Float16* __restrict__ xf2,
            float* __restrict__ S)
{
    const int i   = blockIdx.x;            // 512
    const int xcd = i & 7;
    const int j   = i >> 3;                // 0..63
    const int t   = j & 15;                // tile fastest
    const int b   = xcd * 4 + (j >> 4);    // b slowest
    const int lt  = t >> 2, mt = t & 3;
    const int l0b = lt * 128, m0b = mt * 128;

    const int tid  = threadIdx.x;
    const int lane = tid & 63;
    const int w    = tid >> 6;
    const int wl   = w >> 1, wm = w & 1;
    const int lr   = lane & 15;
    const int lg   = lane >> 4;

    f4 acc[16];
    #pragma unroll
    for (int t2 = 0; t2 < 16; ++t2) acc[t2] = f4{0.f, 0.f, 0.f, 0.f};

    {
        const _Float16* ab = xf1 + (((size_t)b * 32 + lt * 8 + wl * 4) * 24) * 512 + lane * 8;
        const _Float16* bb = xf2 + (((size_t)b * 32 + mt * 8 + wm * 4) * 24) * 512 + lane * 8;
        __builtin_amdgcn_s_setprio(1);
        #pragma unroll
        for (int ks = 0; ks < 24; ++ks) {
            half8 aF[4], bF[4];
            #pragma unroll
            for (int q = 0; q < 4; ++q) {
                aF[q] = *(const half8*)(ab + ((size_t)q * 24 + ks) * 512);
                bF[q] = *(const half8*)(bb + ((size_t)q * 24 + ks) * 512);
            }
            #pragma unroll
            for (int q = 0; q < 4; ++q)
                #pragma unroll
                for (int p = 0; p < 4; ++p)
                    acc[q * 4 + p] = __builtin_amdgcn_mfma_f32_16x16x32_f16(aF[q], bF[p], acc[q * 4 + p], 0, 0, 0);
        }
        __builtin_amdgcn_s_setprio(0);
    }

    {
        float* srow = S + ((size_t)b * 512 + l0b + wl * 64) * 512 + m0b + wm * 64;
        #pragma unroll
        for (int q = 0; q < 4; ++q)
            #pragma unroll
            for (int p = 0; p < 4; ++p)
                #pragma unroll
                for (int r = 0; r < 4; ++r)
                    srow[(size_t)(q * 16 + 4 * lg + r) * 512 + p * 16 + lr] = acc[q * 4 + p][r];
    }
}

// ---------------------------------------------------------------------------
// Stage 1b: ST = S^T (f32), 64x64 tiles via LDS (ST overlays dead XF region).
// ---------------------------------------------------------------------------
__global__ __launch_bounds__(256)
void transpose_s(const float* __restrict__ S, float* __restrict__ ST)
{
    const int i   = blockIdx.x;            // 2048
    const int xcd = i & 7;
    const int j   = i >> 3;                // 0..255
    const int t   = j & 63;
    const int b   = xcd * 4 + (j >> 6);
    const int lt  = t >> 3, mt = t & 7;

    __shared__ float T[64][65];

    const int tid = threadIdx.x;
    const int r   = tid >> 2;
    const int c0  = (tid & 3) * 16;

    {
        const float* src = S + ((size_t)b * 512 + lt * 64 + r) * 512 + mt * 64 + c0;
        #pragma unroll
        for (int k = 0; k < 4; ++k) {
            f4 v = *(const f4*)(src + k * 4);
            T[r][c0 + k * 4 + 0] = v[0]; T[r][c0 + k * 4 + 1] = v[1];
            T[r][c0 + k * 4 + 2] = v[2]; T[r][c0 + k * 4 + 3] = v[3];
        }
    }
    __syncthreads();
    {
        float* dst = ST + ((size_t)b * 512 + mt * 64 + r) * 512 + lt * 64 + c0;
        #pragma unroll
        for (int k = 0; k < 4; ++k) {
            f4 v;
            v[0] = T[c0 + k * 4 + 0][r]; v[1] = T[c0 + k * 4 + 1][r];
            v[2] = T[c0 + k * 4 + 2][r]; v[3] = T[c0 + k * 4 + 3][r];
            *(f4*)(dst + k * 4) = v;
        }
    }
}

// ---------------------------------------------------------------------------
// Stage 2: row softmax on f32 scores; writes normalized P in A-FRAGMENT-PACKED
// f16 layout into the same f32 row-slot space:
//   PF tile (b,t16) at byte ((b*512 + t16*16)*2048); within tile:
//   byte = ks2*1024 + ln*16, ln = (row&15) | ((lane&3)<<4), k = lane*8+j.
// Block owns 32 rows = 2 tiles; all reads complete before writes (barrier).
// ---------------------------------------------------------------------------
__global__ __launch_bounds__(256)
void softmax_pf(float* __restrict__ S32, float* __restrict__ ST32,
                const float* __restrict__ m1, const float* __restrict__ m2)
{
    const int bi   = blockIdx.x;           // 1024
    const int side = bi >> 9;
    const int idx  = bi & 511;
    const int b    = idx >> 4;
    const int rt   = idx & 15;

    float* __restrict__ P = side ? ST32 : S32;
    const float* __restrict__ MK = side ? m1 : m2;

    const int tid  = threadIdx.x;
    const int lane = tid & 63;
    const int w    = tid >> 6;

    __shared__ float mask_s[LKN];
    mask_s[tid] = MK[tid * BB + b];
    mask_s[tid + 256] = MK[(tid + 256) * BB + b];
    __syncthreads();

    float mk[8];
    #pragma unroll
    for (int j = 0; j < 8; ++j) mk[j] = mask_s[lane * 8 + j];

    const int row0 = rt * 32 + w * 8;

    // Phase A: read all 8 rows into registers (coalesced f32)
    f4 fa[8], fb[8];
    #pragma unroll
    for (int rr = 0; rr < 8; ++rr) {
        const float* rp = P + ((size_t)b * 512 + row0 + rr) * 512 + lane * 8;
        fa[rr] = *(const f4*)rp;
        fb[rr] = *(const f4*)(rp + 4);
    }

    // Phase B: softmax per row, pack into half8
    H8 outw[8];
    #pragma unroll
    for (int rr = 0; rr < 8; ++rr) {
        float f[8] = {fa[rr][0], fa[rr][1], fa[rr][2], fa[rr][3],
                      fb[rr][0], fb[rr][1], fb[rr][2], fb[rr][3]};
        float m = fmaxf(fmaxf(fmaxf(f[0], f[1]), fmaxf(f[2], f[3])),
                        fmaxf(fmaxf(f[4], f[5]), fmaxf(f[6], f[7])));
        #pragma unroll
        for (int d = 1; d <= 32; d <<= 1) m = fmaxf(m, __shfl_xor(m, d));
        float e[8], s = 0.f;
        #pragma unroll
        for (int j = 0; j < 8; ++j) { e[j] = __expf(f[j] - m) * mk[j]; s += e[j]; }
        #pragma unroll
        for (int d = 1; d <= 32; d <<= 1) s += __shfl_xor(s, d);
        const float inv = 1.f / (s + 1e-8f);
        outw[rr].u[0] = pk2(e[0] * inv, e[1] * inv);
        outw[rr].u[1] = pk2(e[2] * inv, e[3] * inv);
        outw[rr].u[2] = pk2(e[4] * inv, e[5] * inv);
        outw[rr].u[3] = pk2(e[6] * inv, e[7] * inv);
    }

    __syncthreads();   // ALL rows of this block read before any PF write

    // Phase C: fragment-packed writes
    #pragma unroll
    for (int rr = 0; rr < 8; ++rr) {
        const int row = row0 + rr;
        char* base = (char*)P + ((size_t)b * 512 + (size_t)(row >> 4) * 16) * 2048;
        char* dst  = base + (lane >> 2) * 1024 + (lane & 3) * 256 + (row & 15) * 16;
        *(half8*)dst = outw[rr].h;
    }
}

// ---------------------------------------------------------------------------
// Stage 3: OUT = P.V, fragment-direct: NO LDS, NO barriers. Every operand
// load is a contiguous 1KB wave-load (PF A-frags + XV B-frags), asm-pinned
// in 2-ks2 batches for deep MLP. Block: 64 rows x 192 d; wave: 3 d-tiles.
// ---------------------------------------------------------------------------
__global__ __launch_bounds__(256)
void pv_frag(const float* __restrict__ S32, const float* __restrict__ ST32,
             const _Float16* __restrict__ xv1, const _Float16* __restrict__ xv2,
             float* __restrict__ o1, float* __restrict__ o2)
{
    const int i    = blockIdx.x;           // 2048
    const int xcd  = i & 7;
    const int j    = i >> 3;               // 0..255
    const int lt   = j & 7;                // fastest (8 l-tiles of 64 rows)
    const int dq   = (j >> 3) & 3;         // 4 d-quarters of 192
    const int side = (j >> 5) & 1;
    const int b    = xcd * 4 + (j >> 6);   // slowest
    const int l0   = lt * 64;

    const float* __restrict__ P32   = side ? ST32 : S32;
    const _Float16* __restrict__ VF = side ? xv1 : xv2;   // V = other side
    float* __restrict__ OUT         = side ? o2 : o1;

    const int tid  = threadIdx.x;
    const int lane = tid & 63;
    const int w    = tid >> 6;
    const int lr   = lane & 15;
    const int lg   = lane >> 4;

    // A-frag tile bases (4 q-tiles), B-frag base (3 d-tiles for this wave)
    const char* pb[4];
    #pragma unroll
    for (int q = 0; q < 4; ++q)
        pb[q] = (const char*)P32 + ((size_t)b * 512 + (size_t)(lt * 4 + q) * 16) * 2048 + lane * 16;
    const _Float16* vbase = VF + (((size_t)b * 48 + dq * 12 + w * 3) * 16) * 512 + lane * 8;

    f4 acc[12];                            // [q][nt]
    #pragma unroll
    for (int t = 0; t < 12; ++t) acc[t] = f4{0.f, 0.f, 0.f, 0.f};

    #pragma unroll
    for (int cb = 0; cb < 8; ++cb) {       // 8 batches x 2 ks2
        half8 pa[2][4], vf[2][3];
        #pragma unroll
        for (int k2 = 0; k2 < 2; ++k2) {
            const int ks2 = cb * 2 + k2;
            #pragma unroll
            for (int q = 0; q < 4; ++q)
                gload16(pa[k2][q], (const _Float16*)(pb[q] + ks2 * 1024));
            #pragma unroll
            for (int nt = 0; nt < 3; ++nt)
                gload16(vf[k2][nt], vbase + ((size_t)nt * 16 + ks2) * 512);
        }
        asm volatile("s_waitcnt vmcnt(0)" ::: "memory");
        __builtin_amdgcn_sched_barrier(0);
        __builtin_amdgcn_s_setprio(1);
        #pragma unroll
        for (int k2 = 0; k2 < 2; ++k2)
            #pragma unroll
            for (int nt = 0; nt < 3; ++nt)
                #pragma unroll
                for (int q = 0; q < 4; ++q)
                    acc[q * 3 + nt] = __builtin_amdgcn_mfma_f32_16x16x32_f16(pa[k2][q], vf[k2][nt], acc[q * 3 + nt], 0, 0, 0);
        __builtin_amdgcn_s_setprio(0);
    }

    #pragma unroll
    for (int q = 0; q < 4; ++q)
        #pragma unroll
        for (int nt = 0; nt < 3; ++nt)
            #pragma unroll
            for (int r = 0; r < 4; ++r)
                OUT[((size_t)(l0 + q * 16 + 4 * lg + r) * BB + b) * DD + dq * 192 + (w * 3 + nt) * 16 + lr]
                    = acc[q * 3 + nt][r];
}

// ---------------------------------------------------------------------------
// Fallback (f32 direct, no ws).
// ---------------------------------------------------------------------------
__global__ __launch_bounds__(256)
void coatt_flash_f32(const float* __restrict__ x1, const float* __restrict__ m1,
                     const float* __restrict__ x2, const float* __restrict__ m2,
                     float* __restrict__ o1, float* __restrict__ o2)
{
    const int i    = blockIdx.x;
    const int xcd  = i & 7;
    const int j    = i >> 3;
    const int pair = xcd * 8 + (j >> 5);
    const int qt   = j & 31;
    const int side = pair >> 5;
    const int b    = pair & 31;

    const float* __restrict__ Q   = side ? x2 : x1;
    const float* __restrict__ K   = side ? x1 : x2;
    const float* __restrict__ MK  = side ? m1 : m2;
    float* __restrict__       OUT = side ? o2 : o1;

    const int tid  = threadIdx.x;
    const int lane = tid & 63;
    const int w    = tid >> 6;
    const int lr   = lane & 15;
    const int lg   = lane >> 4;
    const int q0 = qt * 16;
    const int d0 = w * DSL;

    __shared__ float sred[4][16][36];
    __shared__ float mask_s[LKN];
    for (int t = tid; t < LKN; t += 256) mask_s[t] = MK[t * BB + b];

    half8 qf[6];
    {
        const float* qrow = Q + ((q0 + lr) * BB + b) * DD + d0 + lg * 8;
        #pragma unroll
        for (int ks = 0; ks < 6; ++ks) {
            f4 a = *(const f4*)(qrow + ks * 32);
            f4 c = *(const f4*)(qrow + ks * 32 + 4);
            qf[ks] = cvt8(a, c);
        }
    }
    f4 acc[12];
    #pragma unroll
    for (int t = 0; t < 12; ++t) acc[t] = f4{0.f, 0.f, 0.f, 0.f};
    float Mrun = -3.0e38f, Lrun = 0.f;
    for (int kt = 0; kt < 16; ++kt) {
        const int k0 = kt * 32;
        f4 s0 = {0.f,0.f,0.f,0.f}, s1 = {0.f,0.f,0.f,0.f};
        {
            const float* kb0 = K + ((k0 + lr) * BB + b) * DD + d0 + lg * 8;
            const float* kb1 = kb0 + 16 * BB * DD;
            #pragma unroll
            for (int ks = 0; ks < 6; ++ks) {
                f4 a0 = *(const f4*)(kb0 + ks * 32);
                f4 c0 = *(const f4*)(kb0 + ks * 32 + 4);
                s0 = __builtin_amdgcn_mfma_f32_16x16x32_f16(qf[ks], cvt8(a0, c0), s0, 0, 0, 0);
                f4 a1 = *(const f4*)(kb1 + ks * 32);
                f4 c1 = *(const f4*)(kb1 + ks * 32 + 4);
                s1 = __builtin_amdgcn_mfma_f32_16x16x32_f16(qf[ks], cvt8(a1, c1), s1, 0, 0, 0);
            }
        }
        __syncthreads();
        #pragma unroll
        for (int r = 0; r < 4; ++r) {
            sred[w][4 * lg + r][lr]      = s0[r];
            sred[w][4 * lg + r][16 + lr] = s1[r];
        }
        __syncthreads();
        f4 sa = {0.f,0.f,0.f,0.f}, sb = {0.f,0.f,0.f,0.f};
        #pragma unroll
        for (int ww = 0; ww < 4; ++ww) {
            sa += *(const f4*)&sred[ww][lr][lg * 8];
            sb += *(const f4*)&sred[ww][lr][lg * 8 + 4];
        }
        float tmax = fmaxf(fmaxf(fmaxf(sa[0], sa[1]), fmaxf(sa[2], sa[3])),
                           fmaxf(fmaxf(sb[0], sb[1]), fmaxf(sb[2], sb[3])));
        tmax = fmaxf(tmax, __shfl_xor(tmax, 16));
        tmax = fmaxf(tmax, __shfl_xor(tmax, 32));
        const float Mnew  = fmaxf(Mrun, tmax);
        const float scale = __expf(Mrun - Mnew);
        float p[8];
        float psum = 0.f;
        const float* mrow = &mask_s[k0 + lg * 8];
        #pragma unroll
        for (int t = 0; t < 4; ++t) { p[t]     = __expf(sa[t] - Mnew) * mrow[t];     psum += p[t]; }
        #pragma unroll
        for (int t = 0; t < 4; ++t) { p[4 + t] = __expf(sb[t] - Mnew) * mrow[4 + t]; psum += p[4 + t]; }
        psum += __shfl_xor(psum, 16);
        psum += __shfl_xor(psum, 32);
        Lrun = Lrun * scale + psum;
        Mrun = Mnew;
        H8 pf;
        pf.u[0] = pk2(p[0], p[1]); pf.u[1] = pk2(p[2], p[3]);
        pf.u[2] = pk2(p[4], p[5]); pf.u[3] = pk2(p[6], p[7]);
        float sc[4];
        #pragma unroll
        for (int r = 0; r < 4; ++r) sc[r] = __shfl(scale, (lane & 48) + 4 * lg + r);
        #pragma unroll
        for (int t = 0; t < 12; ++t) {
            acc[t][0] *= sc[0]; acc[t][1] *= sc[1];
            acc[t][2] *= sc[2]; acc[t][3] *= sc[3];
        }
        const float* vb = K + ((k0 + lg * 8) * BB + b) * DD + d0 + lr;
        #pragma unroll
        for (int nt = 0; nt < 12; ++nt) {
            const float* vp = vb + nt * 16;
            float vv[8];
            #pragma unroll
            for (int t = 0; t < 8; ++t) vv[t] = vp[t * BB * DD];
            H8 vf;
            vf.u[0] = pk2(vv[0], vv[1]); vf.u[1] = pk2(vv[2], vv[3]);
            vf.u[2] = pk2(vv[4], vv[5]); vf.u[3] = pk2(vv[6], vv[7]);
            acc[nt] = __builtin_amdgcn_mfma_f32_16x16x32_f16(pf.h, vf.h, acc[nt], 0, 0, 0);
        }
    }
    float il[4];
    {
        const float inv = 1.f / (Lrun + 1e-8f);
        #pragma unroll
        for (int r = 0; r < 4; ++r) il[r] = __shfl(inv, (lane & 48) + 4 * lg + r);
    }
    #pragma unroll
    for (int nt = 0; nt < 12; ++nt) {
        #pragma unroll
        for (int r = 0; r < 4; ++r) {
            OUT[((q0 + 4 * lg + r) * BB + b) * DD + d0 + nt * 16 + lr] = acc[nt][r] * il[r];
        }
    }
}

extern "C" void kernel_launch(void* const* d_in, const int* in_sizes, int n_in,
                              void* d_out, int out_size, void* d_ws, size_t ws_size,
                              hipStream_t stream) {
    (void)in_sizes; (void)n_in; (void)out_size;
    const float* x1 = (const float*)d_in[0];
    const float* m1 = (const float*)d_in[1];
    const float* x2 = (const float*)d_in[2];
    const float* m2 = (const float*)d_in[3];
    float* o1 = (float*)d_out;
    float* o2 = o1 + (size_t)LQ * BB * DD;

    const size_t ELEMS = (size_t)LQ * BB * DD;           // 12.58M
    const size_t SELEM = (size_t)BB * 512 * 512;         // 8.39M
    const size_t NEED  = 4 * ELEMS * sizeof(_Float16)    // XF + XV (100.7 MB)
                       + SELEM * sizeof(float);          // S f32 (33.6 MB) = 134.2 MB

    if (ws_size >= NEED) {
        _Float16* xf1 = (_Float16*)d_ws;
        _Float16* xf2 = xf1 + ELEMS;
        _Float16* xv1 = xf2 + ELEMS;
        _Float16* xv2 = xv1 + ELEMS;
        float*    S32 = (float*)(xv2 + ELEMS);           // dedicated 33.6 MB
        float*    ST32 = (float*)d_ws;                   // overlays XF (dead after gemm_s)
        prep_cvt_t<<<6144, 256, 0, stream>>>(x1, x2, xf1, xf2, xv1, xv2);
        gemm_s<<<512, 256, 0, stream>>>(xf1, xf2, S32);
        transpose_s<<<2048, 256, 0, stream>>>(S32, ST32);
        softmax_pf<<<1024, 256, 0, stream>>>(S32, ST32, m1, m2);
        pv_frag<<<2048, 256, 0, stream>>>(S32, ST32, xv1, xv2, o1, o2);
    } else {
        coatt_flash_f32<<<2048, 256, 0, stream>>>(x1, m1, x2, m2, o1, o2);
    }
}

// Round 15
// 156.152 us; speedup vs baseline: 1.4173x; 1.0209x over previous
//
#include <hip/hip_runtime.h>

// Problem constants
#define LQ  512
#define LKN 512
#define BB  32
#define DD  768
#define DSL (DD / 4)

typedef float    f4     __attribute__((ext_vector_type(4)));
typedef _Float16 half8  __attribute__((ext_vector_type(8)));
typedef _Float16 half4  __attribute__((ext_vector_type(4)));
typedef __fp16   fp16x2 __attribute__((ext_vector_type(2)));

union H8 { half8 h; unsigned int u[4]; };

__device__ __forceinline__ unsigned int pk2(float a, float b) {
    union { fp16x2 h; unsigned int u; } c;
    c.h = __builtin_amdgcn_cvt_pkrtz(a, b);
    return c.u;
}
__device__ __forceinline__ half8 cvt8(f4 a, f4 b) {
    H8 r;
    r.u[0] = pk2(a[0], a[1]); r.u[1] = pk2(a[2], a[3]);
    r.u[2] = pk2(b[0], b[1]); r.u[3] = pk2(b[2], b[3]);
    return r.h;
}

// Forced-in-flight global loads (volatile asm cannot be sunk by the scheduler).
__device__ __forceinline__ void gload16(half8& dst, const _Float16* p) {
    asm volatile("global_load_dwordx4 %0, %1, off" : "=v"(dst) : "v"(p));
}
__device__ __forceinline__ void gloadf4(f4& dst, const float* p) {
    asm volatile("global_load_dwordx4 %0, %1, off" : "=v"(dst) : "v"(p));
}

// ---------------------------------------------------------------------------
// Prep: XF = A/B-fragment-packed X (QK^T operands);
//       XV = B-fragment-packed V (PV B operand).
// Input loads are asm-pinned in a 4-deep batch (r14: VGPR=12 showed the
// compiler serialized them 1-deep -> 61us vs 32us BW floor).
// ---------------------------------------------------------------------------
__global__ __launch_bounds__(256)
void prep_cvt_t(const float* __restrict__ x1, const float* __restrict__ x2,
                _Float16* __restrict__ xf1, _Float16* __restrict__ xf2,
                _Float16* __restrict__ xv1, _Float16* __restrict__ xv2)
{
    const int bi   = blockIdx.x;            // 6144
    const int side = bi / 3072;
    const int rem  = bi % 3072;
    const int b    = rem / 96;
    const int rem2 = rem % 96;
    const int l0   = (rem2 / 12) * 64;
    const int d0   = (rem2 % 12) * 64;

    const float* __restrict__ X  = side ? x2  : x1;
    _Float16* __restrict__    XF = side ? xf2 : xf1;
    _Float16* __restrict__    XV = side ? xv2 : xv1;

    __shared__ _Float16 T[64][72];

    const int tid = threadIdx.x;
    {
        const int r  = tid >> 4;            // 0..15
        const int c4 = (tid & 15) * 4;      // 0..60
        const float* src = X + ((size_t)(l0 + r) * BB + b) * DD + d0 + c4;
        f4 v0, v1, v2, v3;
        gloadf4(v0, src);
        gloadf4(v1, src + (size_t)16 * BB * DD);
        gloadf4(v2, src + (size_t)32 * BB * DD);
        gloadf4(v3, src + (size_t)48 * BB * DD);
        asm volatile("s_waitcnt vmcnt(0)" ::: "memory");
        __builtin_amdgcn_sched_barrier(0);
        half4 h;
        h[0] = (_Float16)v0[0]; h[1] = (_Float16)v0[1]; h[2] = (_Float16)v0[2]; h[3] = (_Float16)v0[3];
        *(half4*)&T[r][c4] = h;
        h[0] = (_Float16)v1[0]; h[1] = (_Float16)v1[1]; h[2] = (_Float16)v1[2]; h[3] = (_Float16)v1[3];
        *(half4*)&T[r + 16][c4] = h;
        h[0] = (_Float16)v2[0]; h[1] = (_Float16)v2[1]; h[2] = (_Float16)v2[2]; h[3] = (_Float16)v2[3];
        *(half4*)&T[r + 32][c4] = h;
        h[0] = (_Float16)v3[0]; h[1] = (_Float16)v3[1]; h[2] = (_Float16)v3[2]; h[3] = (_Float16)v3[3];
        *(half4*)&T[r + 48][c4] = h;
    }
    __syncthreads();
    // XF: fragment-packed (A/B operand for QK^T)
    #pragma unroll
    for (int c = tid; c < 512; c += 256) {
        const int t16l = c >> 7;
        const int ksl  = (c >> 6) & 1;
        const int ln   = c & 63;
        half8 v = *(const half8*)&T[t16l * 16 + (ln & 15)][ksl * 32 + (ln >> 4) * 8];
        const size_t t16g = (size_t)(l0 >> 4) + t16l;
        const size_t ksg  = (size_t)(d0 >> 5) + ksl;
        *(half8*)(XF + (((size_t)b * 32 + t16g) * 24 + ksg) * 512 + ln * 8) = v;
    }
    // XV: B-fragment-packed V (k = l dimension, n = d dimension)
    #pragma unroll
    for (int c = tid; c < 512; c += 256) {
        const int dtl  = c >> 7;            // 0..3 (local d-tile)
        const int ks2l = (c >> 6) & 1;      // 0..1 (local k-block of 32)
        const int ln   = c & 63;
        half8 v;
        #pragma unroll
        for (int jj = 0; jj < 8; ++jj)
            v[jj] = T[ks2l * 32 + (ln >> 4) * 8 + jj][dtl * 16 + (ln & 15)];
        *(half8*)(XV + (((size_t)b * 48 + (d0 >> 4) + dtl) * 16 + (l0 >> 5) + ks2l) * 512 + ln * 8) = v;
    }
}

// ---------------------------------------------------------------------------
// Stage 1: S = x1.x2^T (f32), 128x128 tile/block, no LDS.
// ---------------------------------------------------------------------------
__global__ __launch_bounds__(256, 3)
void gemm_s(const _Float16* __restrict__ xf1, const _Float16* __restrict__ xf2,
            float* __restrict__ S)
{
    const int i   = blockIdx.x;            // 512
    const int xcd = i & 7;
    const int j   = i >> 3;                // 0..63
    const int t   = j & 15;                // tile fastest
    const int b   = xcd * 4 + (j >> 4);    // b slowest
    const int lt  = t >> 2, mt = t & 3;
    const int l0b = lt * 128, m0b = mt * 128;

    const int tid  = threadIdx.x;
    const int lane = tid & 63;
    const int w    = tid >> 6;
    const int wl   = w >> 1, wm = w & 1;
    const int lr   = lane & 15;
    const int lg   = lane >> 4;

    f4 acc[16];
    #pragma unroll
    for (int t2 = 0; t2 < 16; ++t2) acc[t2] = f4{0.f, 0.f, 0.f, 0.f};

    {
        const _Float16* ab = xf1 + (((size_t)b * 32 + lt * 8 + wl * 4) * 24) * 512 + lane * 8;
        const _Float16* bb = xf2 + (((size_t)b * 32 + mt * 8 + wm * 4) * 24) * 512 + lane * 8;
        __builtin_amdgcn_s_setprio(1);
        #pragma unroll
        for (int ks = 0; ks < 24; ++ks) {
            half8 aF[4], bF[4];
            #pragma unroll
            for (int q = 0; q < 4; ++q) {
                aF[q] = *(const half8*)(ab + ((size_t)q * 24 + ks) * 512);
                bF[q] = *(const half8*)(bb + ((size_t)q * 24 + ks) * 512);
            }
            #pragma unroll
            for (int q = 0; q < 4; ++q)
                #pragma unroll
                for (int p = 0; p < 4; ++p)
                    acc[q * 4 + p] = __builtin_amdgcn_mfma_f32_16x16x32_f16(aF[q], bF[p], acc[q * 4 + p], 0, 0, 0);
        }
        __builtin_amdgcn_s_setprio(0);
    }

    {
        float* srow = S + ((size_t)b * 512 + l0b + wl * 64) * 512 + m0b + wm * 64;
        #pragma unroll
        for (int q = 0; q < 4; ++q)
            #pragma unroll
            for (int p = 0; p < 4; ++p)
                #pragma unroll
                for (int r = 0; r < 4; ++r)
                    srow[(size_t)(q * 16 + 4 * lg + r) * 512 + p * 16 + lr] = acc[q * 4 + p][r];
    }
}

// ---------------------------------------------------------------------------
// Stage 1b: ST = S^T (f32), 64x64 tiles via LDS (ST overlays dead XF region).
// ---------------------------------------------------------------------------
__global__ __launch_bounds__(256)
void transpose_s(const float* __restrict__ S, float* __restrict__ ST)
{
    const int i   = blockIdx.x;            // 2048
    const int xcd = i & 7;
    const int j   = i >> 3;                // 0..255
    const int t   = j & 63;
    const int b   = xcd * 4 + (j >> 6);
    const int lt  = t >> 3, mt = t & 7;

    __shared__ float T[64][65];

    const int tid = threadIdx.x;
    const int r   = tid >> 2;
    const int c0  = (tid & 3) * 16;

    {
        const float* src = S + ((size_t)b * 512 + lt * 64 + r) * 512 + mt * 64 + c0;
        #pragma unroll
        for (int k = 0; k < 4; ++k) {
            f4 v = *(const f4*)(src + k * 4);
            T[r][c0 + k * 4 + 0] = v[0]; T[r][c0 + k * 4 + 1] = v[1];
            T[r][c0 + k * 4 + 2] = v[2]; T[r][c0 + k * 4 + 3] = v[3];
        }
    }
    __syncthreads();
    {
        float* dst = ST + ((size_t)b * 512 + mt * 64 + r) * 512 + lt * 64 + c0;
        #pragma unroll
        for (int k = 0; k < 4; ++k) {
            f4 v;
            v[0] = T[c0 + k * 4 + 0][r]; v[1] = T[c0 + k * 4 + 1][r];
            v[2] = T[c0 + k * 4 + 2][r]; v[3] = T[c0 + k * 4 + 3][r];
            *(f4*)(dst + k * 4) = v;
        }
    }
}

// ---------------------------------------------------------------------------
// Stage 2: row softmax on f32 scores; writes normalized P in A-FRAGMENT-PACKED
// f16 layout into the same f32 row-slot space.
// ---------------------------------------------------------------------------
__global__ __launch_bounds__(256)
void softmax_pf(float* __restrict__ S32, float* __restrict__ ST32,
                const float* __restrict__ m1, const float* __restrict__ m2)
{
    const int bi   = blockIdx.x;           // 1024
    const int side = bi >> 9;
    const int idx  = bi & 511;
    const int b    = idx >> 4;
    const int rt   = idx & 15;

    float* __restrict__ P = side ? ST32 : S32;
    const float* __restrict__ MK = side ? m1 : m2;

    const int tid  = threadIdx.x;
    const int lane = tid & 63;
    const int w    = tid >> 6;

    __shared__ float mask_s[LKN];
    mask_s[tid] = MK[tid * BB + b];
    mask_s[tid + 256] = MK[(tid + 256) * BB + b];
    __syncthreads();

    float mk[8];
    #pragma unroll
    for (int j = 0; j < 8; ++j) mk[j] = mask_s[lane * 8 + j];

    const int row0 = rt * 32 + w * 8;

    // Phase A: read all 8 rows into registers (coalesced f32)
    f4 fa[8], fb[8];
    #pragma unroll
    for (int rr = 0; rr < 8; ++rr) {
        const float* rp = P + ((size_t)b * 512 + row0 + rr) * 512 + lane * 8;
        fa[rr] = *(const f4*)rp;
        fb[rr] = *(const f4*)(rp + 4);
    }

    // Phase B: softmax per row, pack into half8
    H8 outw[8];
    #pragma unroll
    for (int rr = 0; rr < 8; ++rr) {
        float f[8] = {fa[rr][0], fa[rr][1], fa[rr][2], fa[rr][3],
                      fb[rr][0], fb[rr][1], fb[rr][2], fb[rr][3]};
        float m = fmaxf(fmaxf(fmaxf(f[0], f[1]), fmaxf(f[2], f[3])),
                        fmaxf(fmaxf(f[4], f[5]), fmaxf(f[6], f[7])));
        #pragma unroll
        for (int d = 1; d <= 32; d <<= 1) m = fmaxf(m, __shfl_xor(m, d));
        float e[8], s = 0.f;
        #pragma unroll
        for (int j = 0; j < 8; ++j) { e[j] = __expf(f[j] - m) * mk[j]; s += e[j]; }
        #pragma unroll
        for (int d = 1; d <= 32; d <<= 1) s += __shfl_xor(s, d);
        const float inv = 1.f / (s + 1e-8f);
        outw[rr].u[0] = pk2(e[0] * inv, e[1] * inv);
        outw[rr].u[1] = pk2(e[2] * inv, e[3] * inv);
        outw[rr].u[2] = pk2(e[4] * inv, e[5] * inv);
        outw[rr].u[3] = pk2(e[6] * inv, e[7] * inv);
    }

    __syncthreads();   // ALL rows of this block read before any PF write

    // Phase C: fragment-packed writes
    #pragma unroll
    for (int rr = 0; rr < 8; ++rr) {
        const int row = row0 + rr;
        char* base = (char*)P + ((size_t)b * 512 + (size_t)(row >> 4) * 16) * 2048;
        char* dst  = base + (lane >> 2) * 1024 + (lane & 3) * 256 + (row & 15) * 16;
        *(half8*)dst = outw[rr].h;
    }
}

// ---------------------------------------------------------------------------
// Stage 3: OUT = P.V, fragment-direct: NO LDS, NO barriers; asm-pinned
// contiguous 1KB wave-loads in 2-ks2 batches.
// ---------------------------------------------------------------------------
__global__ __launch_bounds__(256)
void pv_frag(const float* __restrict__ S32, const float* __restrict__ ST32,
             const _Float16* __restrict__ xv1, const _Float16* __restrict__ xv2,
             float* __restrict__ o1, float* __restrict__ o2)
{
    const int i    = blockIdx.x;           // 2048
    const int xcd  = i & 7;
    const int j    = i >> 3;               // 0..255
    const int lt   = j & 7;                // fastest (8 l-tiles of 64 rows)
    const int dq   = (j >> 3) & 3;         // 4 d-quarters of 192
    const int side = (j >> 5) & 1;
    const int b    = xcd * 4 + (j >> 6);   // slowest
    const int l0   = lt * 64;

    const float* __restrict__ P32   = side ? ST32 : S32;
    const _Float16* __restrict__ VF = side ? xv1 : xv2;   // V = other side
    float* __restrict__ OUT         = side ? o2 : o1;

    const int tid  = threadIdx.x;
    const int lane = tid & 63;
    const int w    = tid >> 6;
    const int lr   = lane & 15;
    const int lg   = lane >> 4;

    const char* pb[4];
    #pragma unroll
    for (int q = 0; q < 4; ++q)
        pb[q] = (const char*)P32 + ((size_t)b * 512 + (size_t)(lt * 4 + q) * 16) * 2048 + lane * 16;
    const _Float16* vbase = VF + (((size_t)b * 48 + dq * 12 + w * 3) * 16) * 512 + lane * 8;

    f4 acc[12];                            // [q][nt]
    #pragma unroll
    for (int t = 0; t < 12; ++t) acc[t] = f4{0.f, 0.f, 0.f, 0.f};

    #pragma unroll
    for (int cb = 0; cb < 8; ++cb) {       // 8 batches x 2 ks2
        half8 pa[2][4], vf[2][3];
        #pragma unroll
        for (int k2 = 0; k2 < 2; ++k2) {
            const int ks2 = cb * 2 + k2;
            #pragma unroll
            for (int q = 0; q < 4; ++q)
                gload16(pa[k2][q], (const _Float16*)(pb[q] + ks2 * 1024));
            #pragma unroll
            for (int nt = 0; nt < 3; ++nt)
                gload16(vf[k2][nt], vbase + ((size_t)nt * 16 + ks2) * 512);
        }
        asm volatile("s_waitcnt vmcnt(0)" ::: "memory");
        __builtin_amdgcn_sched_barrier(0);
        __builtin_amdgcn_s_setprio(1);
        #pragma unroll
        for (int k2 = 0; k2 < 2; ++k2)
            #pragma unroll
            for (int nt = 0; nt < 3; ++nt)
                #pragma unroll
                for (int q = 0; q < 4; ++q)
                    acc[q * 3 + nt] = __builtin_amdgcn_mfma_f32_16x16x32_f16(pa[k2][q], vf[k2][nt], acc[q * 3 + nt], 0, 0, 0);
        __builtin_amdgcn_s_setprio(0);
    }

    #pragma unroll
    for (int q = 0; q < 4; ++q)
        #pragma unroll
        for (int nt = 0; nt < 3; ++nt)
            #pragma unroll
            for (int r = 0; r < 4; ++r)
                OUT[((size_t)(l0 + q * 16 + 4 * lg + r) * BB + b) * DD + dq * 192 + (w * 3 + nt) * 16 + lr]
                    = acc[q * 3 + nt][r];
}

// ---------------------------------------------------------------------------
// Fallback (f32 direct, no ws).
// ---------------------------------------------------------------------------
__global__ __launch_bounds__(256)
void coatt_flash_f32(const float* __restrict__ x1, const float* __restrict__ m1,
                     const float* __restrict__ x2, const float* __restrict__ m2,
                     float* __restrict__ o1, float* __restrict__ o2)
{
    const int i    = blockIdx.x;
    const int xcd  = i & 7;
    const int j    = i >> 3;
    const int pair = xcd * 8 + (j >> 5);
    const int qt   = j & 31;
    const int side = pair >> 5;
    const int b    = pair & 31;

    const float* __restrict__ Q   = side ? x2 : x1;
    const float* __restrict__ K   = side ? x1 : x2;
    const float* __restrict__ MK  = side ? m1 : m2;
    float* __restrict__       OUT = side ? o2 : o1;

    const int tid  = threadIdx.x;
    const int lane = tid & 63;
    const int w    = tid >> 6;
    const int lr   = lane & 15;
    const int lg   = lane >> 4;
    const int q0 = qt * 16;
    const int d0 = w * DSL;

    __shared__ float sred[4][16][36];
    __shared__ float mask_s[LKN];
    for (int t = tid; t < LKN; t += 256) mask_s[t] = MK[t * BB + b];

    half8 qf[6];
    {
        const float* qrow = Q + ((q0 + lr) * BB + b) * DD + d0 + lg * 8;
        #pragma unroll
        for (int ks = 0; ks < 6; ++ks) {
            f4 a = *(const f4*)(qrow + ks * 32);
            f4 c = *(const f4*)(qrow + ks * 32 + 4);
            qf[ks] = cvt8(a, c);
        }
    }
    f4 acc[12];
    #pragma unroll
    for (int t = 0; t < 12; ++t) acc[t] = f4{0.f, 0.f, 0.f, 0.f};
    float Mrun = -3.0e38f, Lrun = 0.f;
    for (int kt = 0; kt < 16; ++kt) {
        const int k0 = kt * 32;
        f4 s0 = {0.f,0.f,0.f,0.f}, s1 = {0.f,0.f,0.f,0.f};
        {
            const float* kb0 = K + ((k0 + lr) * BB + b) * DD + d0 + lg * 8;
            const float* kb1 = kb0 + 16 * BB * DD;
            #pragma unroll
            for (int ks = 0; ks < 6; ++ks) {
                f4 a0 = *(const f4*)(kb0 + ks * 32);
                f4 c0 = *(const f4*)(kb0 + ks * 32 + 4);
                s0 = __builtin_amdgcn_mfma_f32_16x16x32_f16(qf[ks], cvt8(a0, c0), s0, 0, 0, 0);
                f4 a1 = *(const f4*)(kb1 + ks * 32);
                f4 c1 = *(const f4*)(kb1 + ks * 32 + 4);
                s1 = __builtin_amdgcn_mfma_f32_16x16x32_f16(qf[ks], cvt8(a1, c1), s1, 0, 0, 0);
            }
        }
        __syncthreads();
        #pragma unroll
        for (int r = 0; r < 4; ++r) {
            sred[w][4 * lg + r][lr]      = s0[r];
            sred[w][4 * lg + r][16 + lr] = s1[r];
        }
        __syncthreads();
        f4 sa = {0.f,0.f,0.f,0.f}, sb = {0.f,0.f,0.f,0.f};
        #pragma unroll
        for (int ww = 0; ww < 4; ++ww) {
            sa += *(const f4*)&sred[ww][lr][lg * 8];
            sb += *(const f4*)&sred[ww][lr][lg * 8 + 4];
        }
        float tmax = fmaxf(fmaxf(fmaxf(sa[0], sa[1]), fmaxf(sa[2], sa[3])),
                           fmaxf(fmaxf(sb[0], sb[1]), fmaxf(sb[2], sb[3])));
        tmax = fmaxf(tmax, __shfl_xor(tmax, 16));
        tmax = fmaxf(tmax, __shfl_xor(tmax, 32));
        const float Mnew  = fmaxf(Mrun, tmax);
        const float scale = __expf(Mrun - Mnew);
        float p[8];
        float psum = 0.f;
        const float* mrow = &mask_s[k0 + lg * 8];
        #pragma unroll
        for (int t = 0; t < 4; ++t) { p[t]     = __expf(sa[t] - Mnew) * mrow[t];     psum += p[t]; }
        #pragma unroll
        for (int t = 0; t < 4; ++t) { p[4 + t] = __expf(sb[t] - Mnew) * mrow[4 + t]; psum += p[4 + t]; }
        psum += __shfl_xor(psum, 16);
        psum += __shfl_xor(psum, 32);
        Lrun = Lrun * scale + psum;
        Mrun = Mnew;
        H8 pf;
        pf.u[0] = pk2(p[0], p[1]); pf.u[1] = pk2(p[2], p[3]);
        pf.u[2] = pk2(p[4], p[5]); pf.u[3] = pk2(p[6], p[7]);
        float sc[4];
        #pragma unroll
        for (int r = 0; r < 4; ++r) sc[r] = __shfl(scale, (lane & 48) + 4 * lg + r);
        #pragma unroll
        for (int t = 0; t < 12; ++t) {
            acc[t][0] *= sc[0]; acc[t][1] *= sc[1];
            acc[t][2] *= sc[2]; acc[t][3] *= sc[3];
        }
        const float* vb = K + ((k0 + lg * 8) * BB + b) * DD + d0 + lr;
        #pragma unroll
        for (int nt = 0; nt < 12; ++nt) {
            const float* vp = vb + nt * 16;
            float vv[8];
            #pragma unroll
            for (int t = 0; t < 8; ++t) vv[t] = vp[t * BB * DD];
            H8 vf;
            vf.u[0] = pk2(vv[0], vv[1]); vf.u[1] = pk2(vv[2], vv[3]);
            vf.u[2] = pk2(vv[4], vv[5]); vf.u[3] = pk2(vv[6], vv[7]);
            acc[nt] = __builtin_amdgcn_mfma_f32_16x16x32_f16(pf.h, vf.h, acc[nt], 0, 0, 0);
        }
    }
    float il[4];
    {
        const float inv = 1.f / (Lrun + 1e-8f);
        #pragma unroll
        for (int r = 0; r < 4; ++r) il[r] = __shfl(inv, (lane & 48) + 4 * lg + r);
    }
    #pragma unroll
    for (int nt = 0; nt < 12; ++nt) {
        #pragma unroll
        for (int r = 0; r < 4; ++r) {
            OUT[((q0 + 4 * lg + r) * BB + b) * DD + d0 + nt * 16 + lr] = acc[nt][r] * il[r];
        }
    }
}

extern "C" void kernel_launch(void* const* d_in, const int* in_sizes, int n_in,
                              void* d_out, int out_size, void* d_ws, size_t ws_size,
                              hipStream_t stream) {
    (void)in_sizes; (void)n_in; (void)out_size;
    const float* x1 = (const float*)d_in[0];
    const float* m1 = (const float*)d_in[1];
    const float* x2 = (const float*)d_in[2];
    const float* m2 = (const float*)d_in[3];
    float* o1 = (float*)d_out;
    float* o2 = o1 + (size_t)LQ * BB * DD;

    const size_t ELEMS = (size_t)LQ * BB * DD;           // 12.58M
    const size_t SELEM = (size_t)BB * 512 * 512;         // 8.39M
    const size_t NEED  = 4 * ELEMS * sizeof(_Float16)    // XF + XV (100.7 MB)
                       + SELEM * sizeof(float);          // S f32 (33.6 MB) = 134.2 MB

    if (ws_size >= NEED) {
        _Float16* xf1 = (_Float16*)d_ws;
        _Float16* xf2 = xf1 + ELEMS;
        _Float16* xv1 = xf2 + ELEMS;
        _Float16* xv2 = xv1 + ELEMS;
        float*    S32 = (float*)(xv2 + ELEMS);           // dedicated 33.6 MB
        float*    ST32 = (float*)d_ws;                   // overlays XF (dead after gemm_s)
        prep_cvt_t<<<6144, 256, 0, stream>>>(x1, x2, xf1, xf2, xv1, xv2);
        gemm_s<<<512, 256, 0, stream>>>(xf1, xf2, S32);
        transpose_s<<<2048, 256, 0, stream>>>(S32, ST32);
        softmax_pf<<<1024, 256, 0, stream>>>(S32, ST32, m1, m2);
        pv_frag<<<2048, 256, 0, stream>>>(S32, ST32, xv1, xv2, o1, o2);
    } else {
        coatt_flash_f32<<<2048, 256, 0, stream>>>(x1, m1, x2, m2, o1, o2);
    }
}

// Round 16
// 143.861 us; speedup vs baseline: 1.5384x; 1.0854x over previous
//
#include <hip/hip_runtime.h>

// Problem constants
#define LQ  512
#define LKN 512
#define BB  32
#define DD  768
#define DSL (DD / 4)

typedef float    f4     __attribute__((ext_vector_type(4)));
typedef _Float16 half8  __attribute__((ext_vector_type(8)));
typedef _Float16 half4  __attribute__((ext_vector_type(4)));
typedef __fp16   fp16x2 __attribute__((ext_vector_type(2)));

union H8 { half8 h; unsigned int u[4]; };

__device__ __forceinline__ unsigned int pk2(float a, float b) {
    union { fp16x2 h; unsigned int u; } c;
    c.h = __builtin_amdgcn_cvt_pkrtz(a, b);
    return c.u;
}
__device__ __forceinline__ half8 cvt8(f4 a, f4 b) {
    H8 r;
    r.u[0] = pk2(a[0], a[1]); r.u[1] = pk2(a[2], a[3]);
    r.u[2] = pk2(b[0], b[1]); r.u[3] = pk2(b[2], b[3]);
    return r.h;
}

// Forced-in-flight global loads (volatile asm cannot be sunk by the scheduler).
__device__ __forceinline__ void gload16(half8& dst, const _Float16* p) {
    asm volatile("global_load_dwordx4 %0, %1, off" : "=v"(dst) : "v"(p));
}
__device__ __forceinline__ void gloadf4(f4& dst, const float* p) {
    asm volatile("global_load_dwordx4 %0, %1, off" : "=v"(dst) : "v"(p));
}

// ---------------------------------------------------------------------------
// prep_pack (RENAMED — verification tripwire): 3072 blocks, 64 l x 128 d per
// block, 8-deep asm-batched input loads. Writes XF (QK^T fragments) and
// XV (PV B-fragments).
// ---------------------------------------------------------------------------
__global__ __launch_bounds__(256)
void prep_pack(const float* __restrict__ x1, const float* __restrict__ x2,
               _Float16* __restrict__ xf1, _Float16* __restrict__ xf2,
               _Float16* __restrict__ xv1, _Float16* __restrict__ xv2)
{
    const int bi   = blockIdx.x;            // 3072
    const int side = bi / 1536;
    const int rem  = bi % 1536;
    const int b    = rem / 48;
    const int rem2 = rem % 48;
    const int l0   = (rem2 / 6) * 64;
    const int d0   = (rem2 % 6) * 128;

    const float* __restrict__ X  = side ? x2  : x1;
    _Float16* __restrict__    XF = side ? xf2 : xf1;
    _Float16* __restrict__    XV = side ? xv2 : xv1;

    __shared__ _Float16 T[64][136];         // 64 x 128 data + pad

    const int tid = threadIdx.x;
    {
        const int r  = tid >> 4;            // 0..15
        const int c8 = (tid & 15) * 8;      // 0..120
        const float* src = X + ((size_t)(l0 + r) * BB + b) * DD + d0 + c8;
        f4 v[8];
        #pragma unroll
        for (int k = 0; k < 4; ++k) {
            gloadf4(v[2 * k],     src + (size_t)k * 16 * BB * DD);
            gloadf4(v[2 * k + 1], src + (size_t)k * 16 * BB * DD + 4);
        }
        asm volatile("s_waitcnt vmcnt(0)" ::: "memory");
        __builtin_amdgcn_sched_barrier(0);
        #pragma unroll
        for (int k = 0; k < 4; ++k) {
            half4 ha, hb;
            ha[0] = (_Float16)v[2*k][0]; ha[1] = (_Float16)v[2*k][1];
            ha[2] = (_Float16)v[2*k][2]; ha[3] = (_Float16)v[2*k][3];
            hb[0] = (_Float16)v[2*k+1][0]; hb[1] = (_Float16)v[2*k+1][1];
            hb[2] = (_Float16)v[2*k+1][2]; hb[3] = (_Float16)v[2*k+1][3];
            *(half4*)&T[r + 16 * k][c8]     = ha;
            *(half4*)&T[r + 16 * k][c8 + 4] = hb;
        }
    }
    __syncthreads();
    // XF: fragment-packed (A/B operand for QK^T): 1024 chunks, 4 per thread
    #pragma unroll
    for (int c2 = tid; c2 < 1024; c2 += 256) {
        const int dhalf = c2 >> 9;          // 0..1
        const int t16l  = (c2 >> 7) & 3;
        const int ksl   = (c2 >> 6) & 1;
        const int ln    = c2 & 63;
        half8 v = *(const half8*)&T[t16l * 16 + (ln & 15)][dhalf * 64 + ksl * 32 + (ln >> 4) * 8];
        const size_t t16g = (size_t)(l0 >> 4) + t16l;
        const size_t ksg  = (size_t)(d0 >> 5) + dhalf * 2 + ksl;
        *(half8*)(XF + (((size_t)b * 32 + t16g) * 24 + ksg) * 512 + ln * 8) = v;
    }
    // XV: B-fragment-packed V: 1024 chunks, 4 per thread
    #pragma unroll
    for (int c2 = tid; c2 < 1024; c2 += 256) {
        const int dtl  = c2 >> 7;           // 0..7
        const int ks2l = (c2 >> 6) & 1;
        const int ln   = c2 & 63;
        half8 v;
        #pragma unroll
        for (int jj = 0; jj < 8; ++jj)
            v[jj] = T[ks2l * 32 + (ln >> 4) * 8 + jj][dtl * 16 + (ln & 15)];
        const size_t dtg  = (size_t)(d0 >> 4) + dtl;
        const size_t ks2g = (size_t)(l0 >> 5) + ks2l;
        *(half8*)(XV + (((size_t)b * 48 + dtg) * 16 + ks2g) * 512 + ln * 8) = v;
    }
}

// ---------------------------------------------------------------------------
// Stage 1: S = x1.x2^T (f32), 128x128 tile/block, no LDS.
// ---------------------------------------------------------------------------
__global__ __launch_bounds__(256, 3)
void gemm_s(const _Float16* __restrict__ xf1, const _Float16* __restrict__ xf2,
            float* __restrict__ S)
{
    const int i   = blockIdx.x;            // 512
    const int xcd = i & 7;
    const int j   = i >> 3;                // 0..63
    const int t   = j & 15;                // tile fastest
    const int b   = xcd * 4 + (j >> 4);    // b slowest
    const int lt  = t >> 2, mt = t & 3;
    const int l0b = lt * 128, m0b = mt * 128;

    const int tid  = threadIdx.x;
    const int lane = tid & 63;
    const int w    = tid >> 6;
    const int wl   = w >> 1, wm = w & 1;
    const int lr   = lane & 15;
    const int lg   = lane >> 4;

    f4 acc[16];
    #pragma unroll
    for (int t2 = 0; t2 < 16; ++t2) acc[t2] = f4{0.f, 0.f, 0.f, 0.f};

    {
        const _Float16* ab = xf1 + (((size_t)b * 32 + lt * 8 + wl * 4) * 24) * 512 + lane * 8;
        const _Float16* bb = xf2 + (((size_t)b * 32 + mt * 8 + wm * 4) * 24) * 512 + lane * 8;
        __builtin_amdgcn_s_setprio(1);
        #pragma unroll
        for (int ks = 0; ks < 24; ++ks) {
            half8 aF[4], bF[4];
            #pragma unroll
            for (int q = 0; q < 4; ++q) {
                aF[q] = *(const half8*)(ab + ((size_t)q * 24 + ks) * 512);
                bF[q] = *(const half8*)(bb + ((size_t)q * 24 + ks) * 512);
            }
            #pragma unroll
            for (int q = 0; q < 4; ++q)
                #pragma unroll
                for (int p = 0; p < 4; ++p)
                    acc[q * 4 + p] = __builtin_amdgcn_mfma_f32_16x16x32_f16(aF[q], bF[p], acc[q * 4 + p], 0, 0, 0);
        }
        __builtin_amdgcn_s_setprio(0);
    }

    {
        float* srow = S + ((size_t)b * 512 + l0b + wl * 64) * 512 + m0b + wm * 64;
        #pragma unroll
        for (int q = 0; q < 4; ++q)
            #pragma unroll
            for (int p = 0; p < 4; ++p)
                #pragma unroll
                for (int r = 0; r < 4; ++r)
                    srow[(size_t)(q * 16 + 4 * lg + r) * 512 + p * 16 + lr] = acc[q * 4 + p][r];
    }
}

// ---------------------------------------------------------------------------
// Stage 2a: COLUMN softmax (side 1) reading pristine f32 S; writes PF1
// (fragment-packed) into the old-XF region. Runs BEFORE the row pass (which
// overwrites S in place). Block: 32 cols x all 512 rows.
// ---------------------------------------------------------------------------
__global__ __launch_bounds__(256)
void softmax_col_pf(const float* __restrict__ S32, float* __restrict__ PF1,
                    const float* __restrict__ m1)
{
    const int i  = blockIdx.x;             // 512
    const int b  = i >> 4;
    const int ct = i & 15;                 // 16 col-groups of 32

    const int tid = threadIdx.x;

    __shared__ float raw[32][513];         // [col][row], conflict-free both axes
    __shared__ float mask_s[LKN];
    __shared__ float redm[8][32];
    __shared__ float reds[8][32];

    mask_s[tid] = m1[tid * BB + b];
    mask_s[tid + 256] = m1[(tid + 256) * BB + b];

    // fill: 16 asm-batched f4 loads per thread (rows it*32 + tid>>3, cols (tid&7)*4)
    {
        const float* sbase = S32 + ((size_t)b * 512 + (tid >> 3)) * 512 + ct * 32 + (tid & 7) * 4;
        f4 vv[16];
        #pragma unroll
        for (int it = 0; it < 8; ++it) gloadf4(vv[it], sbase + (size_t)it * 32 * 512);
        asm volatile("s_waitcnt vmcnt(0)" ::: "memory");
        __builtin_amdgcn_sched_barrier(0);
        #pragma unroll
        for (int it = 8; it < 16; ++it) gloadf4(vv[it], sbase + (size_t)it * 32 * 512);
        #pragma unroll
        for (int it = 0; it < 8; ++it) {
            const int row = it * 32 + (tid >> 3);
            const int c0  = (tid & 7) * 4;
            raw[c0 + 0][row] = vv[it][0]; raw[c0 + 1][row] = vv[it][1];
            raw[c0 + 2][row] = vv[it][2]; raw[c0 + 3][row] = vv[it][3];
        }
        asm volatile("s_waitcnt vmcnt(0)" ::: "memory");
        __builtin_amdgcn_sched_barrier(0);
        #pragma unroll
        for (int it = 8; it < 16; ++it) {
            const int row = it * 32 + (tid >> 3);
            const int c0  = (tid & 7) * 4;
            raw[c0 + 0][row] = vv[it][0]; raw[c0 + 1][row] = vv[it][1];
            raw[c0 + 2][row] = vv[it][2]; raw[c0 + 3][row] = vv[it][3];
        }
    }
    __syncthreads();

    const int col = tid & 31;
    const int seg = tid >> 5;              // 0..7, rows seg*64..+63

    // pass A: column max
    float m = -3.0e38f;
    #pragma unroll
    for (int r = 0; r < 64; ++r) m = fmaxf(m, raw[col][seg * 64 + r]);
    redm[seg][col] = m;
    __syncthreads();
    float M = redm[0][col];
    #pragma unroll
    for (int s2 = 1; s2 < 8; ++s2) M = fmaxf(M, redm[s2][col]);

    // pass B: masked exp-sum
    float s = 0.f;
    #pragma unroll
    for (int r = 0; r < 64; ++r) {
        const int row = seg * 64 + r;
        s += __expf(raw[col][row] - M) * mask_s[row];
    }
    reds[seg][col] = s;
    __syncthreads();
    float L = 0.f;
    #pragma unroll
    for (int s2 = 0; s2 < 8; ++s2) L += reds[s2][col];
    const float inv = 1.f / (L + 1e-8f);

    // pass C: write PF1 fragments (ST-row = col_g, k = row)
    const int col_g = ct * 32 + col;
    char* pfb = (char*)PF1 + ((size_t)b * 512 + (size_t)(col_g >> 4) * 16) * 2048;
    #pragma unroll
    for (int kc = 0; kc < 8; ++kc) {
        const int k0 = seg * 64 + kc * 8;
        float e[8];
        #pragma unroll
        for (int j = 0; j < 8; ++j)
            e[j] = __expf(raw[col][k0 + j] - M) * mask_s[k0 + j] * inv;
        H8 o;
        o.u[0] = pk2(e[0], e[1]); o.u[1] = pk2(e[2], e[3]);
        o.u[2] = pk2(e[4], e[5]); o.u[3] = pk2(e[6], e[7]);
        const int lane_w = seg * 8 + kc;
        *(half8*)(pfb + (lane_w >> 2) * 1024 + (lane_w & 3) * 256 + (col_g & 15) * 16) = o.h;
    }
}

// ---------------------------------------------------------------------------
// Stage 2b: ROW softmax (side 0); writes PF0 in-place into S32 row slots.
// Runs AFTER the column pass.
// ---------------------------------------------------------------------------
__global__ __launch_bounds__(256)
void softmax_row_pf(float* __restrict__ S32, const float* __restrict__ m2)
{
    const int i  = blockIdx.x;             // 512
    const int b  = i >> 4;
    const int rt = i & 15;

    const int tid  = threadIdx.x;
    const int lane = tid & 63;
    const int w    = tid >> 6;

    __shared__ float mask_s[LKN];
    mask_s[tid] = m2[tid * BB + b];
    mask_s[tid + 256] = m2[(tid + 256) * BB + b];
    __syncthreads();

    float mk[8];
    #pragma unroll
    for (int j = 0; j < 8; ++j) mk[j] = mask_s[lane * 8 + j];

    const int row0 = rt * 32 + w * 8;

    f4 fa[8], fb[8];
    #pragma unroll
    for (int rr = 0; rr < 8; ++rr) {
        const float* rp = S32 + ((size_t)b * 512 + row0 + rr) * 512 + lane * 8;
        fa[rr] = *(const f4*)rp;
        fb[rr] = *(const f4*)(rp + 4);
    }

    H8 outw[8];
    #pragma unroll
    for (int rr = 0; rr < 8; ++rr) {
        float f[8] = {fa[rr][0], fa[rr][1], fa[rr][2], fa[rr][3],
                      fb[rr][0], fb[rr][1], fb[rr][2], fb[rr][3]};
        float m = fmaxf(fmaxf(fmaxf(f[0], f[1]), fmaxf(f[2], f[3])),
                        fmaxf(fmaxf(f[4], f[5]), fmaxf(f[6], f[7])));
        #pragma unroll
        for (int d = 1; d <= 32; d <<= 1) m = fmaxf(m, __shfl_xor(m, d));
        float e[8], s = 0.f;
        #pragma unroll
        for (int j = 0; j < 8; ++j) { e[j] = __expf(f[j] - m) * mk[j]; s += e[j]; }
        #pragma unroll
        for (int d = 1; d <= 32; d <<= 1) s += __shfl_xor(s, d);
        const float inv = 1.f / (s + 1e-8f);
        outw[rr].u[0] = pk2(e[0] * inv, e[1] * inv);
        outw[rr].u[1] = pk2(e[2] * inv, e[3] * inv);
        outw[rr].u[2] = pk2(e[4] * inv, e[5] * inv);
        outw[rr].u[3] = pk2(e[6] * inv, e[7] * inv);
    }

    __syncthreads();   // all rows of this block read before any PF write

    #pragma unroll
    for (int rr = 0; rr < 8; ++rr) {
        const int row = row0 + rr;
        char* base = (char*)S32 + ((size_t)b * 512 + (size_t)(row >> 4) * 16) * 2048;
        char* dst  = base + (lane >> 2) * 1024 + (lane & 3) * 256 + (row & 15) * 16;
        *(half8*)dst = outw[rr].h;
    }
}

// ---------------------------------------------------------------------------
// Stage 3: OUT = P.V, fragment-direct: NO LDS, NO barriers; asm-pinned
// contiguous 1KB wave-loads in 2-ks2 batches.
// ---------------------------------------------------------------------------
__global__ __launch_bounds__(256)
void pv_frag(const float* __restrict__ S32, const float* __restrict__ ST32,
             const _Float16* __restrict__ xv1, const _Float16* __restrict__ xv2,
             float* __restrict__ o1, float* __restrict__ o2)
{
    const int i    = blockIdx.x;           // 2048
    const int xcd  = i & 7;
    const int j    = i >> 3;               // 0..255
    const int lt   = j & 7;                // fastest (8 l-tiles of 64 rows)
    const int dq   = (j >> 3) & 3;         // 4 d-quarters of 192
    const int side = (j >> 5) & 1;
    const int b    = xcd * 4 + (j >> 6);   // slowest
    const int l0   = lt * 64;

    const float* __restrict__ P32   = side ? ST32 : S32;
    const _Float16* __restrict__ VF = side ? xv1 : xv2;   // V = other side
    float* __restrict__ OUT         = side ? o2 : o1;

    const int tid  = threadIdx.x;
    const int lane = tid & 63;
    const int w    = tid >> 6;
    const int lr   = lane & 15;
    const int lg   = lane >> 4;

    const char* pb[4];
    #pragma unroll
    for (int q = 0; q < 4; ++q)
        pb[q] = (const char*)P32 + ((size_t)b * 512 + (size_t)(lt * 4 + q) * 16) * 2048 + lane * 16;
    const _Float16* vbase = VF + (((size_t)b * 48 + dq * 12 + w * 3) * 16) * 512 + lane * 8;

    f4 acc[12];                            // [q][nt]
    #pragma unroll
    for (int t = 0; t < 12; ++t) acc[t] = f4{0.f, 0.f, 0.f, 0.f};

    #pragma unroll
    for (int cb = 0; cb < 8; ++cb) {       // 8 batches x 2 ks2
        half8 pa[2][4], vf[2][3];
        #pragma unroll
        for (int k2 = 0; k2 < 2; ++k2) {
            const int ks2 = cb * 2 + k2;
            #pragma unroll
            for (int q = 0; q < 4; ++q)
                gload16(pa[k2][q], (const _Float16*)(pb[q] + ks2 * 1024));
            #pragma unroll
            for (int nt = 0; nt < 3; ++nt)
                gload16(vf[k2][nt], vbase + ((size_t)nt * 16 + ks2) * 512);
        }
        asm volatile("s_waitcnt vmcnt(0)" ::: "memory");
        __builtin_amdgcn_sched_barrier(0);
        __builtin_amdgcn_s_setprio(1);
        #pragma unroll
        for (int k2 = 0; k2 < 2; ++k2)
            #pragma unroll
            for (int nt = 0; nt < 3; ++nt)
                #pragma unroll
                for (int q = 0; q < 4; ++q)
                    acc[q * 3 + nt] = __builtin_amdgcn_mfma_f32_16x16x32_f16(pa[k2][q], vf[k2][nt], acc[q * 3 + nt], 0, 0, 0);
        __builtin_amdgcn_s_setprio(0);
    }

    #pragma unroll
    for (int q = 0; q < 4; ++q)
        #pragma unroll
        for (int nt = 0; nt < 3; ++nt)
            #pragma unroll
            for (int r = 0; r < 4; ++r)
                OUT[((size_t)(l0 + q * 16 + 4 * lg + r) * BB + b) * DD + dq * 192 + (w * 3 + nt) * 16 + lr]
                    = acc[q * 3 + nt][r];
}

// ---------------------------------------------------------------------------
// Fallback (f32 direct, no ws).
// ---------------------------------------------------------------------------
__global__ __launch_bounds__(256)
void coatt_flash_f32(const float* __restrict__ x1, const float* __restrict__ m1,
                     const float* __restrict__ x2, const float* __restrict__ m2,
                     float* __restrict__ o1, float* __restrict__ o2)
{
    const int i    = blockIdx.x;
    const int xcd  = i & 7;
    const int j    = i >> 3;
    const int pair = xcd * 8 + (j >> 5);
    const int qt   = j & 31;
    const int side = pair >> 5;
    const int b    = pair & 31;

    const float* __restrict__ Q   = side ? x2 : x1;
    const float* __restrict__ K   = side ? x1 : x2;
    const float* __restrict__ MK  = side ? m1 : m2;
    float* __restrict__       OUT = side ? o2 : o1;

    const int tid  = threadIdx.x;
    const int lane = tid & 63;
    const int w    = tid >> 6;
    const int lr   = lane & 15;
    const int lg   = lane >> 4;
    const int q0 = qt * 16;
    const int d0 = w * DSL;

    __shared__ float sred[4][16][36];
    __shared__ float mask_s[LKN];
    for (int t = tid; t < LKN; t += 256) mask_s[t] = MK[t * BB + b];

    half8 qf[6];
    {
        const float* qrow = Q + ((q0 + lr) * BB + b) * DD + d0 + lg * 8;
        #pragma unroll
        for (int ks = 0; ks < 6; ++ks) {
            f4 a = *(const f4*)(qrow + ks * 32);
            f4 c = *(const f4*)(qrow + ks * 32 + 4);
            qf[ks] = cvt8(a, c);
        }
    }
    f4 acc[12];
    #pragma unroll
    for (int t = 0; t < 12; ++t) acc[t] = f4{0.f, 0.f, 0.f, 0.f};
    float Mrun = -3.0e38f, Lrun = 0.f;
    for (int kt = 0; kt < 16; ++kt) {
        const int k0 = kt * 32;
        f4 s0 = {0.f,0.f,0.f,0.f}, s1 = {0.f,0.f,0.f,0.f};
        {
            const float* kb0 = K + ((k0 + lr) * BB + b) * DD + d0 + lg * 8;
            const float* kb1 = kb0 + 16 * BB * DD;
            #pragma unroll
            for (int ks = 0; ks < 6; ++ks) {
                f4 a0 = *(const f4*)(kb0 + ks * 32);
                f4 c0 = *(const f4*)(kb0 + ks * 32 + 4);
                s0 = __builtin_amdgcn_mfma_f32_16x16x32_f16(qf[ks], cvt8(a0, c0), s0, 0, 0, 0);
                f4 a1 = *(const f4*)(kb1 + ks * 32);
                f4 c1 = *(const f4*)(kb1 + ks * 32 + 4);
                s1 = __builtin_amdgcn_mfma_f32_16x16x32_f16(qf[ks], cvt8(a1, c1), s1, 0, 0, 0);
            }
        }
        __syncthreads();
        #pragma unroll
        for (int r = 0; r < 4; ++r) {
            sred[w][4 * lg + r][lr]      = s0[r];
            sred[w][4 * lg + r][16 + lr] = s1[r];
        }
        __syncthreads();
        f4 sa = {0.f,0.f,0.f,0.f}, sb = {0.f,0.f,0.f,0.f};
        #pragma unroll
        for (int ww = 0; ww < 4; ++ww) {
            sa += *(const f4*)&sred[ww][lr][lg * 8];
            sb += *(const f4*)&sred[ww][lr][lg * 8 + 4];
        }
        float tmax = fmaxf(fmaxf(fmaxf(sa[0], sa[1]), fmaxf(sa[2], sa[3])),
                           fmaxf(fmaxf(sb[0], sb[1]), fmaxf(sb[2], sb[3])));
        tmax = fmaxf(tmax, __shfl_xor(tmax, 16));
        tmax = fmaxf(tmax, __shfl_xor(tmax, 32));
        const float Mnew  = fmaxf(Mrun, tmax);
        const float scale = __expf(Mrun - Mnew);
        float p[8];
        float psum = 0.f;
        const float* mrow = &mask_s[k0 + lg * 8];
        #pragma unroll
        for (int t = 0; t < 4; ++t) { p[t]     = __expf(sa[t] - Mnew) * mrow[t];     psum += p[t]; }
        #pragma unroll
        for (int t = 0; t < 4; ++t) { p[4 + t] = __expf(sb[t] - Mnew) * mrow[4 + t]; psum += p[4 + t]; }
        psum += __shfl_xor(psum, 16);
        psum += __shfl_xor(psum, 32);
        Lrun = Lrun * scale + psum;
        Mrun = Mnew;
        H8 pf;
        pf.u[0] = pk2(p[0], p[1]); pf.u[1] = pk2(p[2], p[3]);
        pf.u[2] = pk2(p[4], p[5]); pf.u[3] = pk2(p[6], p[7]);
        float sc[4];
        #pragma unroll
        for (int r = 0; r < 4; ++r) sc[r] = __shfl(scale, (lane & 48) + 4 * lg + r);
        #pragma unroll
        for (int t = 0; t < 12; ++t) {
            acc[t][0] *= sc[0]; acc[t][1] *= sc[1];
            acc[t][2] *= sc[2]; acc[t][3] *= sc[3];
        }
        const float* vb = K + ((k0 + lg * 8) * BB + b) * DD + d0 + lr;
        #pragma unroll
        for (int nt = 0; nt < 12; ++nt) {
            const float* vp = vb + nt * 16;
            float vv[8];
            #pragma unroll
            for (int t = 0; t < 8; ++t) vv[t] = vp[t * BB * DD];
            H8 vf;
            vf.u[0] = pk2(vv[0], vv[1]); vf.u[1] = pk2(vv[2], vv[3]);
            vf.u[2] = pk2(vv[4], vv[5]); vf.u[3] = pk2(vv[6], vv[7]);
            acc[nt] = __builtin_amdgcn_mfma_f32_16x16x32_f16(pf.h, vf.h, acc[nt], 0, 0, 0);
        }
    }
    float il[4];
    {
        const float inv = 1.f / (Lrun + 1e-8f);
        #pragma unroll
        for (int r = 0; r < 4; ++r) il[r] = __shfl(inv, (lane & 48) + 4 * lg + r);
    }
    #pragma unroll
    for (int nt = 0; nt < 12; ++nt) {
        #pragma unroll
        for (int r = 0; r < 4; ++r) {
            OUT[((q0 + 4 * lg + r) * BB + b) * DD + d0 + nt * 16 + lr] = acc[nt][r] * il[r];
        }
    }
}

extern "C" void kernel_launch(void* const* d_in, const int* in_sizes, int n_in,
                              void* d_out, int out_size, void* d_ws, size_t ws_size,
                              hipStream_t stream) {
    (void)in_sizes; (void)n_in; (void)out_size;
    const float* x1 = (const float*)d_in[0];
    const float* m1 = (const float*)d_in[1];
    const float* x2 = (const float*)d_in[2];
    const float* m2 = (const float*)d_in[3];
    float* o1 = (float*)d_out;
    float* o2 = o1 + (size_t)LQ * BB * DD;

    const size_t ELEMS = (size_t)LQ * BB * DD;           // 12.58M
    const size_t SELEM = (size_t)BB * 512 * 512;         // 8.39M
    const size_t NEED  = 4 * ELEMS * sizeof(_Float16)    // XF + XV (100.7 MB)
                       + SELEM * sizeof(float);          // S f32 (33.6 MB) = 134.2 MB

    if (ws_size >= NEED) {
        _Float16* xf1 = (_Float16*)d_ws;
        _Float16* xf2 = xf1 + ELEMS;
        _Float16* xv1 = xf2 + ELEMS;
        _Float16* xv2 = xv1 + ELEMS;
        float*    S32 = (float*)(xv2 + ELEMS);           // dedicated 33.6 MB
        float*    PF1 = (float*)d_ws;                    // overlays XF (dead after gemm_s)
        prep_pack<<<3072, 256, 0, stream>>>(x1, x2, xf1, xf2, xv1, xv2);
        gemm_s<<<512, 256, 0, stream>>>(xf1, xf2, S32);
        softmax_col_pf<<<512, 256, 0, stream>>>(S32, PF1, m1);   // reads pristine S
        softmax_row_pf<<<512, 256, 0, stream>>>(S32, m2);        // overwrites S in place
        pv_frag<<<2048, 256, 0, stream>>>(S32, PF1, xv1, xv2, o1, o2);
    } else {
        coatt_flash_f32<<<2048, 256, 0, stream>>>(x1, m1, x2, m2, o1, o2);
    }
}

// Round 17
// 142.209 us; speedup vs baseline: 1.5563x; 1.0116x over previous
//
#include <hip/hip_runtime.h>

// Problem constants
#define LQ  512
#define LKN 512
#define BB  32
#define DD  768
#define DSL (DD / 4)

typedef float    f4     __attribute__((ext_vector_type(4)));
typedef _Float16 half8  __attribute__((ext_vector_type(8)));
typedef _Float16 half4  __attribute__((ext_vector_type(4)));
typedef __fp16   fp16x2 __attribute__((ext_vector_type(2)));

union H8 { half8 h; unsigned int u[4]; };

__device__ __forceinline__ unsigned int pk2(float a, float b) {
    union { fp16x2 h; unsigned int u; } c;
    c.h = __builtin_amdgcn_cvt_pkrtz(a, b);
    return c.u;
}
__device__ __forceinline__ half8 cvt8(f4 a, f4 b) {
    H8 r;
    r.u[0] = pk2(a[0], a[1]); r.u[1] = pk2(a[2], a[3]);
    r.u[2] = pk2(b[0], b[1]); r.u[3] = pk2(b[2], b[3]);
    return r.h;
}

// Forced-in-flight global loads (volatile asm cannot be sunk by the scheduler).
__device__ __forceinline__ void gload16(half8& dst, const _Float16* p) {
    asm volatile("global_load_dwordx4 %0, %1, off" : "=v"(dst) : "v"(p));
}
__device__ __forceinline__ void gloadf4(f4& dst, const float* p) {
    asm volatile("global_load_dwordx4 %0, %1, off" : "=v"(dst) : "v"(p));
}

// ---------------------------------------------------------------------------
// prep_pack: 3072 blocks, 64 l x 128 d per block. Writes XF (QK^T fragments)
// and XV (PV B-fragments).
// ---------------------------------------------------------------------------
__global__ __launch_bounds__(256)
void prep_pack(const float* __restrict__ x1, const float* __restrict__ x2,
               _Float16* __restrict__ xf1, _Float16* __restrict__ xf2,
               _Float16* __restrict__ xv1, _Float16* __restrict__ xv2)
{
    const int bi   = blockIdx.x;            // 3072
    const int side = bi / 1536;
    const int rem  = bi % 1536;
    const int b    = rem / 48;
    const int rem2 = rem % 48;
    const int l0   = (rem2 / 6) * 64;
    const int d0   = (rem2 % 6) * 128;

    const float* __restrict__ X  = side ? x2  : x1;
    _Float16* __restrict__    XF = side ? xf2 : xf1;
    _Float16* __restrict__    XV = side ? xv2 : xv1;

    __shared__ _Float16 T[64][136];         // 64 x 128 data + pad

    const int tid = threadIdx.x;
    {
        const int r  = tid >> 4;            // 0..15
        const int c8 = (tid & 15) * 8;      // 0..120
        const float* src = X + ((size_t)(l0 + r) * BB + b) * DD + d0 + c8;
        f4 v[8];
        #pragma unroll
        for (int k = 0; k < 4; ++k) {
            gloadf4(v[2 * k],     src + (size_t)k * 16 * BB * DD);
            gloadf4(v[2 * k + 1], src + (size_t)k * 16 * BB * DD + 4);
        }
        asm volatile("s_waitcnt vmcnt(0)" ::: "memory");
        __builtin_amdgcn_sched_barrier(0);
        #pragma unroll
        for (int k = 0; k < 4; ++k) {
            half4 ha, hb;
            ha[0] = (_Float16)v[2*k][0]; ha[1] = (_Float16)v[2*k][1];
            ha[2] = (_Float16)v[2*k][2]; ha[3] = (_Float16)v[2*k][3];
            hb[0] = (_Float16)v[2*k+1][0]; hb[1] = (_Float16)v[2*k+1][1];
            hb[2] = (_Float16)v[2*k+1][2]; hb[3] = (_Float16)v[2*k+1][3];
            *(half4*)&T[r + 16 * k][c8]     = ha;
            *(half4*)&T[r + 16 * k][c8 + 4] = hb;
        }
    }
    __syncthreads();
    // XF: fragment-packed (A/B operand for QK^T): 1024 chunks, 4 per thread
    #pragma unroll
    for (int c2 = tid; c2 < 1024; c2 += 256) {
        const int dhalf = c2 >> 9;          // 0..1
        const int t16l  = (c2 >> 7) & 3;
        const int ksl   = (c2 >> 6) & 1;
        const int ln    = c2 & 63;
        half8 v = *(const half8*)&T[t16l * 16 + (ln & 15)][dhalf * 64 + ksl * 32 + (ln >> 4) * 8];
        const size_t t16g = (size_t)(l0 >> 4) + t16l;
        const size_t ksg  = (size_t)(d0 >> 5) + dhalf * 2 + ksl;
        *(half8*)(XF + (((size_t)b * 32 + t16g) * 24 + ksg) * 512 + ln * 8) = v;
    }
    // XV: B-fragment-packed V: 1024 chunks, 4 per thread
    #pragma unroll
    for (int c2 = tid; c2 < 1024; c2 += 256) {
        const int dtl  = c2 >> 7;           // 0..7
        const int ks2l = (c2 >> 6) & 1;
        const int ln   = c2 & 63;
        half8 v;
        #pragma unroll
        for (int jj = 0; jj < 8; ++jj)
            v[jj] = T[ks2l * 32 + (ln >> 4) * 8 + jj][dtl * 16 + (ln & 15)];
        const size_t dtg  = (size_t)(d0 >> 4) + dtl;
        const size_t ks2g = (size_t)(l0 >> 5) + ks2l;
        *(half8*)(XV + (((size_t)b * 48 + dtg) * 16 + ks2g) * 512 + ln * 8) = v;
    }
}

// ---------------------------------------------------------------------------
// Stage 1: S = x1.x2^T (f32), 128x128 tile/block, no LDS.
// ---------------------------------------------------------------------------
__global__ __launch_bounds__(256, 3)
void gemm_s(const _Float16* __restrict__ xf1, const _Float16* __restrict__ xf2,
            float* __restrict__ S)
{
    const int i   = blockIdx.x;            // 512
    const int xcd = i & 7;
    const int j   = i >> 3;                // 0..63
    const int t   = j & 15;                // tile fastest
    const int b   = xcd * 4 + (j >> 4);    // b slowest
    const int lt  = t >> 2, mt = t & 3;
    const int l0b = lt * 128, m0b = mt * 128;

    const int tid  = threadIdx.x;
    const int lane = tid & 63;
    const int w    = tid >> 6;
    const int wl   = w >> 1, wm = w & 1;
    const int lr   = lane & 15;
    const int lg   = lane >> 4;

    f4 acc[16];
    #pragma unroll
    for (int t2 = 0; t2 < 16; ++t2) acc[t2] = f4{0.f, 0.f, 0.f, 0.f};

    {
        const _Float16* ab = xf1 + (((size_t)b * 32 + lt * 8 + wl * 4) * 24) * 512 + lane * 8;
        const _Float16* bb = xf2 + (((size_t)b * 32 + mt * 8 + wm * 4) * 24) * 512 + lane * 8;
        __builtin_amdgcn_s_setprio(1);
        #pragma unroll
        for (int ks = 0; ks < 24; ++ks) {
            half8 aF[4], bF[4];
            #pragma unroll
            for (int q = 0; q < 4; ++q) {
                aF[q] = *(const half8*)(ab + ((size_t)q * 24 + ks) * 512);
                bF[q] = *(const half8*)(bb + ((size_t)q * 24 + ks) * 512);
            }
            #pragma unroll
            for (int q = 0; q < 4; ++q)
                #pragma unroll
                for (int p = 0; p < 4; ++p)
                    acc[q * 4 + p] = __builtin_amdgcn_mfma_f32_16x16x32_f16(aF[q], bF[p], acc[q * 4 + p], 0, 0, 0);
        }
        __builtin_amdgcn_s_setprio(0);
    }

    {
        float* srow = S + ((size_t)b * 512 + l0b + wl * 64) * 512 + m0b + wm * 64;
        #pragma unroll
        for (int q = 0; q < 4; ++q)
            #pragma unroll
            for (int p = 0; p < 4; ++p)
                #pragma unroll
                for (int r = 0; r < 4; ++r)
                    srow[(size_t)(q * 16 + 4 * lg + r) * 512 + p * 16 + lr] = acc[q * 4 + p][r];
    }
}

// ---------------------------------------------------------------------------
// Stage 2a: COLUMN softmax (side 1) reading pristine f32 S; writes PF1
// (fragment-packed) into the old-XF region. Runs BEFORE the row pass.
// ---------------------------------------------------------------------------
__global__ __launch_bounds__(256)
void softmax_col_pf(const float* __restrict__ S32, float* __restrict__ PF1,
                    const float* __restrict__ m1)
{
    const int i  = blockIdx.x;             // 512
    const int b  = i >> 4;
    const int ct = i & 15;                 // 16 col-groups of 32

    const int tid = threadIdx.x;

    __shared__ float raw[32][513];         // [col][row]
    __shared__ float mask_s[LKN];
    __shared__ float redm[8][32];
    __shared__ float reds[8][32];

    mask_s[tid] = m1[tid * BB + b];
    mask_s[tid + 256] = m1[(tid + 256) * BB + b];

    {
        const float* sbase = S32 + ((size_t)b * 512 + (tid >> 3)) * 512 + ct * 32 + (tid & 7) * 4;
        f4 vv[16];
        #pragma unroll
        for (int it = 0; it < 8; ++it) gloadf4(vv[it], sbase + (size_t)it * 32 * 512);
        asm volatile("s_waitcnt vmcnt(0)" ::: "memory");
        __builtin_amdgcn_sched_barrier(0);
        #pragma unroll
        for (int it = 8; it < 16; ++it) gloadf4(vv[it], sbase + (size_t)it * 32 * 512);
        #pragma unroll
        for (int it = 0; it < 8; ++it) {
            const int row = it * 32 + (tid >> 3);
            const int c0  = (tid & 7) * 4;
            raw[c0 + 0][row] = vv[it][0]; raw[c0 + 1][row] = vv[it][1];
            raw[c0 + 2][row] = vv[it][2]; raw[c0 + 3][row] = vv[it][3];
        }
        asm volatile("s_waitcnt vmcnt(0)" ::: "memory");
        __builtin_amdgcn_sched_barrier(0);
        #pragma unroll
        for (int it = 8; it < 16; ++it) {
            const int row = it * 32 + (tid >> 3);
            const int c0  = (tid & 7) * 4;
            raw[c0 + 0][row] = vv[it][0]; raw[c0 + 1][row] = vv[it][1];
            raw[c0 + 2][row] = vv[it][2]; raw[c0 + 3][row] = vv[it][3];
        }
    }
    __syncthreads();

    const int col = tid & 31;
    const int seg = tid >> 5;              // 0..7, rows seg*64..+63

    float m = -3.0e38f;
    #pragma unroll
    for (int r = 0; r < 64; ++r) m = fmaxf(m, raw[col][seg * 64 + r]);
    redm[seg][col] = m;
    __syncthreads();
    float M = redm[0][col];
    #pragma unroll
    for (int s2 = 1; s2 < 8; ++s2) M = fmaxf(M, redm[s2][col]);

    float s = 0.f;
    #pragma unroll
    for (int r = 0; r < 64; ++r) {
        const int row = seg * 64 + r;
        s += __expf(raw[col][row] - M) * mask_s[row];
    }
    reds[seg][col] = s;
    __syncthreads();
    float L = 0.f;
    #pragma unroll
    for (int s2 = 0; s2 < 8; ++s2) L += reds[s2][col];
    const float inv = 1.f / (L + 1e-8f);

    const int col_g = ct * 32 + col;
    char* pfb = (char*)PF1 + ((size_t)b * 512 + (size_t)(col_g >> 4) * 16) * 2048;
    #pragma unroll
    for (int kc = 0; kc < 8; ++kc) {
        const int k0 = seg * 64 + kc * 8;
        float e[8];
        #pragma unroll
        for (int j = 0; j < 8; ++j)
            e[j] = __expf(raw[col][k0 + j] - M) * mask_s[k0 + j] * inv;
        H8 o;
        o.u[0] = pk2(e[0], e[1]); o.u[1] = pk2(e[2], e[3]);
        o.u[2] = pk2(e[4], e[5]); o.u[3] = pk2(e[6], e[7]);
        const int lane_w = seg * 8 + kc;
        *(half8*)(pfb + (lane_w >> 2) * 1024 + (lane_w & 3) * 256 + (col_g & 15) * 16) = o.h;
    }
}

// ---------------------------------------------------------------------------
// Stage 2b: ROW softmax (side 0); writes PF0 in-place into S32 row slots.
// ---------------------------------------------------------------------------
__global__ __launch_bounds__(256)
void softmax_row_pf(float* __restrict__ S32, const float* __restrict__ m2)
{
    const int i  = blockIdx.x;             // 512
    const int b  = i >> 4;
    const int rt = i & 15;

    const int tid  = threadIdx.x;
    const int lane = tid & 63;
    const int w    = tid >> 6;

    __shared__ float mask_s[LKN];
    mask_s[tid] = m2[tid * BB + b];
    mask_s[tid + 256] = m2[(tid + 256) * BB + b];
    __syncthreads();

    float mk[8];
    #pragma unroll
    for (int j = 0; j < 8; ++j) mk[j] = mask_s[lane * 8 + j];

    const int row0 = rt * 32 + w * 8;

    f4 fa[8], fb[8];
    #pragma unroll
    for (int rr = 0; rr < 8; ++rr) {
        const float* rp = S32 + ((size_t)b * 512 + row0 + rr) * 512 + lane * 8;
        fa[rr] = *(const f4*)rp;
        fb[rr] = *(const f4*)(rp + 4);
    }

    H8 outw[8];
    #pragma unroll
    for (int rr = 0; rr < 8; ++rr) {
        float f[8] = {fa[rr][0], fa[rr][1], fa[rr][2], fa[rr][3],
                      fb[rr][0], fb[rr][1], fb[rr][2], fb[rr][3]};
        float m = fmaxf(fmaxf(fmaxf(f[0], f[1]), fmaxf(f[2], f[3])),
                        fmaxf(fmaxf(f[4], f[5]), fmaxf(f[6], f[7])));
        #pragma unroll
        for (int d = 1; d <= 32; d <<= 1) m = fmaxf(m, __shfl_xor(m, d));
        float e[8], s = 0.f;
        #pragma unroll
        for (int j = 0; j < 8; ++j) { e[j] = __expf(f[j] - m) * mk[j]; s += e[j]; }
        #pragma unroll
        for (int d = 1; d <= 32; d <<= 1) s += __shfl_xor(s, d);
        const float inv = 1.f / (s + 1e-8f);
        outw[rr].u[0] = pk2(e[0] * inv, e[1] * inv);
        outw[rr].u[1] = pk2(e[2] * inv, e[3] * inv);
        outw[rr].u[2] = pk2(e[4] * inv, e[5] * inv);
        outw[rr].u[3] = pk2(e[6] * inv, e[7] * inv);
    }

    __syncthreads();   // all rows of this block read before any PF write

    #pragma unroll
    for (int rr = 0; rr < 8; ++rr) {
        const int row = row0 + rr;
        char* base = (char*)S32 + ((size_t)b * 512 + (size_t)(row >> 4) * 16) * 2048;
        char* dst  = base + (lane >> 2) * 1024 + (lane & 3) * 256 + (row & 15) * 16;
        *(half8*)dst = outw[rr].h;
    }
}

// ---------------------------------------------------------------------------
// Stage 3: OUT = P.V, fragment-direct, double-buffered with COUNTED vmcnt:
// batch cb+1's 14 loads stay in flight across batch cb's 24 MFMAs
// (s_waitcnt vmcnt(14), never 0 until the last batch).
// ---------------------------------------------------------------------------
__global__ __launch_bounds__(256)
void pv_frag(const float* __restrict__ S32, const float* __restrict__ ST32,
             const _Float16* __restrict__ xv1, const _Float16* __restrict__ xv2,
             float* __restrict__ o1, float* __restrict__ o2)
{
    const int i    = blockIdx.x;           // 2048
    const int xcd  = i & 7;
    const int j    = i >> 3;               // 0..255
    const int lt   = j & 7;                // fastest (8 l-tiles of 64 rows)
    const int dq   = (j >> 3) & 3;         // 4 d-quarters of 192
    const int side = (j >> 5) & 1;
    const int b    = xcd * 4 + (j >> 6);   // slowest
    const int l0   = lt * 64;

    const float* __restrict__ P32   = side ? ST32 : S32;
    const _Float16* __restrict__ VF = side ? xv1 : xv2;   // V = other side
    float* __restrict__ OUT         = side ? o2 : o1;

    const int tid  = threadIdx.x;
    const int lane = tid & 63;
    const int w    = tid >> 6;
    const int lr   = lane & 15;
    const int lg   = lane >> 4;

    const char* pb[4];
    #pragma unroll
    for (int q = 0; q < 4; ++q)
        pb[q] = (const char*)P32 + ((size_t)b * 512 + (size_t)(lt * 4 + q) * 16) * 2048 + lane * 16;
    const _Float16* vbase = VF + (((size_t)b * 48 + dq * 12 + w * 3) * 16) * 512 + lane * 8;

    f4 acc[12];                            // [q][nt]
    #pragma unroll
    for (int t = 0; t < 12; ++t) acc[t] = f4{0.f, 0.f, 0.f, 0.f};

    half8 pa[2][2][4], vf[2][2][3];        // [buf][k2][...]

    // prologue: issue batch 0 into buf 0
    #pragma unroll
    for (int k2 = 0; k2 < 2; ++k2) {
        #pragma unroll
        for (int q = 0; q < 4; ++q)
            gload16(pa[0][k2][q], (const _Float16*)(pb[q] + k2 * 1024));
        #pragma unroll
        for (int nt = 0; nt < 3; ++nt)
            gload16(vf[0][k2][nt], vbase + ((size_t)nt * 16 + k2) * 512);
    }

    #pragma unroll
    for (int cb = 0; cb < 8; ++cb) {       // 8 batches x 2 ks2; cur=cb&1
        const int cur = cb & 1;
        const int nxt = cur ^ 1;
        if (cb < 7) {                      // issue batch cb+1 into the other buffer
            #pragma unroll
            for (int k2 = 0; k2 < 2; ++k2) {
                const int ks2 = (cb + 1) * 2 + k2;
                #pragma unroll
                for (int q = 0; q < 4; ++q)
                    gload16(pa[nxt][k2][q], (const _Float16*)(pb[q] + ks2 * 1024));
                #pragma unroll
                for (int nt = 0; nt < 3; ++nt)
                    gload16(vf[nxt][k2][nt], vbase + ((size_t)nt * 16 + ks2) * 512);
            }
            asm volatile("s_waitcnt vmcnt(14)" ::: "memory");   // batch cb done, cb+1 in flight
        } else {
            asm volatile("s_waitcnt vmcnt(0)" ::: "memory");
        }
        __builtin_amdgcn_sched_barrier(0);   // rule #18: no MFMA hoisted above the wait
        __builtin_amdgcn_s_setprio(1);
        #pragma unroll
        for (int k2 = 0; k2 < 2; ++k2)
            #pragma unroll
            for (int nt = 0; nt < 3; ++nt)
                #pragma unroll
                for (int q = 0; q < 4; ++q)
                    acc[q * 3 + nt] = __builtin_amdgcn_mfma_f32_16x16x32_f16(pa[cur][k2][q], vf[cur][k2][nt], acc[q * 3 + nt], 0, 0, 0);
        __builtin_amdgcn_s_setprio(0);
    }

    #pragma unroll
    for (int q = 0; q < 4; ++q)
        #pragma unroll
        for (int nt = 0; nt < 3; ++nt)
            #pragma unroll
            for (int r = 0; r < 4; ++r)
                OUT[((size_t)(l0 + q * 16 + 4 * lg + r) * BB + b) * DD + dq * 192 + (w * 3 + nt) * 16 + lr]
                    = acc[q * 3 + nt][r];
}

// ---------------------------------------------------------------------------
// Fallback (f32 direct, no ws).
// ---------------------------------------------------------------------------
__global__ __launch_bounds__(256)
void coatt_flash_f32(const float* __restrict__ x1, const float* __restrict__ m1,
                     const float* __restrict__ x2, const float* __restrict__ m2,
                     float* __restrict__ o1, float* __restrict__ o2)
{
    const int i    = blockIdx.x;
    const int xcd  = i & 7;
    const int j    = i >> 3;
    const int pair = xcd * 8 + (j >> 5);
    const int qt   = j & 31;
    const int side = pair >> 5;
    const int b    = pair & 31;

    const float* __restrict__ Q   = side ? x2 : x1;
    const float* __restrict__ K   = side ? x1 : x2;
    const float* __restrict__ MK  = side ? m1 : m2;
    float* __restrict__       OUT = side ? o2 : o1;

    const int tid  = threadIdx.x;
    const int lane = tid & 63;
    const int w    = tid >> 6;
    const int lr   = lane & 15;
    const int lg   = lane >> 4;
    const int q0 = qt * 16;
    const int d0 = w * DSL;

    __shared__ float sred[4][16][36];
    __shared__ float mask_s[LKN];
    for (int t = tid; t < LKN; t += 256) mask_s[t] = MK[t * BB + b];

    half8 qf[6];
    {
        const float* qrow = Q + ((q0 + lr) * BB + b) * DD + d0 + lg * 8;
        #pragma unroll
        for (int ks = 0; ks < 6; ++ks) {
            f4 a = *(const f4*)(qrow + ks * 32);
            f4 c = *(const f4*)(qrow + ks * 32 + 4);
            qf[ks] = cvt8(a, c);
        }
    }
    f4 acc[12];
    #pragma unroll
    for (int t = 0; t < 12; ++t) acc[t] = f4{0.f, 0.f, 0.f, 0.f};
    float Mrun = -3.0e38f, Lrun = 0.f;
    for (int kt = 0; kt < 16; ++kt) {
        const int k0 = kt * 32;
        f4 s0 = {0.f,0.f,0.f,0.f}, s1 = {0.f,0.f,0.f,0.f};
        {
            const float* kb0 = K + ((k0 + lr) * BB + b) * DD + d0 + lg * 8;
            const float* kb1 = kb0 + 16 * BB * DD;
            #pragma unroll
            for (int ks = 0; ks < 6; ++ks) {
                f4 a0 = *(const f4*)(kb0 + ks * 32);
                f4 c0 = *(const f4*)(kb0 + ks * 32 + 4);
                s0 = __builtin_amdgcn_mfma_f32_16x16x32_f16(qf[ks], cvt8(a0, c0), s0, 0, 0, 0);
                f4 a1 = *(const f4*)(kb1 + ks * 32);
                f4 c1 = *(const f4*)(kb1 + ks * 32 + 4);
                s1 = __builtin_amdgcn_mfma_f32_16x16x32_f16(qf[ks], cvt8(a1, c1), s1, 0, 0, 0);
            }
        }
        __syncthreads();
        #pragma unroll
        for (int r = 0; r < 4; ++r) {
            sred[w][4 * lg + r][lr]      = s0[r];
            sred[w][4 * lg + r][16 + lr] = s1[r];
        }
        __syncthreads();
        f4 sa = {0.f,0.f,0.f,0.f}, sb = {0.f,0.f,0.f,0.f};
        #pragma unroll
        for (int ww = 0; ww < 4; ++ww) {
            sa += *(const f4*)&sred[ww][lr][lg * 8];
            sb += *(const f4*)&sred[ww][lr][lg * 8 + 4];
        }
        float tmax = fmaxf(fmaxf(fmaxf(sa[0], sa[1]), fmaxf(sa[2], sa[3])),
                           fmaxf(fmaxf(sb[0], sb[1]), fmaxf(sb[2], sb[3])));
        tmax = fmaxf(tmax, __shfl_xor(tmax, 16));
        tmax = fmaxf(tmax, __shfl_xor(tmax, 32));
        const float Mnew  = fmaxf(Mrun, tmax);
        const float scale = __expf(Mrun - Mnew);
        float p[8];
        float psum = 0.f;
        const float* mrow = &mask_s[k0 + lg * 8];
        #pragma unroll
        for (int t = 0; t < 4; ++t) { p[t]     = __expf(sa[t] - Mnew) * mrow[t];     psum += p[t]; }
        #pragma unroll
        for (int t = 0; t < 4; ++t) { p[4 + t] = __expf(sb[t] - Mnew) * mrow[4 + t]; psum += p[4 + t]; }
        psum += __shfl_xor(psum, 16);
        psum += __shfl_xor(psum, 32);
        Lrun = Lrun * scale + psum;
        Mrun = Mnew;
        H8 pf;
        pf.u[0] = pk2(p[0], p[1]); pf.u[1] = pk2(p[2], p[3]);
        pf.u[2] = pk2(p[4], p[5]); pf.u[3] = pk2(p[6], p[7]);
        float sc[4];
        #pragma unroll
        for (int r = 0; r < 4; ++r) sc[r] = __shfl(scale, (lane & 48) + 4 * lg + r);
        #pragma unroll
        for (int t = 0; t < 12; ++t) {
            acc[t][0] *= sc[0]; acc[t][1] *= sc[1];
            acc[t][2] *= sc[2]; acc[t][3] *= sc[3];
        }
        const float* vb = K + ((k0 + lg * 8) * BB + b) * DD + d0 + lr;
        #pragma unroll
        for (int nt = 0; nt < 12; ++nt) {
            const float* vp = vb + nt * 16;
            float vv[8];
            #pragma unroll
            for (int t = 0; t < 8; ++t) vv[t] = vp[t * BB * DD];
            H8 vf;
            vf.u[0] = pk2(vv[0], vv[1]); vf.u[1] = pk2(vv[2], vv[3]);
            vf.u[2] = pk2(vv[4], vv[5]); vf.u[3] = pk2(vv[6], vv[7]);
            acc[nt] = __builtin_amdgcn_mfma_f32_16x16x32_f16(pf.h, vf.h, acc[nt], 0, 0, 0);
        }
    }
    float il[4];
    {
        const float inv = 1.f / (Lrun + 1e-8f);
        #pragma unroll
        for (int r = 0; r < 4; ++r) il[r] = __shfl(inv, (lane & 48) + 4 * lg + r);
    }
    #pragma unroll
    for (int nt = 0; nt < 12; ++nt) {
        #pragma unroll
        for (int r = 0; r < 4; ++r) {
            OUT[((q0 + 4 * lg + r) * BB + b) * DD + d0 + nt * 16 + lr] = acc[nt][r] * il[r];
        }
    }
}

extern "C" void kernel_launch(void* const* d_in, const int* in_sizes, int n_in,
                              void* d_out, int out_size, void* d_ws, size_t ws_size,
                              hipStream_t stream) {
    (void)in_sizes; (void)n_in; (void)out_size;
    const float* x1 = (const float*)d_in[0];
    const float* m1 = (const float*)d_in[1];
    const float* x2 = (const float*)d_in[2];
    const float* m2 = (const float*)d_in[3];
    float* o1 = (float*)d_out;
    float* o2 = o1 + (size_t)LQ * BB * DD;

    const size_t ELEMS = (size_t)LQ * BB * DD;           // 12.58M
    const size_t SELEM = (size_t)BB * 512 * 512;         // 8.39M
    const size_t NEED  = 4 * ELEMS * sizeof(_Float16)    // XF + XV (100.7 MB)
                       + SELEM * sizeof(float);          // S f32 (33.6 MB) = 134.2 MB

    if (ws_size >= NEED) {
        _Float16* xf1 = (_Float16*)d_ws;
        _Float16* xf2 = xf1 + ELEMS;
        _Float16* xv1 = xf2 + ELEMS;
        _Float16* xv2 = xv1 + ELEMS;
        float*    S32 = (float*)(xv2 + ELEMS);           // dedicated 33.6 MB
        float*    PF1 = (float*)d_ws;                    // overlays XF (dead after gemm_s)
        prep_pack<<<3072, 256, 0, stream>>>(x1, x2, xf1, xf2, xv1, xv2);
        gemm_s<<<512, 256, 0, stream>>>(xf1, xf2, S32);
        softmax_col_pf<<<512, 256, 0, stream>>>(S32, PF1, m1);   // reads pristine S
        softmax_row_pf<<<512, 256, 0, stream>>>(S32, m2);        // overwrites S in place
        pv_frag<<<2048, 256, 0, stream>>>(S32, PF1, xv1, xv2, o1, o2);
    } else {
        coatt_flash_f32<<<2048, 256, 0, stream>>>(x1, m1, x2, m2, o1, o2);
    }
}

// Round 18
// 135.020 us; speedup vs baseline: 1.6392x; 1.0533x over previous
//
#include <hip/hip_runtime.h>

// Problem constants
#define LQ  512
#define LKN 512
#define BB  32
#define DD  768

typedef float    f4     __attribute__((ext_vector_type(4)));
typedef _Float16 half8  __attribute__((ext_vector_type(8)));
typedef _Float16 half4  __attribute__((ext_vector_type(4)));
typedef __fp16   fp16x2 __attribute__((ext_vector_type(2)));

union H8 { half8 h; unsigned int u[4]; };

__device__ __forceinline__ unsigned int pk2(float a, float b) {
    union { fp16x2 h; unsigned int u; } c;
    c.h = __builtin_amdgcn_cvt_pkrtz(a, b);
    return c.u;
}
__device__ __forceinline__ half8 cvt8(f4 a, f4 b) {
    H8 r;
    r.u[0] = pk2(a[0], a[1]); r.u[1] = pk2(a[2], a[3]);
    r.u[2] = pk2(b[0], b[1]); r.u[3] = pk2(b[2], b[3]);
    return r.h;
}

// Forced-in-flight global loads (volatile asm cannot be sunk by the scheduler).
__device__ __forceinline__ void gload16(half8& dst, const _Float16* p) {
    asm volatile("global_load_dwordx4 %0, %1, off" : "=v"(dst) : "v"(p));
}
__device__ __forceinline__ void gloadf4(f4& dst, const float* p) {
    asm volatile("global_load_dwordx4 %0, %1, off" : "=v"(dst) : "v"(p));
}

// ---------------------------------------------------------------------------
// prep_pack: 3072 blocks, 64 l x 128 d per block. Writes XF (QK^T fragments)
// and XV (PV B-fragments). Counted-vmcnt split: convert first half while the
// second half of the input loads is still in flight.
// ---------------------------------------------------------------------------
__global__ __launch_bounds__(256)
void prep_pack(const float* __restrict__ x1, const float* __restrict__ x2,
               _Float16* __restrict__ xf1, _Float16* __restrict__ xf2,
               _Float16* __restrict__ xv1, _Float16* __restrict__ xv2)
{
    const int bi   = blockIdx.x;            // 3072
    const int side = bi / 1536;
    const int rem  = bi % 1536;
    const int b    = rem / 48;
    const int rem2 = rem % 48;
    const int l0   = (rem2 / 6) * 64;
    const int d0   = (rem2 % 6) * 128;

    const float* __restrict__ X  = side ? x2  : x1;
    _Float16* __restrict__    XF = side ? xf2 : xf1;
    _Float16* __restrict__    XV = side ? xv2 : xv1;

    __shared__ _Float16 T[64][136];         // 64 x 128 data + pad

    const int tid = threadIdx.x;
    {
        const int r  = tid >> 4;            // 0..15
        const int c8 = (tid & 15) * 8;      // 0..120
        const float* src = X + ((size_t)(l0 + r) * BB + b) * DD + d0 + c8;
        f4 v[8];
        #pragma unroll
        for (int k = 0; k < 4; ++k) {
            gloadf4(v[2 * k],     src + (size_t)k * 16 * BB * DD);
            gloadf4(v[2 * k + 1], src + (size_t)k * 16 * BB * DD + 4);
        }
        asm volatile("s_waitcnt vmcnt(4)" ::: "memory");   // first 4 loads done
        __builtin_amdgcn_sched_barrier(0);
        #pragma unroll
        for (int k = 0; k < 2; ++k) {
            half4 ha, hb;
            ha[0] = (_Float16)v[2*k][0]; ha[1] = (_Float16)v[2*k][1];
            ha[2] = (_Float16)v[2*k][2]; ha[3] = (_Float16)v[2*k][3];
            hb[0] = (_Float16)v[2*k+1][0]; hb[1] = (_Float16)v[2*k+1][1];
            hb[2] = (_Float16)v[2*k+1][2]; hb[3] = (_Float16)v[2*k+1][3];
            *(half4*)&T[r + 16 * k][c8]     = ha;
            *(half4*)&T[r + 16 * k][c8 + 4] = hb;
        }
        asm volatile("s_waitcnt vmcnt(0)" ::: "memory");
        __builtin_amdgcn_sched_barrier(0);
        #pragma unroll
        for (int k = 2; k < 4; ++k) {
            half4 ha, hb;
            ha[0] = (_Float16)v[2*k][0]; ha[1] = (_Float16)v[2*k][1];
            ha[2] = (_Float16)v[2*k][2]; ha[3] = (_Float16)v[2*k][3];
            hb[0] = (_Float16)v[2*k+1][0]; hb[1] = (_Float16)v[2*k+1][1];
            hb[2] = (_Float16)v[2*k+1][2]; hb[3] = (_Float16)v[2*k+1][3];
            *(half4*)&T[r + 16 * k][c8]     = ha;
            *(half4*)&T[r + 16 * k][c8 + 4] = hb;
        }
    }
    __syncthreads();
    // XF: fragment-packed (A/B operand for QK^T): 1024 chunks, 4 per thread
    #pragma unroll
    for (int c2 = tid; c2 < 1024; c2 += 256) {
        const int dhalf = c2 >> 9;          // 0..1
        const int t16l  = (c2 >> 7) & 3;
        const int ksl   = (c2 >> 6) & 1;
        const int ln    = c2 & 63;
        half8 v = *(const half8*)&T[t16l * 16 + (ln & 15)][dhalf * 64 + ksl * 32 + (ln >> 4) * 8];
        const size_t t16g = (size_t)(l0 >> 4) + t16l;
        const size_t ksg  = (size_t)(d0 >> 5) + dhalf * 2 + ksl;
        *(half8*)(XF + (((size_t)b * 32 + t16g) * 24 + ksg) * 512 + ln * 8) = v;
    }
    // XV: B-fragment-packed V: 1024 chunks, 4 per thread
    #pragma unroll
    for (int c2 = tid; c2 < 1024; c2 += 256) {
        const int dtl  = c2 >> 7;           // 0..7
        const int ks2l = (c2 >> 6) & 1;
        const int ln   = c2 & 63;
        half8 v;
        #pragma unroll
        for (int jj = 0; jj < 8; ++jj)
            v[jj] = T[ks2l * 32 + (ln >> 4) * 8 + jj][dtl * 16 + (ln & 15)];
        const size_t dtg  = (size_t)(d0 >> 4) + dtl;
        const size_t ks2g = (size_t)(l0 >> 5) + ks2l;
        *(half8*)(XV + (((size_t)b * 48 + dtg) * 16 + ks2g) * 512 + ln * 8) = v;
    }
}

// ---------------------------------------------------------------------------
// Stage 1: S = x1.x2^T (f32), 128x128 tile/block, no LDS.
// ---------------------------------------------------------------------------
__global__ __launch_bounds__(256, 3)
void gemm_s(const _Float16* __restrict__ xf1, const _Float16* __restrict__ xf2,
            float* __restrict__ S)
{
    const int i   = blockIdx.x;            // 512
    const int xcd = i & 7;
    const int j   = i >> 3;                // 0..63
    const int t   = j & 15;                // tile fastest
    const int b   = xcd * 4 + (j >> 4);    // b slowest
    const int lt  = t >> 2, mt = t & 3;
    const int l0b = lt * 128, m0b = mt * 128;

    const int tid  = threadIdx.x;
    const int lane = tid & 63;
    const int w    = tid >> 6;
    const int wl   = w >> 1, wm = w & 1;
    const int lr   = lane & 15;
    const int lg   = lane >> 4;

    f4 acc[16];
    #pragma unroll
    for (int t2 = 0; t2 < 16; ++t2) acc[t2] = f4{0.f, 0.f, 0.f, 0.f};

    {
        const _Float16* ab = xf1 + (((size_t)b * 32 + lt * 8 + wl * 4) * 24) * 512 + lane * 8;
        const _Float16* bb = xf2 + (((size_t)b * 32 + mt * 8 + wm * 4) * 24) * 512 + lane * 8;
        __builtin_amdgcn_s_setprio(1);
        #pragma unroll
        for (int ks = 0; ks < 24; ++ks) {
            half8 aF[4], bF[4];
            #pragma unroll
            for (int q = 0; q < 4; ++q) {
                aF[q] = *(const half8*)(ab + ((size_t)q * 24 + ks) * 512);
                bF[q] = *(const half8*)(bb + ((size_t)q * 24 + ks) * 512);
            }
            #pragma unroll
            for (int q = 0; q < 4; ++q)
                #pragma unroll
                for (int p = 0; p < 4; ++p)
                    acc[q * 4 + p] = __builtin_amdgcn_mfma_f32_16x16x32_f16(aF[q], bF[p], acc[q * 4 + p], 0, 0, 0);
        }
        __builtin_amdgcn_s_setprio(0);
    }

    {
        float* srow = S + ((size_t)b * 512 + l0b + wl * 64) * 512 + m0b + wm * 64;
        #pragma unroll
        for (int q = 0; q < 4; ++q)
            #pragma unroll
            for (int p = 0; p < 4; ++p)
                #pragma unroll
                for (int r = 0; r < 4; ++r)
                    srow[(size_t)(q * 16 + 4 * lg + r) * 512 + p * 16 + lr] = acc[q * 4 + p][r];
    }
}

// ---------------------------------------------------------------------------
// Stage 2 (FUSED): row softmax (side 0, mask m2 -> PF0) and column softmax
// (side 1, mask m1 -> PF1) in one 1024-block launch. S32 is read-only.
// PF tiles are DENSE: tile (b,t16) at byte (b*32+t16)*16384; intra-tile
// byte = (lw>>2)*1024 + (lw&3)*256 + (row&15)*16 with lw = k/8.
// ---------------------------------------------------------------------------
__global__ __launch_bounds__(256)
void softmax_both(const float* __restrict__ S32, float* __restrict__ PF0,
                  float* __restrict__ PF1,
                  const float* __restrict__ m1, const float* __restrict__ m2)
{
    const int bi   = blockIdx.x;           // 1024
    const int side = bi >> 9;              // 0: row pass, 1: col pass
    const int idx  = bi & 511;
    const int b    = idx >> 4;
    const int t    = idx & 15;

    const int tid  = threadIdx.x;

    if (side == 0) {
        // ---------------- ROW softmax -> PF0 ----------------
        const int lane = tid & 63;
        const int w    = tid >> 6;
        __shared__ float mask_r[LKN];
        mask_r[tid] = m2[tid * BB + b];
        mask_r[tid + 256] = m2[(tid + 256) * BB + b];
        __syncthreads();

        float mk[8];
        #pragma unroll
        for (int j = 0; j < 8; ++j) mk[j] = mask_r[lane * 8 + j];

        const int row0 = t * 32 + w * 8;

        f4 fa[8], fb[8];
        #pragma unroll
        for (int rr = 0; rr < 8; ++rr) {
            const float* rp = S32 + ((size_t)b * 512 + row0 + rr) * 512 + lane * 8;
            fa[rr] = *(const f4*)rp;
            fb[rr] = *(const f4*)(rp + 4);
        }

        #pragma unroll
        for (int rr = 0; rr < 8; ++rr) {
            float f[8] = {fa[rr][0], fa[rr][1], fa[rr][2], fa[rr][3],
                          fb[rr][0], fb[rr][1], fb[rr][2], fb[rr][3]};
            float m = fmaxf(fmaxf(fmaxf(f[0], f[1]), fmaxf(f[2], f[3])),
                            fmaxf(fmaxf(f[4], f[5]), fmaxf(f[6], f[7])));
            #pragma unroll
            for (int d = 1; d <= 32; d <<= 1) m = fmaxf(m, __shfl_xor(m, d));
            float e[8], s = 0.f;
            #pragma unroll
            for (int j = 0; j < 8; ++j) { e[j] = __expf(f[j] - m) * mk[j]; s += e[j]; }
            #pragma unroll
            for (int d = 1; d <= 32; d <<= 1) s += __shfl_xor(s, d);
            const float inv = 1.f / (s + 1e-8f);
            H8 o;
            o.u[0] = pk2(e[0] * inv, e[1] * inv); o.u[1] = pk2(e[2] * inv, e[3] * inv);
            o.u[2] = pk2(e[4] * inv, e[5] * inv); o.u[3] = pk2(e[6] * inv, e[7] * inv);
            const int row = row0 + rr;
            char* base = (char*)PF0 + ((size_t)b * 32 + (row >> 4)) * 16384;
            *(half8*)(base + (lane >> 2) * 1024 + (lane & 3) * 256 + (row & 15) * 16) = o.h;
        }
    } else {
        // ---------------- COLUMN softmax -> PF1 ----------------
        __shared__ float raw[32][513];
        __shared__ float mask_c[LKN];
        __shared__ float redm[8][32];
        __shared__ float reds[8][32];

        mask_c[tid] = m1[tid * BB + b];
        mask_c[tid + 256] = m1[(tid + 256) * BB + b];

        {
            const float* sbase = S32 + ((size_t)b * 512 + (tid >> 3)) * 512 + t * 32 + (tid & 7) * 4;
            f4 vv[16];
            #pragma unroll
            for (int it = 0; it < 8; ++it) gloadf4(vv[it], sbase + (size_t)it * 32 * 512);
            asm volatile("s_waitcnt vmcnt(0)" ::: "memory");
            __builtin_amdgcn_sched_barrier(0);
            #pragma unroll
            for (int it = 8; it < 16; ++it) gloadf4(vv[it], sbase + (size_t)it * 32 * 512);
            #pragma unroll
            for (int it = 0; it < 8; ++it) {
                const int row = it * 32 + (tid >> 3);
                const int c0  = (tid & 7) * 4;
                raw[c0 + 0][row] = vv[it][0]; raw[c0 + 1][row] = vv[it][1];
                raw[c0 + 2][row] = vv[it][2]; raw[c0 + 3][row] = vv[it][3];
            }
            asm volatile("s_waitcnt vmcnt(0)" ::: "memory");
            __builtin_amdgcn_sched_barrier(0);
            #pragma unroll
            for (int it = 8; it < 16; ++it) {
                const int row = it * 32 + (tid >> 3);
                const int c0  = (tid & 7) * 4;
                raw[c0 + 0][row] = vv[it][0]; raw[c0 + 1][row] = vv[it][1];
                raw[c0 + 2][row] = vv[it][2]; raw[c0 + 3][row] = vv[it][3];
            }
        }
        __syncthreads();

        const int col = tid & 31;
        const int seg = tid >> 5;          // 0..7, rows seg*64..+63

        float m = -3.0e38f;
        #pragma unroll
        for (int r = 0; r < 64; ++r) m = fmaxf(m, raw[col][seg * 64 + r]);
        redm[seg][col] = m;
        __syncthreads();
        float M = redm[0][col];
        #pragma unroll
        for (int s2 = 1; s2 < 8; ++s2) M = fmaxf(M, redm[s2][col]);

        float s = 0.f;
        #pragma unroll
        for (int r = 0; r < 64; ++r) {
            const int row = seg * 64 + r;
            s += __expf(raw[col][row] - M) * mask_c[row];
        }
        reds[seg][col] = s;
        __syncthreads();
        float L = 0.f;
        #pragma unroll
        for (int s2 = 0; s2 < 8; ++s2) L += reds[s2][col];
        const float inv = 1.f / (L + 1e-8f);

        const int col_g = t * 32 + col;
        char* pfb = (char*)PF1 + ((size_t)b * 32 + (col_g >> 4)) * 16384;
        #pragma unroll
        for (int kc = 0; kc < 8; ++kc) {
            const int k0 = seg * 64 + kc * 8;
            float e[8];
            #pragma unroll
            for (int j = 0; j < 8; ++j)
                e[j] = __expf(raw[col][k0 + j] - M) * mask_c[k0 + j] * inv;
            H8 o;
            o.u[0] = pk2(e[0], e[1]); o.u[1] = pk2(e[2], e[3]);
            o.u[2] = pk2(e[4], e[5]); o.u[3] = pk2(e[6], e[7]);
            const int lw = seg * 8 + kc;
            *(half8*)(pfb + (lw >> 2) * 1024 + (lw & 3) * 256 + (col_g & 15) * 16) = o.h;
        }
    }
}

// ---------------------------------------------------------------------------
// Stage 3: OUT = P.V, fragment-direct, double-buffered counted vmcnt.
// P tiles are DENSE 16KB (stride 16384).
// ---------------------------------------------------------------------------
__global__ __launch_bounds__(256)
void pv_frag(const float* __restrict__ PF0, const float* __restrict__ PF1,
             const _Float16* __restrict__ xv1, const _Float16* __restrict__ xv2,
             float* __restrict__ o1, float* __restrict__ o2)
{
    const int i    = blockIdx.x;           // 2048
    const int xcd  = i & 7;
    const int j    = i >> 3;               // 0..255
    const int lt   = j & 7;                // fastest (8 l-tiles of 64 rows)
    const int dq   = (j >> 3) & 3;         // 4 d-quarters of 192
    const int side = (j >> 5) & 1;
    const int b    = xcd * 4 + (j >> 6);   // slowest
    const int l0   = lt * 64;

    const float* __restrict__ PF    = side ? PF1 : PF0;
    const _Float16* __restrict__ VF = side ? xv1 : xv2;   // V = other side
    float* __restrict__ OUT         = side ? o2 : o1;

    const int tid  = threadIdx.x;
    const int lane = tid & 63;
    const int w    = tid >> 6;
    const int lr   = lane & 15;
    const int lg   = lane >> 4;

    const char* pb[4];
    #pragma unroll
    for (int q = 0; q < 4; ++q)
        pb[q] = (const char*)PF + ((size_t)b * 32 + lt * 4 + q) * 16384 + lane * 16;
    const _Float16* vbase = VF + (((size_t)b * 48 + dq * 12 + w * 3) * 16) * 512 + lane * 8;

    f4 acc[12];                            // [q][nt]
    #pragma unroll
    for (int t = 0; t < 12; ++t) acc[t] = f4{0.f, 0.f, 0.f, 0.f};

    half8 pa[2][2][4], vf[2][2][3];        // [buf][k2][...]

    #pragma unroll
    for (int k2 = 0; k2 < 2; ++k2) {
        #pragma unroll
        for (int q = 0; q < 4; ++q)
            gload16(pa[0][k2][q], (const _Float16*)(pb[q] + k2 * 1024));
        #pragma unroll
        for (int nt = 0; nt < 3; ++nt)
            gload16(vf[0][k2][nt], vbase + ((size_t)nt * 16 + k2) * 512);
    }

    #pragma unroll
    for (int cb = 0; cb < 8; ++cb) {       // 8 batches x 2 ks2; cur=cb&1
        const int cur = cb & 1;
        const int nxt = cur ^ 1;
        if (cb < 7) {
            #pragma unroll
            for (int k2 = 0; k2 < 2; ++k2) {
                const int ks2 = (cb + 1) * 2 + k2;
                #pragma unroll
                for (int q = 0; q < 4; ++q)
                    gload16(pa[nxt][k2][q], (const _Float16*)(pb[q] + ks2 * 1024));
                #pragma unroll
                for (int nt = 0; nt < 3; ++nt)
                    gload16(vf[nxt][k2][nt], vbase + ((size_t)nt * 16 + ks2) * 512);
            }
            asm volatile("s_waitcnt vmcnt(14)" ::: "memory");
        } else {
            asm volatile("s_waitcnt vmcnt(0)" ::: "memory");
        }
        __builtin_amdgcn_sched_barrier(0);
        __builtin_amdgcn_s_setprio(1);
        #pragma unroll
        for (int k2 = 0; k2 < 2; ++k2)
            #pragma unroll
            for (int nt = 0; nt < 3; ++nt)
                #pragma unroll
                for (int q = 0; q < 4; ++q)
                    acc[q * 3 + nt] = __builtin_amdgcn_mfma_f32_16x16x32_f16(pa[cur][k2][q], vf[cur][k2][nt], acc[q * 3 + nt], 0, 0, 0);
        __builtin_amdgcn_s_setprio(0);
    }

    #pragma unroll
    for (int q = 0; q < 4; ++q)
        #pragma unroll
        for (int nt = 0; nt < 3; ++nt)
            #pragma unroll
            for (int r = 0; r < 4; ++r)
                OUT[((size_t)(l0 + q * 16 + 4 * lg + r) * BB + b) * DD + dq * 192 + (w * 3 + nt) * 16 + lr]
                    = acc[q * 3 + nt][r];
}

// ---------------------------------------------------------------------------
// Fallback (f32 direct, no ws).
// ---------------------------------------------------------------------------
__global__ __launch_bounds__(256)
void coatt_flash_f32(const float* __restrict__ x1, const float* __restrict__ m1,
                     const float* __restrict__ x2, const float* __restrict__ m2,
                     float* __restrict__ o1, float* __restrict__ o2)
{
    const int i    = blockIdx.x;
    const int xcd  = i & 7;
    const int j    = i >> 3;
    const int pair = xcd * 8 + (j >> 5);
    const int qt   = j & 31;
    const int side = pair >> 5;
    const int b    = pair & 31;

    const float* __restrict__ Q   = side ? x2 : x1;
    const float* __restrict__ K   = side ? x1 : x2;
    const float* __restrict__ MK  = side ? m1 : m2;
    float* __restrict__       OUT = side ? o2 : o1;

    const int tid  = threadIdx.x;
    const int lane = tid & 63;
    const int w    = tid >> 6;
    const int lr   = lane & 15;
    const int lg   = lane >> 4;
    const int q0 = qt * 16;
    const int d0 = w * (DD / 4);

    __shared__ float sred[4][16][36];
    __shared__ float mask_s[LKN];
    for (int t = tid; t < LKN; t += 256) mask_s[t] = MK[t * BB + b];

    half8 qf[6];
    {
        const float* qrow = Q + ((q0 + lr) * BB + b) * DD + d0 + lg * 8;
        #pragma unroll
        for (int ks = 0; ks < 6; ++ks) {
            f4 a = *(const f4*)(qrow + ks * 32);
            f4 c = *(const f4*)(qrow + ks * 32 + 4);
            qf[ks] = cvt8(a, c);
        }
    }
    f4 acc[12];
    #pragma unroll
    for (int t = 0; t < 12; ++t) acc[t] = f4{0.f, 0.f, 0.f, 0.f};
    float Mrun = -3.0e38f, Lrun = 0.f;
    for (int kt = 0; kt < 16; ++kt) {
        const int k0 = kt * 32;
        f4 s0 = {0.f,0.f,0.f,0.f}, s1 = {0.f,0.f,0.f,0.f};
        {
            const float* kb0 = K + ((k0 + lr) * BB + b) * DD + d0 + lg * 8;
            const float* kb1 = kb0 + 16 * BB * DD;
            #pragma unroll
            for (int ks = 0; ks < 6; ++ks) {
                f4 a0 = *(const f4*)(kb0 + ks * 32);
                f4 c0 = *(const f4*)(kb0 + ks * 32 + 4);
                s0 = __builtin_amdgcn_mfma_f32_16x16x32_f16(qf[ks], cvt8(a0, c0), s0, 0, 0, 0);
                f4 a1 = *(const f4*)(kb1 + ks * 32);
                f4 c1 = *(const f4*)(kb1 + ks * 32 + 4);
                s1 = __builtin_amdgcn_mfma_f32_16x16x32_f16(qf[ks], cvt8(a1, c1), s1, 0, 0, 0);
            }
        }
        __syncthreads();
        #pragma unroll
        for (int r = 0; r < 4; ++r) {
            sred[w][4 * lg + r][lr]      = s0[r];
            sred[w][4 * lg + r][16 + lr] = s1[r];
        }
        __syncthreads();
        f4 sa = {0.f,0.f,0.f,0.f}, sb = {0.f,0.f,0.f,0.f};
        #pragma unroll
        for (int ww = 0; ww < 4; ++ww) {
            sa += *(const f4*)&sred[ww][lr][lg * 8];
            sb += *(const f4*)&sred[ww][lr][lg * 8 + 4];
        }
        float tmax = fmaxf(fmaxf(fmaxf(sa[0], sa[1]), fmaxf(sa[2], sa[3])),
                           fmaxf(fmaxf(sb[0], sb[1]), fmaxf(sb[2], sb[3])));
        tmax = fmaxf(tmax, __shfl_xor(tmax, 16));
        tmax = fmaxf(tmax, __shfl_xor(tmax, 32));
        const float Mnew  = fmaxf(Mrun, tmax);
        const float scale = __expf(Mrun - Mnew);
        float p[8];
        float psum = 0.f;
        const float* mrow = &mask_s[k0 + lg * 8];
        #pragma unroll
        for (int t = 0; t < 4; ++t) { p[t]     = __expf(sa[t] - Mnew) * mrow[t];     psum += p[t]; }
        #pragma unroll
        for (int t = 0; t < 4; ++t) { p[4 + t] = __expf(sb[t] - Mnew) * mrow[4 + t]; psum += p[4 + t]; }
        psum += __shfl_xor(psum, 16);
        psum += __shfl_xor(psum, 32);
        Lrun = Lrun * scale + psum;
        Mrun = Mnew;
        H8 pf;
        pf.u[0] = pk2(p[0], p[1]); pf.u[1] = pk2(p[2], p[3]);
        pf.u[2] = pk2(p[4], p[5]); pf.u[3] = pk2(p[6], p[7]);
        float sc[4];
        #pragma unroll
        for (int r = 0; r < 4; ++r) sc[r] = __shfl(scale, (lane & 48) + 4 * lg + r);
        #pragma unroll
        for (int t = 0; t < 12; ++t) {
            acc[t][0] *= sc[0]; acc[t][1] *= sc[1];
            acc[t][2] *= sc[2]; acc[t][3] *= sc[3];
        }
        const float* vb = K + ((k0 + lg * 8) * BB + b) * DD + d0 + lr;
        #pragma unroll
        for (int nt = 0; nt < 12; ++nt) {
            const float* vp = vb + nt * 16;
            float vv[8];
            #pragma unroll
            for (int t = 0; t < 8; ++t) vv[t] = vp[t * BB * DD];
            H8 vf;
            vf.u[0] = pk2(vv[0], vv[1]); vf.u[1] = pk2(vv[2], vv[3]);
            vf.u[2] = pk2(vv[4], vv[5]); vf.u[3] = pk2(vv[6], vv[7]);
            acc[nt] = __builtin_amdgcn_mfma_f32_16x16x32_f16(pf.h, vf.h, acc[nt], 0, 0, 0);
        }
    }
    float il[4];
    {
        const float inv = 1.f / (Lrun + 1e-8f);
        #pragma unroll
        for (int r = 0; r < 4; ++r) il[r] = __shfl(inv, (lane & 48) + 4 * lg + r);
    }
    #pragma unroll
    for (int nt = 0; nt < 12; ++nt) {
        #pragma unroll
        for (int r = 0; r < 4; ++r) {
            OUT[((q0 + 4 * lg + r) * BB + b) * DD + d0 + nt * 16 + lr] = acc[nt][r] * il[r];
        }
    }
}

extern "C" void kernel_launch(void* const* d_in, const int* in_sizes, int n_in,
                              void* d_out, int out_size, void* d_ws, size_t ws_size,
                              hipStream_t stream) {
    (void)in_sizes; (void)n_in; (void)out_size;
    const float* x1 = (const float*)d_in[0];
    const float* m1 = (const float*)d_in[1];
    const float* x2 = (const float*)d_in[2];
    const float* m2 = (const float*)d_in[3];
    float* o1 = (float*)d_out;
    float* o2 = o1 + (size_t)LQ * BB * DD;

    const size_t ELEMS = (size_t)LQ * BB * DD;           // 12.58M
    const size_t SELEM = (size_t)BB * 512 * 512;         // 8.39M
    const size_t NEED  = 4 * ELEMS * sizeof(_Float16)    // XF + XV (100.7 MB)
                       + SELEM * sizeof(float);          // S f32 (33.6 MB) = 134.2 MB

    if (ws_size >= NEED) {
        _Float16* xf1 = (_Float16*)d_ws;
        _Float16* xf2 = xf1 + ELEMS;
        _Float16* xv1 = xf2 + ELEMS;
        _Float16* xv2 = xv1 + ELEMS;
        float*    S32 = (float*)(xv2 + ELEMS);           // dedicated 33.6 MB
        // Dense P buffers overlay the XF region (dead after gemm_s):
        // PF0 at +0 (16.78 MB), PF1 at +16.78 MB. Both < 50.3 MB region.
        float*    PF0 = (float*)d_ws;
        float*    PF1 = (float*)((char*)d_ws + (size_t)32 * 32 * 16384);
        prep_pack<<<3072, 256, 0, stream>>>(x1, x2, xf1, xf2, xv1, xv2);
        gemm_s<<<512, 256, 0, stream>>>(xf1, xf2, S32);
        softmax_both<<<1024, 256, 0, stream>>>(S32, PF0, PF1, m1, m2);
        pv_frag<<<2048, 256, 0, stream>>>(PF0, PF1, xv1, xv2, o1, o2);
    } else {
        coatt_flash_f32<<<2048, 256, 0, stream>>>(x1, m1, x2, m2, o1, o2);
    }
}